// Round 1
// baseline (4107.676 us; speedup 1.0000x reference)
//
#include <hip/hip_runtime.h>
#include <math.h>

#define NN 100000
#define NE 1600000
#define NG 128
#define L 32
#define H 64
#define D 256

__device__ __forceinline__ float sigm(float x){ return 1.0f/(1.0f+expf(-x)); }

// ---- degree / counts ----
__global__ void k_count_deg(const int* __restrict__ dst, float* __restrict__ deg){
    int i = blockIdx.x*blockDim.x + threadIdx.x;
    if (i < NE) atomicAdd(&deg[dst[i]], 1.0f);
}
__global__ void k_count_batch(const int* __restrict__ batch, float* __restrict__ cnt){
    int i = blockIdx.x*blockDim.x + threadIdx.x;
    if (i < NN) atomicAdd(&cnt[batch[i]], 1.0f);
}
__global__ void k_dinv(float* __restrict__ deg){
    int i = blockIdx.x*blockDim.x + threadIdx.x;
    if (i < NN) deg[i] = rsqrtf(deg[i] + 1.0f);
}

// ---- pre: f = (feat@W + b) * rsqrt(max(cnt,1))[batch]; a[:,0:64] = f*(1+delta) ----
__global__ void k_pre(const float* __restrict__ feat, const float* __restrict__ W,
                      const float* __restrict__ b, const int* __restrict__ batch,
                      const float* __restrict__ cnt, const float* __restrict__ delta,
                      float* __restrict__ f, float* __restrict__ a){
    __shared__ float Ws[L*H];
    __shared__ float bs[H];
    int tid = threadIdx.x;
    for (int i = tid; i < L*H; i += 256) Ws[i] = W[i];
    if (tid < H) bs[tid] = b[tid];
    __syncthreads();
    long idx = (long)blockIdx.x*256 + tid;
    int n = (int)(idx >> 6); int h = (int)(idx & 63);
    if (n >= NN) return;
    const float* fr = feat + (long)n*L;
    float v = bs[h];
#pragma unroll
    for (int k = 0; k < L; k++) v += fr[k]*Ws[k*H+h];
    float nrm = rsqrtf(fmaxf(cnt[batch[n]], 1.0f));
    float fv = v*nrm;
    f[(long)n*H + h] = fv;
    a[(long)n*D + h] = fv*(1.0f + delta[0]);
}

// ---- xw = x @ W (64x64), x has row-stride xs ----
__global__ void k_gemm64(const float* __restrict__ x, int xs,
                         const float* __restrict__ W, float* __restrict__ xw){
    __shared__ float Ws[H*H];
    int tid = threadIdx.x;
    for (int i = tid; i < H*H; i += 256) Ws[i] = W[i];
    __syncthreads();
    long idx = (long)blockIdx.x*256 + tid;
    int n = (int)(idx >> 6); int h = (int)(idx & 63);
    if (n >= NN) return;
    const float* xr = x + (long)n*xs;
    float v = 0.f;
#pragma unroll
    for (int k = 0; k < H; k++) v += xr[k]*Ws[k*H+h];
    xw[(long)n*H + h] = v;
}

// ---- edge scatter: agg[dst] += xw[src] * dinv[src]*dinv[dst] ----
__global__ void k_scatter(const int* __restrict__ src, const int* __restrict__ dst,
                          const float* __restrict__ dinv, const float* __restrict__ xw,
                          float* __restrict__ agg){
    long idx = (long)blockIdx.x*256 + threadIdx.x;
    long e = idx >> 6; int h = (int)(idx & 63);
    if (e >= NE) return;
    int s = src[e], d = dst[e];
    float c = dinv[s]*dinv[d];
    atomicAdd(&agg[(long)d*H + h], xw[(long)s*H + h]*c);
}

// ---- combine: y = agg + xw*dinv^2 + b ; optional y = relu(y)+x ; write to a-slice (stride D) ----
__global__ void k_combine(const float* __restrict__ agg, const float* __restrict__ xw,
                          const float* __restrict__ dinv, const float* __restrict__ b,
                          const float* __restrict__ xin, int xs,
                          float* __restrict__ aout, int relu_res){
    long idx = (long)blockIdx.x*256 + threadIdx.x;
    int n = (int)(idx >> 6); int h = (int)(idx & 63);
    if (n >= NN) return;
    float di = dinv[n];
    float y = agg[(long)n*H + h] + xw[(long)n*H + h]*di*di + b[h];
    if (relu_res) y = fmaxf(y, 0.f) + xin[(long)n*xs + h];
    aout[(long)n*D + h] = y;
}

// ---- segmented sum over sorted batch: s[g,d] += a[n,d] ----
__global__ void k_segsum(const float* __restrict__ a, const int* __restrict__ batch,
                         float* __restrict__ s){
    int d = threadIdx.x;                 // 256 = D columns
    int n0 = blockIdx.x*256;
    if (n0 >= NN) return;
    int n1 = min(n0 + 256, NN);
    float acc = 0.f;
    int curg = batch[n0];
    for (int n = n0; n < n1; n++){
        int g = batch[n];
        if (g != curg){ atomicAdd(&s[curg*D + d], acc); acc = 0.f; curg = g; }
        acc += a[(long)n*D + d];
    }
    atomicAdd(&s[curg*D + d], acc);
}

// ---- t = tanh((s @ att_W) / max(cnt,1)) ----
__global__ void k_ctx(const float* __restrict__ s, const float* __restrict__ attW,
                      const float* __restrict__ cnt, float* __restrict__ t){
    int idx = blockIdx.x*256 + threadIdx.x;   // G*D
    int g = idx >> 8; int d = idx & 255;
    float inv = 1.0f/fmaxf(cnt[g], 1.0f);
    float v = 0.f;
    for (int k = 0; k < D; k++) v += s[g*D + k]*attW[k*D + d];
    t[idx] = tanhf(v*inv);
}

// ---- coef[n] = sigmoid(a[n]·t[batch[n]]); ap[g] += coef*a[n] ; one wave per 64 nodes ----
__global__ void k_coef_ap(const float* __restrict__ a, const int* __restrict__ batch,
                          const float* __restrict__ t, float* __restrict__ ap){
    int lane = threadIdx.x & 63;
    int wid  = (blockIdx.x*blockDim.x + threadIdx.x) >> 6;
    int n0 = wid*64;
    if (n0 >= NN) return;
    int n1 = min(n0 + 64, NN);
    float acc[4] = {0.f, 0.f, 0.f, 0.f};
    int curg = batch[n0];
    for (int n = n0; n < n1; n++){
        int g = batch[n];
        const float* ar = a + (long)n*D;
        const float* tr = t + (long)g*D;
        float v[4]; float part = 0.f;
#pragma unroll
        for (int j = 0; j < 4; j++){ v[j] = ar[j*64 + lane]; part += v[j]*tr[j*64 + lane]; }
#pragma unroll
        for (int off = 32; off; off >>= 1) part += __shfl_xor(part, off, 64);
        float coef = sigm(part);
        if (g != curg){
#pragma unroll
            for (int j = 0; j < 4; j++){ atomicAdd(&ap[curg*D + j*64 + lane], acc[j]); acc[j] = 0.f; }
            curg = g;
        }
#pragma unroll
        for (int j = 0; j < 4; j++) acc[j] += coef*v[j];
    }
#pragma unroll
    for (int j = 0; j < 4; j++) atomicAdd(&ap[curg*D + j*64 + lane], acc[j]);
}

// ---- per-graph MLP: out = relu(p@W1+b1)@W2+b2, p = mu*ap + (1-mu)*s ----
__global__ void k_mlp2(const float* __restrict__ ap, const float* __restrict__ s,
                       const float* __restrict__ mu,
                       const float* __restrict__ W1, const float* __restrict__ b1,
                       const float* __restrict__ W2, const float* __restrict__ b2,
                       float* __restrict__ out){
    __shared__ float p[D];
    __shared__ float hid[128];
    int g = blockIdx.x; int tid = threadIdx.x;   // 128 threads
    for (int i = tid; i < D; i += 128){
        float m = mu[i];
        p[i] = m*ap[g*D + i] + (1.0f - m)*s[g*D + i];
    }
    __syncthreads();
    float v = b1[tid];
    for (int k = 0; k < D; k++) v += p[k]*W1[k*128 + tid];
    hid[tid] = fmaxf(v, 0.f);
    __syncthreads();
    if (tid < H){
        float o = b2[tid];
        for (int k = 0; k < 128; k++) o += hid[k]*W2[k*H + tid];
        out[g*H + tid] = o;
    }
}

// ---- final NTN + scoring, one wave per graph ----
__global__ void k_final(const float* __restrict__ gx, const float* __restrict__ hx,
                        const float* __restrict__ tnW, const float* __restrict__ tnV,
                        const float* __restrict__ tnb,
                        const float* __restrict__ scW1, const float* __restrict__ scb1,
                        const float* __restrict__ scW2, const float* __restrict__ scb2,
                        const float* __restrict__ alpha, float* __restrict__ outp){
    __shared__ float sg[H], sh[H], sc[16], h2[16];
    int g = blockIdx.x; int lane = threadIdx.x;  // 64 threads
    float gv = gx[g*H + lane], hv = hx[g*H + lane];
    sg[lane] = gv; sh[lane] = hv;
    __syncthreads();
    float myt1 = 0.f;
    for (int k = 0; k < 16; k++){
        float inner = 0.f;
        for (int d = 0; d < H; d++) inner += sg[d]*tnW[(d*H + lane)*16 + k];
        float part = inner*hv;
#pragma unroll
        for (int off = 32; off; off >>= 1) part += __shfl_xor(part, off, 64);
        if (lane == k) myt1 = part;
    }
    if (lane < 16){
        float t2 = tnb[lane];
        for (int d = 0; d < H; d++) t2 += sg[d]*tnV[lane*128 + d];
        for (int e = 0; e < H; e++) t2 += sh[e]*tnV[lane*128 + 64 + e];
        sc[lane] = fmaxf(myt1 + t2, 0.f);
    }
    __syncthreads();
    if (lane < 16){
        float v = scb1[lane];
        for (int j = 0; j < 16; j++) v += sc[j]*scW1[j*16 + lane];
        h2[lane] = fmaxf(v, 0.f);
    }
    __syncthreads();
    float dff = gv - hv;
    float ssq = dff*dff;
#pragma unroll
    for (int off = 32; off; off >>= 1) ssq += __shfl_xor(ssq, off, 64);
    if (lane == 0){
        float score = scb2[0];
        for (int j = 0; j < 16; j++) score += h2[j]*scW2[j];
        float l2 = sqrtf(ssq);
        float al = alpha[0];
        outp[g] = al*sigm(score) + (1.0f - al)*(1.0f/(1.0f + expf(l2)));
    }
}

extern "C" void kernel_launch(void* const* d_in, const int* in_sizes, int n_in,
                              void* d_out, int out_size, void* d_ws, size_t ws_size,
                              hipStream_t stream) {
    const int*   ei1   = (const int*)d_in[0];
    const int*   ei2   = (const int*)d_in[1];
    const int*   bat1  = (const int*)d_in[2];
    const int*   bat2  = (const int*)d_in[3];
    const float* feat1 = (const float*)d_in[4];
    const float* feat2 = (const float*)d_in[5];
    const float* preW  = (const float*)d_in[6];
    const float* preb  = (const float*)d_in[7];
    const float* convW = (const float*)d_in[8];
    const float* convb = (const float*)d_in[9];
    const float* delta = (const float*)d_in[10];
    const float* alpha = (const float*)d_in[11];
    const float* mu    = (const float*)d_in[12];
    const float* attW  = (const float*)d_in[13];
    const float* pW1   = (const float*)d_in[14];
    const float* pb1   = (const float*)d_in[15];
    const float* pW2   = (const float*)d_in[16];
    const float* pb2   = (const float*)d_in[17];
    const float* tnW   = (const float*)d_in[18];
    const float* tnV   = (const float*)d_in[19];
    const float* tnb   = (const float*)d_in[20];
    const float* scW1  = (const float*)d_in[21];
    const float* scb1  = (const float*)d_in[22];
    const float* scW2  = (const float*)d_in[23];
    const float* scb2  = (const float*)d_in[24];
    float* out = (float*)d_out;

    // workspace carve (floats)
    float* ws = (float*)d_ws;
    float* a    = ws;  ws += (size_t)NN*D;
    float* f    = ws;  ws += (size_t)NN*H;
    float* xw   = ws;  ws += (size_t)NN*H;
    float* agg  = ws;  ws += (size_t)NN*H;
    float* dinv = ws;  ws += NN;
    float* cnt  = ws;  ws += NG;
    float* ssum = ws;  ws += NG*D;
    float* tmat = ws;  ws += NG*D;
    float* ap   = ws;  ws += NG*D;
    float* gx   = ws;  ws += NG*H;
    float* hx   = ws;  ws += NG*H;

    const int B = 256;
    const int gNH   = (NN*H + B - 1)/B;          // node x feature grids
    const int gE    = (NE + B - 1)/B;
    const int gN    = (NN + B - 1)/B;
    const long eh   = (long)NE*H;
    const int gEH   = (int)((eh + B - 1)/B);
    const int gSeg  = (NN + 255)/256;
    const int waves = (NN + 63)/64;
    const int gCoef = (waves + 3)/4;

    auto run_side = [&](const int* ei, const int* batch, const float* feat, float* gout){
        const int* src = ei;
        const int* dst = ei + NE;
        hipMemsetAsync(dinv, 0, NN*sizeof(float), stream);
        hipMemsetAsync(cnt,  0, NG*sizeof(float), stream);
        hipMemsetAsync(ssum, 0, NG*D*sizeof(float), stream);
        hipMemsetAsync(ap,   0, NG*D*sizeof(float), stream);
        k_count_deg<<<gE, B, 0, stream>>>(dst, dinv);
        k_count_batch<<<gN, B, 0, stream>>>(batch, cnt);
        k_dinv<<<gN, B, 0, stream>>>(dinv);
        k_pre<<<gNH, B, 0, stream>>>(feat, preW, preb, batch, cnt, delta, f, a);

        const float* xin = f; int xs = H;
        for (int i = 0; i < 3; i++){
            k_gemm64<<<gNH, B, 0, stream>>>(xin, xs, convW + i*H*H, xw);
            hipMemsetAsync(agg, 0, (size_t)NN*H*sizeof(float), stream);
            k_scatter<<<gEH, B, 0, stream>>>(src, dst, dinv, xw, agg);
            float* aout = a + (i + 1)*H;
            k_combine<<<gNH, B, 0, stream>>>(agg, xw, dinv, convb + i*H, xin, xs, aout, i < 2 ? 1 : 0);
            xin = aout; xs = D;
        }
        k_segsum<<<gSeg, 256, 0, stream>>>(a, batch, ssum);
        k_ctx<<<NG*D/256, 256, 0, stream>>>(ssum, attW, cnt, tmat);
        k_coef_ap<<<gCoef, 256, 0, stream>>>(a, batch, tmat, ap);
        k_mlp2<<<NG, 128, 0, stream>>>(ap, ssum, mu, pW1, pb1, pW2, pb2, gout);
    };

    run_side(ei1, bat1, feat1, gx);
    run_side(ei2, bat2, feat2, hx);
    k_final<<<NG, 64, 0, stream>>>(gx, hx, tnW, tnV, tnb, scW1, scb1, scW2, scb2, alpha, out);
}

// Round 2
// 1961.538 us; speedup vs baseline: 2.0941x; 2.0941x over previous
//
#include <hip/hip_runtime.h>
#include <math.h>

#define NN 100000
#define NE 1600000
#define NG 128
#define L 32
#define H 64
#define D 256

__device__ __forceinline__ float sigm(float x){ return 1.0f/(1.0f+expf(-x)); }

// ================= CSR build =================
__global__ void k_deg_count(const int* __restrict__ dst, int* __restrict__ deg){
    int i = blockIdx.x*blockDim.x + threadIdx.x;
    if (i < NE) atomicAdd(&deg[dst[i]], 1);
}
__global__ void k_blocksum(const int* __restrict__ deg, int* __restrict__ bsum){
    __shared__ int s[256];
    int t = threadIdx.x; int i = blockIdx.x*256 + t;
    s[t] = (i < NN) ? deg[i] : 0;
    __syncthreads();
    for (int o = 128; o; o >>= 1){ if (t < o) s[t] += s[t+o]; __syncthreads(); }
    if (t == 0) bsum[blockIdx.x] = s[0];
}
__global__ void k_scan_bsum(int* __restrict__ bsum, int nb){
    __shared__ int s[512];
    int t = threadIdx.x;
    s[t] = (t < nb) ? bsum[t] : 0;
    __syncthreads();
    for (int o = 1; o < 512; o <<= 1){
        int u = (t >= o) ? s[t-o] : 0;
        __syncthreads();
        s[t] += u;
        __syncthreads();
    }
    if (t < nb) bsum[t] = (t == 0) ? 0 : s[t-1];   // exclusive block offsets
}
__global__ void k_scan_apply(const int* __restrict__ deg, const int* __restrict__ boff,
                             int* __restrict__ off){
    __shared__ int s[256];
    int t = threadIdx.x; int i = blockIdx.x*256 + t;
    int v = (i < NN) ? deg[i] : 0;
    s[t] = v;
    __syncthreads();
    for (int o = 1; o < 256; o <<= 1){
        int u = (t >= o) ? s[t-o] : 0;
        __syncthreads();
        s[t] += u;
        __syncthreads();
    }
    if (i < NN) off[i] = boff[blockIdx.x] + s[t] - v;  // exclusive prefix
    if (i == 0) off[NN] = NE;
}
__global__ void k_fill(const int* __restrict__ src, const int* __restrict__ dst,
                       const int* __restrict__ off, int* __restrict__ cur,
                       int* __restrict__ csrc){
    int e = blockIdx.x*blockDim.x + threadIdx.x;
    if (e >= NE) return;
    int d = dst[e];
    int p = atomicAdd(&cur[d], 1);
    csrc[off[d] + p] = src[e];
}
__global__ void k_dinv(const int* __restrict__ deg, float* __restrict__ dinv){
    int i = blockIdx.x*blockDim.x + threadIdx.x;
    if (i < NN) dinv[i] = rsqrtf((float)deg[i] + 1.0f);
}

// ================= batch counts (sorted batch, no contended atomics) =================
__global__ void k_bounds(const int* __restrict__ batch, int* __restrict__ bs, int* __restrict__ be){
    int i = blockIdx.x*blockDim.x + threadIdx.x;
    if (i >= NN) return;
    int g = batch[i];
    if (i == 0 || batch[i-1] != g) bs[g] = i;
    if (i == NN-1 || batch[i+1] != g) be[g] = i + 1;
}
__global__ void k_cnt(const int* __restrict__ bs, const int* __restrict__ be, float* __restrict__ cnt){
    int g = threadIdx.x;
    if (g < NG) cnt[g] = (float)(be[g] - bs[g]);
}

// ================= pre =================
__global__ void k_pre(const float* __restrict__ feat, const float* __restrict__ W,
                      const float* __restrict__ b, const int* __restrict__ batch,
                      const float* __restrict__ cnt, const float* __restrict__ delta,
                      float* __restrict__ f, float* __restrict__ a){
    __shared__ float Ws[L*H];
    __shared__ float bs[H];
    int tid = threadIdx.x;
    for (int i = tid; i < L*H; i += 256) Ws[i] = W[i];
    if (tid < H) bs[tid] = b[tid];
    __syncthreads();
    long idx = (long)blockIdx.x*256 + tid;
    int n = (int)(idx >> 6); int h = (int)(idx & 63);
    if (n >= NN) return;
    const float* fr = feat + (long)n*L;
    float v = bs[h];
#pragma unroll
    for (int k = 0; k < L; k++) v += fr[k]*Ws[k*H+h];
    float nrm = rsqrtf(fmaxf(cnt[batch[n]], 1.0f));
    float fv = v*nrm;
    f[(long)n*H + h] = fv;
    a[(long)n*D + h] = fv*(1.0f + delta[0]);
}

// ================= xw = x @ W (64x64) =================
__global__ void k_gemm64(const float* __restrict__ x, int xs,
                         const float* __restrict__ W, float* __restrict__ xw){
    __shared__ float Ws[H*H];
    int tid = threadIdx.x;
    for (int i = tid; i < H*H; i += 256) Ws[i] = W[i];
    __syncthreads();
    long idx = (long)blockIdx.x*256 + tid;
    int n = (int)(idx >> 6); int h = (int)(idx & 63);
    if (n >= NN) return;
    const float* xr = x + (long)n*xs;
    float v = 0.f;
#pragma unroll
    for (int k = 0; k < H; k++) v += xr[k]*Ws[k*H+h];
    xw[(long)n*H + h] = v;
}

// ================= fused CSR gather + combine =================
// y[d,h] = (sum_{e in in(d)} xw[src_e,h]*dinv[src_e] + xw[d,h]*dinv[d]) * dinv[d] + b[h]
// if relu_res: y = relu(y) + xin[d,h]; write to aout[d*D+h]
__global__ void k_conv(const int* __restrict__ off, const int* __restrict__ csrc,
                       const float* __restrict__ dinv, const float* __restrict__ xw,
                       const float* __restrict__ b, const float* __restrict__ xin, int xs,
                       float* __restrict__ aout, int relu_res){
    int wid  = (blockIdx.x*blockDim.x + threadIdx.x) >> 6;
    int lane = threadIdx.x & 63;
    if (wid >= NN) return;
    int d = wid;
    int e0 = off[d], e1 = off[d+1];
    float acc = 0.f, acc2 = 0.f;
    int e = e0;
    for (; e + 1 < e1; e += 2){
        int s0 = csrc[e], s1 = csrc[e+1];
        float c0 = dinv[s0], c1 = dinv[s1];
        acc  += xw[(long)s0*H + lane]*c0;
        acc2 += xw[(long)s1*H + lane]*c1;
    }
    if (e < e1){ int s0 = csrc[e]; acc += xw[(long)s0*H + lane]*dinv[s0]; }
    acc += acc2;
    float di = dinv[d];
    float y = (acc + xw[(long)d*H + lane]*di)*di + b[lane];
    if (relu_res) y = fmaxf(y, 0.f) + xin[(long)d*xs + lane];
    aout[(long)d*D + lane] = y;
}

// ================= segmented sum over sorted batch =================
__global__ void k_segsum(const float* __restrict__ a, const int* __restrict__ batch,
                         float* __restrict__ s){
    int d = threadIdx.x;                 // 256 = D columns
    int n0 = blockIdx.x*64;
    if (n0 >= NN) return;
    int n1 = min(n0 + 64, NN);
    float acc = 0.f;
    int curg = batch[n0];
    for (int n = n0; n < n1; n++){
        int g = batch[n];
        if (g != curg){ atomicAdd(&s[curg*D + d], acc); acc = 0.f; curg = g; }
        acc += a[(long)n*D + d];
    }
    atomicAdd(&s[curg*D + d], acc);
}

// ================= t = tanh((s @ att_W) / max(cnt,1)) =================
__global__ void k_ctx(const float* __restrict__ s, const float* __restrict__ attW,
                      const float* __restrict__ cnt, float* __restrict__ t){
    int idx = blockIdx.x*256 + threadIdx.x;   // G*D
    int g = idx >> 8; int d = idx & 255;
    float inv = 1.0f/fmaxf(cnt[g], 1.0f);
    float v = 0.f;
    for (int k = 0; k < D; k++) v += s[g*D + k]*attW[k*D + d];
    t[idx] = tanhf(v*inv);
}

// ================= coef + attention pool (float4) =================
__global__ void k_coef_ap(const float* __restrict__ a, const int* __restrict__ batch,
                          const float* __restrict__ t, float* __restrict__ ap){
    int lane = threadIdx.x & 63;
    int wid  = (blockIdx.x*blockDim.x + threadIdx.x) >> 6;
    int n0 = wid*64;
    if (n0 >= NN) return;
    int n1 = min(n0 + 64, NN);
    float ax=0.f, ay=0.f, az=0.f, aw=0.f;
    int curg = batch[n0];
    for (int n = n0; n < n1; n++){
        int g = batch[n];
        const float4* ar = (const float4*)(a + (long)n*D);
        const float4* tr = (const float4*)(t + (long)g*D);
        float4 v = ar[lane];
        float4 tv = tr[lane];
        float part = v.x*tv.x + v.y*tv.y + v.z*tv.z + v.w*tv.w;
#pragma unroll
        for (int o = 32; o; o >>= 1) part += __shfl_xor(part, o, 64);
        float coef = sigm(part);
        if (g != curg){
            atomicAdd(&ap[curg*D + lane*4 + 0], ax);
            atomicAdd(&ap[curg*D + lane*4 + 1], ay);
            atomicAdd(&ap[curg*D + lane*4 + 2], az);
            atomicAdd(&ap[curg*D + lane*4 + 3], aw);
            ax = ay = az = aw = 0.f; curg = g;
        }
        ax += coef*v.x; ay += coef*v.y; az += coef*v.z; aw += coef*v.w;
    }
    atomicAdd(&ap[curg*D + lane*4 + 0], ax);
    atomicAdd(&ap[curg*D + lane*4 + 1], ay);
    atomicAdd(&ap[curg*D + lane*4 + 2], az);
    atomicAdd(&ap[curg*D + lane*4 + 3], aw);
}

// ================= per-graph MLP =================
__global__ void k_mlp2(const float* __restrict__ ap, const float* __restrict__ s,
                       const float* __restrict__ mu,
                       const float* __restrict__ W1, const float* __restrict__ b1,
                       const float* __restrict__ W2, const float* __restrict__ b2,
                       float* __restrict__ out){
    __shared__ float p[D];
    __shared__ float hid[128];
    int g = blockIdx.x; int tid = threadIdx.x;   // 128 threads
    for (int i = tid; i < D; i += 128){
        float m = mu[i];
        p[i] = m*ap[g*D + i] + (1.0f - m)*s[g*D + i];
    }
    __syncthreads();
    float v = b1[tid];
    for (int k = 0; k < D; k++) v += p[k]*W1[k*128 + tid];
    hid[tid] = fmaxf(v, 0.f);
    __syncthreads();
    if (tid < H){
        float o = b2[tid];
        for (int k = 0; k < 128; k++) o += hid[k]*W2[k*H + tid];
        out[g*H + tid] = o;
    }
}

// ================= final NTN + scoring =================
__global__ void k_final(const float* __restrict__ gx, const float* __restrict__ hx,
                        const float* __restrict__ tnW, const float* __restrict__ tnV,
                        const float* __restrict__ tnb,
                        const float* __restrict__ scW1, const float* __restrict__ scb1,
                        const float* __restrict__ scW2, const float* __restrict__ scb2,
                        const float* __restrict__ alpha, float* __restrict__ outp){
    __shared__ float sg[H], sh[H], sc[16], h2[16];
    int g = blockIdx.x; int lane = threadIdx.x;  // 64 threads
    float gv = gx[g*H + lane], hv = hx[g*H + lane];
    sg[lane] = gv; sh[lane] = hv;
    __syncthreads();
    float myt1 = 0.f;
    for (int k = 0; k < 16; k++){
        float inner = 0.f;
        for (int d = 0; d < H; d++) inner += sg[d]*tnW[(d*H + lane)*16 + k];
        float part = inner*hv;
#pragma unroll
        for (int o = 32; o; o >>= 1) part += __shfl_xor(part, o, 64);
        if (lane == k) myt1 = part;
    }
    if (lane < 16){
        float t2 = tnb[lane];
        for (int d = 0; d < H; d++) t2 += sg[d]*tnV[lane*128 + d];
        for (int e = 0; e < H; e++) t2 += sh[e]*tnV[lane*128 + 64 + e];
        sc[lane] = fmaxf(myt1 + t2, 0.f);
    }
    __syncthreads();
    if (lane < 16){
        float v = scb1[lane];
        for (int j = 0; j < 16; j++) v += sc[j]*scW1[j*16 + lane];
        h2[lane] = fmaxf(v, 0.f);
    }
    __syncthreads();
    float dff = gv - hv;
    float ssq = dff*dff;
#pragma unroll
    for (int o = 32; o; o >>= 1) ssq += __shfl_xor(ssq, o, 64);
    if (lane == 0){
        float score = scb2[0];
        for (int j = 0; j < 16; j++) score += h2[j]*scW2[j];
        float l2 = sqrtf(ssq);
        float al = alpha[0];
        outp[g] = al*sigm(score) + (1.0f - al)*(1.0f/(1.0f + expf(l2)));
    }
}

extern "C" void kernel_launch(void* const* d_in, const int* in_sizes, int n_in,
                              void* d_out, int out_size, void* d_ws, size_t ws_size,
                              hipStream_t stream) {
    const int*   ei1   = (const int*)d_in[0];
    const int*   ei2   = (const int*)d_in[1];
    const int*   bat1  = (const int*)d_in[2];
    const int*   bat2  = (const int*)d_in[3];
    const float* feat1 = (const float*)d_in[4];
    const float* feat2 = (const float*)d_in[5];
    const float* preW  = (const float*)d_in[6];
    const float* preb  = (const float*)d_in[7];
    const float* convW = (const float*)d_in[8];
    const float* convb = (const float*)d_in[9];
    const float* delta = (const float*)d_in[10];
    const float* alpha = (const float*)d_in[11];
    const float* mu    = (const float*)d_in[12];
    const float* attW  = (const float*)d_in[13];
    const float* pW1   = (const float*)d_in[14];
    const float* pb1   = (const float*)d_in[15];
    const float* pW2   = (const float*)d_in[16];
    const float* pb2   = (const float*)d_in[17];
    const float* tnW   = (const float*)d_in[18];
    const float* tnV   = (const float*)d_in[19];
    const float* tnb   = (const float*)d_in[20];
    const float* scW1  = (const float*)d_in[21];
    const float* scb1  = (const float*)d_in[22];
    const float* scW2  = (const float*)d_in[23];
    const float* scb2  = (const float*)d_in[24];
    float* out = (float*)d_out;

    // workspace carve
    char* w = (char*)d_ws;
    float* a    = (float*)w; w += sizeof(float)*(size_t)NN*D;
    float* f    = (float*)w; w += sizeof(float)*(size_t)NN*H;
    float* xw   = (float*)w; w += sizeof(float)*(size_t)NN*H;
    float* dinv = (float*)w; w += sizeof(float)*NN;
    int*   deg  = (int*)w;   w += sizeof(int)*NN;
    int*   off  = (int*)w;   w += sizeof(int)*(NN+1);
    int*   cur  = (int*)w;   w += sizeof(int)*NN;
    int*   csrc = (int*)w;   w += sizeof(int)*NE;
    int*   bsum = (int*)w;   w += sizeof(int)*512;
    int*   bs   = (int*)w;   w += sizeof(int)*NG;
    int*   be   = (int*)w;   w += sizeof(int)*NG;
    float* cnt  = (float*)w; w += sizeof(float)*NG;
    float* ssum = (float*)w; w += sizeof(float)*NG*D;
    float* tmat = (float*)w; w += sizeof(float)*NG*D;
    float* ap   = (float*)w; w += sizeof(float)*NG*D;
    float* gx   = (float*)w; w += sizeof(float)*NG*H;
    float* hx   = (float*)w; w += sizeof(float)*NG*H;

    const int B = 256;
    const int gNH   = (NN*H + B - 1)/B;
    const int gE    = (NE + B - 1)/B;
    const int gN    = (NN + B - 1)/B;   // 391
    const int gSeg  = (NN + 63)/64;     // 1563
    const int waves = (NN + 63)/64;
    const int gCoef = (waves + 3)/4;

    auto run_side = [&](const int* ei, const int* batch, const float* feat, float* gout){
        const int* src = ei;
        const int* dst = ei + NE;
        hipMemsetAsync(deg, 0, NN*sizeof(int), stream);
        hipMemsetAsync(cur, 0, NN*sizeof(int), stream);
        hipMemsetAsync(bs,  0, NG*sizeof(int), stream);
        hipMemsetAsync(be,  0, NG*sizeof(int), stream);
        hipMemsetAsync(ssum, 0, NG*D*sizeof(float), stream);
        hipMemsetAsync(ap,   0, NG*D*sizeof(float), stream);

        // CSR build
        k_deg_count<<<gE, B, 0, stream>>>(dst, deg);
        k_blocksum<<<gN, B, 0, stream>>>(deg, bsum);
        k_scan_bsum<<<1, 512, 0, stream>>>(bsum, gN);
        k_scan_apply<<<gN, B, 0, stream>>>(deg, bsum, off);
        k_fill<<<gE, B, 0, stream>>>(src, dst, off, cur, csrc);
        k_dinv<<<gN, B, 0, stream>>>(deg, dinv);

        // batch counts
        k_bounds<<<gN, B, 0, stream>>>(batch, bs, be);
        k_cnt<<<1, NG, 0, stream>>>(bs, be, cnt);

        k_pre<<<gNH, B, 0, stream>>>(feat, preW, preb, batch, cnt, delta, f, a);

        const float* xin = f; int xs = H;
        for (int i = 0; i < 3; i++){
            k_gemm64<<<gNH, B, 0, stream>>>(xin, xs, convW + i*H*H, xw);
            float* aout = a + (i + 1)*H;
            k_conv<<<gNH, B, 0, stream>>>(off, csrc, dinv, xw, convb + i*H, xin, xs, aout, i < 2 ? 1 : 0);
            xin = aout; xs = D;
        }
        k_segsum<<<gSeg, 256, 0, stream>>>(a, batch, ssum);
        k_ctx<<<NG*D/256, 256, 0, stream>>>(ssum, attW, cnt, tmat);
        k_coef_ap<<<gCoef, 256, 0, stream>>>(a, batch, tmat, ap);
        k_mlp2<<<NG, 128, 0, stream>>>(ap, ssum, mu, pW1, pb1, pW2, pb2, gout);
    };

    run_side(ei1, bat1, feat1, gx);
    run_side(ei2, bat2, feat2, hx);
    k_final<<<NG, 64, 0, stream>>>(gx, hx, tnW, tnV, tnb, scW1, scb1, scW2, scb2, alpha, out);
}

// Round 3
// 1656.248 us; speedup vs baseline: 2.4801x; 1.1843x over previous
//
#include <hip/hip_runtime.h>
#include <math.h>

#define NN 100000
#define NE 1600000
#define NG 128
#define L 32
#define H 64
#define D 256
#define TN 16

__device__ __forceinline__ float sigm(float x){ return 1.0f/(1.0f+expf(-x)); }

// ================= CSR build =================
__global__ void k_deg_count(const int* __restrict__ dst, int* __restrict__ deg){
    int i = blockIdx.x*blockDim.x + threadIdx.x;
    if (i < NE) atomicAdd(&deg[dst[i]], 1);
}
__global__ void k_blocksum(const int* __restrict__ deg, int* __restrict__ bsum){
    __shared__ int s[256];
    int t = threadIdx.x; int i = blockIdx.x*256 + t;
    s[t] = (i < NN) ? deg[i] : 0;
    __syncthreads();
    for (int o = 128; o; o >>= 1){ if (t < o) s[t] += s[t+o]; __syncthreads(); }
    if (t == 0) bsum[blockIdx.x] = s[0];
}
__global__ void k_scan_bsum(int* __restrict__ bsum, int nb){
    __shared__ int s[512];
    int t = threadIdx.x;
    s[t] = (t < nb) ? bsum[t] : 0;
    __syncthreads();
    for (int o = 1; o < 512; o <<= 1){
        int u = (t >= o) ? s[t-o] : 0;
        __syncthreads();
        s[t] += u;
        __syncthreads();
    }
    if (t < nb) bsum[t] = (t == 0) ? 0 : s[t-1];   // exclusive block offsets
}
__global__ void k_scan_apply(const int* __restrict__ deg, const int* __restrict__ boff,
                             int* __restrict__ off){
    __shared__ int s[256];
    int t = threadIdx.x; int i = blockIdx.x*256 + t;
    int v = (i < NN) ? deg[i] : 0;
    s[t] = v;
    __syncthreads();
    for (int o = 1; o < 256; o <<= 1){
        int u = (t >= o) ? s[t-o] : 0;
        __syncthreads();
        s[t] += u;
        __syncthreads();
    }
    if (i < NN) off[i] = boff[blockIdx.x] + s[t] - v;  // exclusive prefix
    if (i == 0) off[NN] = NE;
}
__global__ void k_fill(const int* __restrict__ src, const int* __restrict__ dst,
                       const int* __restrict__ off, int* __restrict__ cur,
                       int* __restrict__ csrc){
    int e = blockIdx.x*blockDim.x + threadIdx.x;
    if (e >= NE) return;
    int d = dst[e];
    int p = atomicAdd(&cur[d], 1);
    csrc[off[d] + p] = src[e];
}
__global__ void k_dinv(const int* __restrict__ deg, float* __restrict__ dinv){
    int i = blockIdx.x*blockDim.x + threadIdx.x;
    if (i < NN) dinv[i] = rsqrtf((float)deg[i] + 1.0f);
}

// ================= batch counts =================
__global__ void k_bounds(const int* __restrict__ batch, int* __restrict__ bs, int* __restrict__ be){
    int i = blockIdx.x*blockDim.x + threadIdx.x;
    if (i >= NN) return;
    int g = batch[i];
    if (i == 0 || batch[i-1] != g) bs[g] = i;
    if (i == NN-1 || batch[i+1] != g) be[g] = i + 1;
}
__global__ void k_cnt(const int* __restrict__ bs, const int* __restrict__ be, float* __restrict__ cnt){
    int g = threadIdx.x;
    if (g < NG) cnt[g] = (float)(be[g] - bs[g]);
}

// ================= pre =================
__global__ void k_pre(const float* __restrict__ feat, const float* __restrict__ W,
                      const float* __restrict__ b, const int* __restrict__ batch,
                      const float* __restrict__ cnt, const float* __restrict__ delta,
                      float* __restrict__ f, float* __restrict__ a){
    __shared__ float Ws[L*H];
    __shared__ float bs[H];
    int tid = threadIdx.x;
    for (int i = tid; i < L*H; i += 256) Ws[i] = W[i];
    if (tid < H) bs[tid] = b[tid];
    __syncthreads();
    long idx = (long)blockIdx.x*256 + tid;
    int n = (int)(idx >> 6); int h = (int)(idx & 63);
    if (n >= NN) return;
    const float* fr = feat + (long)n*L;
    float v = bs[h];
#pragma unroll
    for (int k = 0; k < L; k++) v += fr[k]*Ws[k*H+h];
    float nrm = rsqrtf(fmaxf(cnt[batch[n]], 1.0f));
    float fv = v*nrm;
    f[(long)n*H + h] = fv;
    a[(long)n*D + h] = fv*(1.0f + delta[0]);
}

// ================= xws = (x @ W) * dinv[n]  (64x64) =================
__global__ void k_gemm64(const float* __restrict__ x, int xs,
                         const float* __restrict__ W, const float* __restrict__ dinv,
                         float* __restrict__ xws){
    __shared__ float Ws[H*H];
    int tid = threadIdx.x;
    for (int i = tid; i < H*H; i += 256) Ws[i] = W[i];
    __syncthreads();
    long idx = (long)blockIdx.x*256 + tid;
    int n = (int)(idx >> 6); int h = (int)(idx & 63);
    if (n >= NN) return;
    const float* xr = x + (long)n*xs;
    float v = 0.f;
#pragma unroll
    for (int k = 0; k < H; k++) v += xr[k]*Ws[k*H+h];
    xws[(long)n*H + h] = v*dinv[n];
}

// ================= fused CSR gather + combine =================
// y = (xws[d] + sum_e xws[src_e]) * dinv[d] + b ; optional relu+residual; store stride D
__global__ void k_conv(const int* __restrict__ off, const int* __restrict__ csrc,
                       const float* __restrict__ dinv, const float* __restrict__ xws,
                       const float* __restrict__ b, const float* __restrict__ xin, int xs,
                       float* __restrict__ aout, int relu_res){
    int wid  = (blockIdx.x*blockDim.x + threadIdx.x) >> 6;
    int lane = threadIdx.x & 63;
    if (wid >= NN) return;
    int d = wid;
    int e0 = off[d], e1 = off[d+1];
    float acc  = xws[(long)d*H + lane];   // self loop
    float acc2 = 0.f;
    for (int base = e0; base < e1; base += 64){
        int m = min(64, e1 - base);
        int idx = (base + lane < e1) ? csrc[base + lane] : 0;
        int j = 0;
        for (; j + 1 < m; j += 2){
            int s0 = __shfl(idx, j, 64);
            int s1 = __shfl(idx, j+1, 64);
            acc  += xws[(long)s0*H + lane];
            acc2 += xws[(long)s1*H + lane];
        }
        if (j < m){
            int s0 = __shfl(idx, j, 64);
            acc += xws[(long)s0*H + lane];
        }
    }
    acc += acc2;
    float y = acc*dinv[d] + b[lane];
    if (relu_res) y = fmaxf(y, 0.f) + xin[(long)d*xs + lane];
    aout[(long)d*D + lane] = y;
}

// ================= segmented sum over sorted batch =================
__global__ void k_segsum(const float* __restrict__ a, const int* __restrict__ batch,
                         float* __restrict__ s){
    int d = threadIdx.x;                 // 256 = D columns
    int n0 = blockIdx.x*64;
    if (n0 >= NN) return;
    int n1 = min(n0 + 64, NN);
    float acc = 0.f;
    int curg = batch[n0];
    for (int n = n0; n < n1; n++){
        int g = batch[n];
        if (g != curg){ atomicAdd(&s[curg*D + d], acc); acc = 0.f; curg = g; }
        acc += a[(long)n*D + d];
    }
    atomicAdd(&s[curg*D + d], acc);
}

// ================= t = tanh((s @ att_W) / max(cnt,1)) =================
__global__ void k_ctx(const float* __restrict__ s, const float* __restrict__ attW,
                      const float* __restrict__ cnt, float* __restrict__ t){
    int idx = blockIdx.x*256 + threadIdx.x;   // G*D
    int g = idx >> 8; int d = idx & 255;
    float inv = 1.0f/fmaxf(cnt[g], 1.0f);
    float v = 0.f;
    for (int k = 0; k < D; k++) v += s[g*D + k]*attW[k*D + d];
    t[idx] = tanhf(v*inv);
}

// ================= coef + attention pool (float4) =================
__global__ void k_coef_ap(const float* __restrict__ a, const int* __restrict__ batch,
                          const float* __restrict__ t, float* __restrict__ ap){
    int lane = threadIdx.x & 63;
    int wid  = (blockIdx.x*blockDim.x + threadIdx.x) >> 6;
    int n0 = wid*64;
    if (n0 >= NN) return;
    int n1 = min(n0 + 64, NN);
    float ax=0.f, ay=0.f, az=0.f, aw=0.f;
    int curg = batch[n0];
    for (int n = n0; n < n1; n++){
        int g = batch[n];
        const float4* ar = (const float4*)(a + (long)n*D);
        const float4* tr = (const float4*)(t + (long)g*D);
        float4 v = ar[lane];
        float4 tv = tr[lane];
        float part = v.x*tv.x + v.y*tv.y + v.z*tv.z + v.w*tv.w;
#pragma unroll
        for (int o = 32; o; o >>= 1) part += __shfl_xor(part, o, 64);
        float coef = sigm(part);
        if (g != curg){
            atomicAdd(&ap[curg*D + lane*4 + 0], ax);
            atomicAdd(&ap[curg*D + lane*4 + 1], ay);
            atomicAdd(&ap[curg*D + lane*4 + 2], az);
            atomicAdd(&ap[curg*D + lane*4 + 3], aw);
            ax = ay = az = aw = 0.f; curg = g;
        }
        ax += coef*v.x; ay += coef*v.y; az += coef*v.z; aw += coef*v.w;
    }
    atomicAdd(&ap[curg*D + lane*4 + 0], ax);
    atomicAdd(&ap[curg*D + lane*4 + 1], ay);
    atomicAdd(&ap[curg*D + lane*4 + 2], az);
    atomicAdd(&ap[curg*D + lane*4 + 3], aw);
}

// ================= per-graph MLP =================
__global__ void k_mlp2(const float* __restrict__ ap, const float* __restrict__ s,
                       const float* __restrict__ mu,
                       const float* __restrict__ W1, const float* __restrict__ b1,
                       const float* __restrict__ W2, const float* __restrict__ b2,
                       float* __restrict__ out){
    __shared__ float p[D];
    __shared__ float hid[128];
    int g = blockIdx.x; int tid = threadIdx.x;   // 128 threads
    for (int i = tid; i < D; i += 128){
        float m = mu[i];
        p[i] = m*ap[g*D + i] + (1.0f - m)*s[g*D + i];
    }
    __syncthreads();
    float v = b1[tid];
    for (int k = 0; k < D; k++) v += p[k]*W1[k*128 + tid];
    hid[tid] = fmaxf(v, 0.f);
    __syncthreads();
    if (tid < H){
        float o = b2[tid];
        for (int k = 0; k < 128; k++) o += hid[k]*W2[k*H + tid];
        out[g*H + tid] = o;
    }
}

// ================= NTN stage 1: M[g, e*16+k] = sum_d gx[g,d] * tnW[d, e*16+k] =================
__global__ void k_ntn(const float* __restrict__ gx, const float* __restrict__ tnW,
                      float* __restrict__ M){
    __shared__ float sgx[H];
    int b = blockIdx.x;                 // 512 blocks: g = b>>2, quarter = b&3
    int g = b >> 2;
    int ek = (b & 3)*256 + threadIdx.x; // 0..1023
    if (threadIdx.x < H) sgx[threadIdx.x] = gx[g*H + threadIdx.x];
    __syncthreads();
    float v = 0.f;
#pragma unroll 8
    for (int d = 0; d < H; d++) v += sgx[d]*tnW[d*(H*TN) + ek];
    M[g*(H*TN) + ek] = v;
}

// ================= final: t1 contraction + scoring =================
__global__ void k_final(const float* __restrict__ gx, const float* __restrict__ hx,
                        const float* __restrict__ M, const float* __restrict__ tnV,
                        const float* __restrict__ tnb,
                        const float* __restrict__ scW1, const float* __restrict__ scb1,
                        const float* __restrict__ scW2, const float* __restrict__ scb2,
                        const float* __restrict__ alpha, float* __restrict__ outp){
    __shared__ float sg[H], sh[H], sc[TN], h2[TN];
    int g = blockIdx.x; int lane = threadIdx.x;  // 64 threads, lane = e
    float gv = gx[g*H + lane], hv = hx[g*H + lane];
    sg[lane] = gv; sh[lane] = hv;
    __syncthreads();
    const float* Mg = M + g*(H*TN) + lane*TN;
    float myt1 = 0.f;
#pragma unroll
    for (int k = 0; k < TN; k++){
        float part = Mg[k]*hv;           // M[g, lane, k] * hx[g, lane]
#pragma unroll
        for (int o = 32; o; o >>= 1) part += __shfl_xor(part, o, 64);
        if (lane == k) myt1 = part;
    }
    if (lane < TN){
        float t2 = tnb[lane];
        for (int d = 0; d < H; d++) t2 += sg[d]*tnV[lane*128 + d];
        for (int e = 0; e < H; e++) t2 += sh[e]*tnV[lane*128 + 64 + e];
        sc[lane] = fmaxf(myt1 + t2, 0.f);
    }
    __syncthreads();
    if (lane < TN){
        float v = scb1[lane];
        for (int j = 0; j < TN; j++) v += sc[j]*scW1[j*TN + lane];
        h2[lane] = fmaxf(v, 0.f);
    }
    __syncthreads();
    float dff = gv - hv;
    float ssq = dff*dff;
#pragma unroll
    for (int o = 32; o; o >>= 1) ssq += __shfl_xor(ssq, o, 64);
    if (lane == 0){
        float score = scb2[0];
        for (int j = 0; j < TN; j++) score += h2[j]*scW2[j];
        float l2 = sqrtf(ssq);
        float al = alpha[0];
        outp[g] = al*sigm(score) + (1.0f - al)*(1.0f/(1.0f + expf(l2)));
    }
}

extern "C" void kernel_launch(void* const* d_in, const int* in_sizes, int n_in,
                              void* d_out, int out_size, void* d_ws, size_t ws_size,
                              hipStream_t stream) {
    const int*   ei1   = (const int*)d_in[0];
    const int*   ei2   = (const int*)d_in[1];
    const int*   bat1  = (const int*)d_in[2];
    const int*   bat2  = (const int*)d_in[3];
    const float* feat1 = (const float*)d_in[4];
    const float* feat2 = (const float*)d_in[5];
    const float* preW  = (const float*)d_in[6];
    const float* preb  = (const float*)d_in[7];
    const float* convW = (const float*)d_in[8];
    const float* convb = (const float*)d_in[9];
    const float* delta = (const float*)d_in[10];
    const float* alpha = (const float*)d_in[11];
    const float* mu    = (const float*)d_in[12];
    const float* attW  = (const float*)d_in[13];
    const float* pW1   = (const float*)d_in[14];
    const float* pb1   = (const float*)d_in[15];
    const float* pW2   = (const float*)d_in[16];
    const float* pb2   = (const float*)d_in[17];
    const float* tnW   = (const float*)d_in[18];
    const float* tnV   = (const float*)d_in[19];
    const float* tnb   = (const float*)d_in[20];
    const float* scW1  = (const float*)d_in[21];
    const float* scb1  = (const float*)d_in[22];
    const float* scW2  = (const float*)d_in[23];
    const float* scb2  = (const float*)d_in[24];
    float* out = (float*)d_out;

    // workspace carve
    char* w = (char*)d_ws;
    float* a    = (float*)w; w += sizeof(float)*(size_t)NN*D;
    float* f    = (float*)w; w += sizeof(float)*(size_t)NN*H;
    float* xws  = (float*)w; w += sizeof(float)*(size_t)NN*H;
    float* dinv = (float*)w; w += sizeof(float)*NN;
    int*   deg  = (int*)w;   w += sizeof(int)*NN;
    int*   off  = (int*)w;   w += sizeof(int)*(NN+1);
    int*   cur  = (int*)w;   w += sizeof(int)*NN;
    int*   csrc = (int*)w;   w += sizeof(int)*NE;
    int*   bsum = (int*)w;   w += sizeof(int)*512;
    int*   bs   = (int*)w;   w += sizeof(int)*NG;
    int*   be   = (int*)w;   w += sizeof(int)*NG;
    float* cnt  = (float*)w; w += sizeof(float)*NG;
    float* ssum = (float*)w; w += sizeof(float)*NG*D;
    float* tmat = (float*)w; w += sizeof(float)*NG*D;
    float* ap   = (float*)w; w += sizeof(float)*NG*D;
    float* gx   = (float*)w; w += sizeof(float)*NG*H;
    float* hx   = (float*)w; w += sizeof(float)*NG*H;
    float* M    = (float*)w; w += sizeof(float)*NG*H*TN;

    const int B = 256;
    const int gNH   = (NN*H + B - 1)/B;
    const int gE    = (NE + B - 1)/B;
    const int gN    = (NN + B - 1)/B;   // 391
    const int gSeg  = (NN + 63)/64;     // 1563
    const int waves = (NN + 63)/64;
    const int gCoef = (waves + 3)/4;

    auto run_side = [&](const int* ei, const int* batch, const float* feat, float* gout){
        const int* src = ei;
        const int* dst = ei + NE;
        hipMemsetAsync(deg, 0, NN*sizeof(int), stream);
        hipMemsetAsync(cur, 0, NN*sizeof(int), stream);
        hipMemsetAsync(ssum, 0, NG*D*sizeof(float), stream);
        hipMemsetAsync(ap,   0, NG*D*sizeof(float), stream);

        // CSR build
        k_deg_count<<<gE, B, 0, stream>>>(dst, deg);
        k_blocksum<<<gN, B, 0, stream>>>(deg, bsum);
        k_scan_bsum<<<1, 512, 0, stream>>>(bsum, gN);
        k_scan_apply<<<gN, B, 0, stream>>>(deg, bsum, off);
        k_fill<<<gE, B, 0, stream>>>(src, dst, off, cur, csrc);
        k_dinv<<<gN, B, 0, stream>>>(deg, dinv);

        // batch counts
        k_bounds<<<gN, B, 0, stream>>>(batch, bs, be);
        k_cnt<<<1, NG, 0, stream>>>(bs, be, cnt);

        k_pre<<<gNH, B, 0, stream>>>(feat, preW, preb, batch, cnt, delta, f, a);

        const float* xin = f; int xs = H;
        for (int i = 0; i < 3; i++){
            k_gemm64<<<gNH, B, 0, stream>>>(xin, xs, convW + i*H*H, dinv, xws);
            float* aout = a + (i + 1)*H;
            k_conv<<<gNH, B, 0, stream>>>(off, csrc, dinv, xws, convb + i*H, xin, xs, aout, i < 2 ? 1 : 0);
            xin = aout; xs = D;
        }
        k_segsum<<<gSeg, 256, 0, stream>>>(a, batch, ssum);
        k_ctx<<<NG*D/256, 256, 0, stream>>>(ssum, attW, cnt, tmat);
        k_coef_ap<<<gCoef, 256, 0, stream>>>(a, batch, tmat, ap);
        k_mlp2<<<NG, 128, 0, stream>>>(ap, ssum, mu, pW1, pb1, pW2, pb2, gout);
    };

    run_side(ei1, bat1, feat1, gx);
    run_side(ei2, bat2, feat2, hx);
    k_ntn<<<NG*4, 256, 0, stream>>>(gx, tnW, M);
    k_final<<<NG, 64, 0, stream>>>(gx, hx, M, tnV, tnb, scW1, scb1, scW2, scb2, alpha, out);
}

// Round 4
// 1333.249 us; speedup vs baseline: 3.0810x; 1.2423x over previous
//
#include <hip/hip_runtime.h>
#include <math.h>

#define NN 100000
#define NE 1600000
#define NG 128
#define L 32
#define H 64
#define D 256
#define TN 16

__device__ __forceinline__ float sigm(float x){ return 1.0f/(1.0f+expf(-x)); }

// ================= bounds + zero-init (replaces memsets + k_cnt) =================
__global__ void k_bounds(const int* __restrict__ batch, int* __restrict__ bs, int* __restrict__ be,
                         int* __restrict__ deg, float* __restrict__ ssum, float* __restrict__ ap){
    int i = blockIdx.x*blockDim.x + threadIdx.x;
    if (i < NG*D){ ssum[i] = 0.f; ap[i] = 0.f; }
    if (i >= NN) return;
    deg[i] = 0;
    int g = batch[i];
    if (i == 0 || batch[i-1] != g) bs[g] = i;
    if (i == NN-1 || batch[i+1] != g) be[g] = i + 1;
}

// ================= degree count + per-edge rank =================
__global__ void k_deg(const int* __restrict__ dst, int* __restrict__ deg, int* __restrict__ rank){
    int i = blockIdx.x*blockDim.x + threadIdx.x;
    if (i < NE) rank[i] = atomicAdd(&deg[dst[i]], 1);
}

// ================= scan =================
__global__ void k_blocksum(const int* __restrict__ deg, int* __restrict__ bsum){
    __shared__ int s[256];
    int t = threadIdx.x; int i = blockIdx.x*256 + t;
    s[t] = (i < NN) ? deg[i] : 0;
    __syncthreads();
    for (int o = 128; o; o >>= 1){ if (t < o) s[t] += s[t+o]; __syncthreads(); }
    if (t == 0) bsum[blockIdx.x] = s[0];
}
__global__ void k_scan_bsum(int* __restrict__ bsum, int nb){
    __shared__ int s[512];
    int t = threadIdx.x;
    s[t] = (t < nb) ? bsum[t] : 0;
    __syncthreads();
    for (int o = 1; o < 512; o <<= 1){
        int u = (t >= o) ? s[t-o] : 0;
        __syncthreads();
        s[t] += u;
        __syncthreads();
    }
    if (t < nb) bsum[t] = (t == 0) ? 0 : s[t-1];
}
__global__ void k_scan_apply(const int* __restrict__ deg, const int* __restrict__ boff,
                             int* __restrict__ off, float* __restrict__ dinv){
    __shared__ int s[256];
    int t = threadIdx.x; int i = blockIdx.x*256 + t;
    int v = (i < NN) ? deg[i] : 0;
    s[t] = v;
    __syncthreads();
    for (int o = 1; o < 256; o <<= 1){
        int u = (t >= o) ? s[t-o] : 0;
        __syncthreads();
        s[t] += u;
        __syncthreads();
    }
    if (i < NN){
        off[i] = boff[blockIdx.x] + s[t] - v;
        dinv[i] = rsqrtf((float)v + 1.0f);
    }
    if (i == 0) off[NN] = NE;
}
__global__ void k_fill(const int* __restrict__ src, const int* __restrict__ dst,
                       const int* __restrict__ rank, const int* __restrict__ off,
                       int* __restrict__ csrc){
    int e = blockIdx.x*blockDim.x + threadIdx.x;
    if (e >= NE) return;
    csrc[off[dst[e]] + rank[e]] = src[e];
}

// ================= pre: f = (feat@W + b)*rsqrt(cnt)[batch]; a[:,0:64] = f*(1+delta) =================
__global__ void k_pre(const float* __restrict__ feat, const float* __restrict__ W,
                      const float* __restrict__ b, const int* __restrict__ batch,
                      const int* __restrict__ bs, const int* __restrict__ be,
                      const float* __restrict__ delta,
                      float* __restrict__ f, float* __restrict__ a){
    __shared__ float Ws[L*H];
    __shared__ float bsh[H];
    int tid = threadIdx.x;
    for (int i = tid; i < L*H; i += 256) Ws[i] = W[i];
    if (tid < H) bsh[tid] = b[tid];
    __syncthreads();
    long idx = (long)blockIdx.x*256 + tid;
    int n = (int)(idx >> 6); int h = (int)(idx & 63);
    if (n >= NN) return;
    int lane = tid & 63;
    float xv = (lane < L) ? feat[(long)n*L + lane] : 0.f;
    float v = bsh[h];
#pragma unroll
    for (int k = 0; k < L; k++) v += __shfl(xv, k, 64)*Ws[k*H+h];
    int g = batch[n];
    float nrm = rsqrtf(fmaxf((float)(be[g] - bs[g]), 1.0f));
    float fv = v*nrm;
    f[(long)n*H + h] = fv;
    a[(long)n*D + h] = fv*(1.0f + delta[0]);
}

// ================= xws = (x @ W) * dinv : 64-node tile, 4x4 register blocking =================
__global__ __launch_bounds__(256) void k_gemm64(const float* __restrict__ x, int xs,
                         const float* __restrict__ W, const float* __restrict__ dinv,
                         float* __restrict__ xws){
    __shared__ float Xl[64*65];
    __shared__ float Wl[64*64];
    int t = threadIdx.x;
    int n0 = blockIdx.x*64;
    {   // load W (4096 floats), coalesced float4
        const float4* Wg = (const float4*)W;
        float4* Ws4 = (float4*)Wl;
#pragma unroll
        for (int j = 0; j < 4; j++) Ws4[t + j*256] = Wg[t + j*256];
    }
    int r = t & 15, ig = t >> 4;
    // stage X rows (cols 0..63), padded stride 65
#pragma unroll
    for (int p = 0; p < 4; p++){
        int i = p*16 + ig;
        int n = n0 + i;
        float4 v = {0.f,0.f,0.f,0.f};
        if (n < NN) v = *(const float4*)(x + (long)n*xs + r*4);
        Xl[i*65 + r*4 + 0] = v.x;
        Xl[i*65 + r*4 + 1] = v.y;
        Xl[i*65 + r*4 + 2] = v.z;
        Xl[i*65 + r*4 + 3] = v.w;
    }
    __syncthreads();
    float4 a0={0,0,0,0}, a1={0,0,0,0}, a2={0,0,0,0}, a3={0,0,0,0};
    const float4* Wl4 = (const float4*)Wl;
#pragma unroll
    for (int k = 0; k < 64; k++){
        float4 w = Wl4[k*16 + r];
        float x0 = Xl[(ig*4+0)*65 + k];
        float x1 = Xl[(ig*4+1)*65 + k];
        float x2 = Xl[(ig*4+2)*65 + k];
        float x3 = Xl[(ig*4+3)*65 + k];
        a0.x += x0*w.x; a0.y += x0*w.y; a0.z += x0*w.z; a0.w += x0*w.w;
        a1.x += x1*w.x; a1.y += x1*w.y; a1.z += x1*w.z; a1.w += x1*w.w;
        a2.x += x2*w.x; a2.y += x2*w.y; a2.z += x2*w.z; a2.w += x2*w.w;
        a3.x += x3*w.x; a3.y += x3*w.y; a3.z += x3*w.z; a3.w += x3*w.w;
    }
    float4 accs[4] = {a0, a1, a2, a3};
#pragma unroll
    for (int c = 0; c < 4; c++){
        int n = n0 + ig*4 + c;
        if (n < NN){
            float di = dinv[n];
            float4 o; o.x = accs[c].x*di; o.y = accs[c].y*di; o.z = accs[c].z*di; o.w = accs[c].w*di;
            ((float4*)(xws + (long)n*H))[r] = o;
        }
    }
}

// ================= fused CSR gather + combine (4-edge-parallel float4) =================
__global__ void k_conv(const int* __restrict__ off, const int* __restrict__ csrc,
                       const float* __restrict__ dinv, const float* __restrict__ xws,
                       const float* __restrict__ b, const float* __restrict__ xin, int xs,
                       float* __restrict__ aout, int relu_res){
    int wid  = (blockIdx.x*blockDim.x + threadIdx.x) >> 6;
    int lane = threadIdx.x & 63;
    if (wid >= NN) return;
    int q = lane >> 4, r = lane & 15;
    int d = wid;
    int e0 = off[d], e1 = off[d+1];
    const float4* X = (const float4*)xws;
    float4 acc = {0.f,0.f,0.f,0.f};
    for (int base = e0; base < e1; base += 64){
        int m = min(64, e1 - base);
        int idx = (base + lane < e1) ? csrc[base + lane] : 0;
        for (int j = 0; j < m; j += 4){
            int jq = j + q;
            int s = __shfl(idx, jq, 64);
            if (jq < m){
                float4 v = X[(long)s*16 + r];
                acc.x += v.x; acc.y += v.y; acc.z += v.z; acc.w += v.w;
            }
        }
    }
    // reduce across the 4 quarters
    acc.x += __shfl_xor(acc.x, 16, 64); acc.x += __shfl_xor(acc.x, 32, 64);
    acc.y += __shfl_xor(acc.y, 16, 64); acc.y += __shfl_xor(acc.y, 32, 64);
    acc.z += __shfl_xor(acc.z, 16, 64); acc.z += __shfl_xor(acc.z, 32, 64);
    acc.w += __shfl_xor(acc.w, 16, 64); acc.w += __shfl_xor(acc.w, 32, 64);
    float4 self = X[(long)d*16 + r];
    float di = dinv[d];
    float4 b4 = ((const float4*)b)[r];
    float4 y;
    y.x = (acc.x + self.x)*di + b4.x;
    y.y = (acc.y + self.y)*di + b4.y;
    y.z = (acc.z + self.z)*di + b4.z;
    y.w = (acc.w + self.w)*di + b4.w;
    if (relu_res){
        float4 xi = *(const float4*)(xin + (long)d*xs + r*4);
        y.x = fmaxf(y.x, 0.f) + xi.x;
        y.y = fmaxf(y.y, 0.f) + xi.y;
        y.z = fmaxf(y.z, 0.f) + xi.z;
        y.w = fmaxf(y.w, 0.f) + xi.w;
    }
    if (q == 0) ((float4*)(aout + (long)d*D))[r] = y;
}

// ================= segmented sum over sorted batch =================
__global__ void k_segsum(const float* __restrict__ a, const int* __restrict__ batch,
                         float* __restrict__ s){
    int d = threadIdx.x;                 // 256 = D columns
    int n0 = blockIdx.x*64;
    if (n0 >= NN) return;
    int n1 = min(n0 + 64, NN);
    float acc = 0.f;
    int curg = batch[n0];
    for (int n = n0; n < n1; n++){
        int g = batch[n];
        if (g != curg){ atomicAdd(&s[curg*D + d], acc); acc = 0.f; curg = g; }
        acc += a[(long)n*D + d];
    }
    atomicAdd(&s[curg*D + d], acc);
}

// ================= t = tanh((s @ att_W) / max(cnt,1)) =================
__global__ void k_ctx(const float* __restrict__ s, const float* __restrict__ attW,
                      const int* __restrict__ bs, const int* __restrict__ be,
                      float* __restrict__ t){
    int idx = blockIdx.x*256 + threadIdx.x;   // G*D
    int g = idx >> 8; int d = idx & 255;
    float inv = 1.0f/fmaxf((float)(be[g] - bs[g]), 1.0f);
    float v = 0.f;
    for (int k = 0; k < D; k++) v += s[g*D + k]*attW[k*D + d];
    t[idx] = tanhf(v*inv);
}

// ================= coef + attention pool (float4) =================
__global__ void k_coef_ap(const float* __restrict__ a, const int* __restrict__ batch,
                          const float* __restrict__ t, float* __restrict__ ap){
    int lane = threadIdx.x & 63;
    int wid  = (blockIdx.x*blockDim.x + threadIdx.x) >> 6;
    int n0 = wid*64;
    if (n0 >= NN) return;
    int n1 = min(n0 + 64, NN);
    float ax=0.f, ay=0.f, az=0.f, aw=0.f;
    int curg = batch[n0];
    for (int n = n0; n < n1; n++){
        int g = batch[n];
        const float4* ar = (const float4*)(a + (long)n*D);
        const float4* tr = (const float4*)(t + (long)g*D);
        float4 v = ar[lane];
        float4 tv = tr[lane];
        float part = v.x*tv.x + v.y*tv.y + v.z*tv.z + v.w*tv.w;
#pragma unroll
        for (int o = 32; o; o >>= 1) part += __shfl_xor(part, o, 64);
        float coef = sigm(part);
        if (g != curg){
            atomicAdd(&ap[curg*D + lane*4 + 0], ax);
            atomicAdd(&ap[curg*D + lane*4 + 1], ay);
            atomicAdd(&ap[curg*D + lane*4 + 2], az);
            atomicAdd(&ap[curg*D + lane*4 + 3], aw);
            ax = ay = az = aw = 0.f; curg = g;
        }
        ax += coef*v.x; ay += coef*v.y; az += coef*v.z; aw += coef*v.w;
    }
    atomicAdd(&ap[curg*D + lane*4 + 0], ax);
    atomicAdd(&ap[curg*D + lane*4 + 1], ay);
    atomicAdd(&ap[curg*D + lane*4 + 2], az);
    atomicAdd(&ap[curg*D + lane*4 + 3], aw);
}

// ================= per-graph MLP =================
__global__ void k_mlp2(const float* __restrict__ ap, const float* __restrict__ s,
                       const float* __restrict__ mu,
                       const float* __restrict__ W1, const float* __restrict__ b1,
                       const float* __restrict__ W2, const float* __restrict__ b2,
                       float* __restrict__ out){
    __shared__ float p[D];
    __shared__ float hid[128];
    int g = blockIdx.x; int tid = threadIdx.x;   // 128 threads
    for (int i = tid; i < D; i += 128){
        float m = mu[i];
        p[i] = m*ap[g*D + i] + (1.0f - m)*s[g*D + i];
    }
    __syncthreads();
    float v = b1[tid];
    for (int k = 0; k < D; k++) v += p[k]*W1[k*128 + tid];
    hid[tid] = fmaxf(v, 0.f);
    __syncthreads();
    if (tid < H){
        float o = b2[tid];
        for (int k = 0; k < 128; k++) o += hid[k]*W2[k*H + tid];
        out[g*H + tid] = o;
    }
}

// ================= NTN stage 1: M[g, e*16+k] = sum_d gx[g,d]*tnW[d, e*16+k] =================
__global__ void k_ntn(const float* __restrict__ gx, const float* __restrict__ tnW,
                      float* __restrict__ M){
    __shared__ float sgx[H];
    int b = blockIdx.x;
    int g = b >> 2;
    int ek = (b & 3)*256 + threadIdx.x;
    if (threadIdx.x < H) sgx[threadIdx.x] = gx[g*H + threadIdx.x];
    __syncthreads();
    float v = 0.f;
#pragma unroll 8
    for (int d = 0; d < H; d++) v += sgx[d]*tnW[d*(H*TN) + ek];
    M[g*(H*TN) + ek] = v;
}

// ================= final scoring =================
__global__ void k_final(const float* __restrict__ gx, const float* __restrict__ hx,
                        const float* __restrict__ M, const float* __restrict__ tnV,
                        const float* __restrict__ tnb,
                        const float* __restrict__ scW1, const float* __restrict__ scb1,
                        const float* __restrict__ scW2, const float* __restrict__ scb2,
                        const float* __restrict__ alpha, float* __restrict__ outp){
    __shared__ float sg[H], sh[H], sc[TN], h2[TN];
    int g = blockIdx.x; int lane = threadIdx.x;  // 64 threads
    float gv = gx[g*H + lane], hv = hx[g*H + lane];
    sg[lane] = gv; sh[lane] = hv;
    __syncthreads();
    const float* Mg = M + g*(H*TN) + lane*TN;
    float myt1 = 0.f;
#pragma unroll
    for (int k = 0; k < TN; k++){
        float part = Mg[k]*hv;
#pragma unroll
        for (int o = 32; o; o >>= 1) part += __shfl_xor(part, o, 64);
        if (lane == k) myt1 = part;
    }
    if (lane < TN){
        float t2 = tnb[lane];
        for (int d = 0; d < H; d++) t2 += sg[d]*tnV[lane*128 + d];
        for (int e = 0; e < H; e++) t2 += sh[e]*tnV[lane*128 + 64 + e];
        sc[lane] = fmaxf(myt1 + t2, 0.f);
    }
    __syncthreads();
    if (lane < TN){
        float v = scb1[lane];
        for (int j = 0; j < TN; j++) v += sc[j]*scW1[j*TN + lane];
        h2[lane] = fmaxf(v, 0.f);
    }
    __syncthreads();
    float dff = gv - hv;
    float ssq = dff*dff;
#pragma unroll
    for (int o = 32; o; o >>= 1) ssq += __shfl_xor(ssq, o, 64);
    if (lane == 0){
        float score = scb2[0];
        for (int j = 0; j < TN; j++) score += h2[j]*scW2[j];
        float l2 = sqrtf(ssq);
        float al = alpha[0];
        outp[g] = al*sigm(score) + (1.0f - al)*(1.0f/(1.0f + expf(l2)));
    }
}

extern "C" void kernel_launch(void* const* d_in, const int* in_sizes, int n_in,
                              void* d_out, int out_size, void* d_ws, size_t ws_size,
                              hipStream_t stream) {
    const int*   ei1   = (const int*)d_in[0];
    const int*   ei2   = (const int*)d_in[1];
    const int*   bat1  = (const int*)d_in[2];
    const int*   bat2  = (const int*)d_in[3];
    const float* feat1 = (const float*)d_in[4];
    const float* feat2 = (const float*)d_in[5];
    const float* preW  = (const float*)d_in[6];
    const float* preb  = (const float*)d_in[7];
    const float* convW = (const float*)d_in[8];
    const float* convb = (const float*)d_in[9];
    const float* delta = (const float*)d_in[10];
    const float* alpha = (const float*)d_in[11];
    const float* mu    = (const float*)d_in[12];
    const float* attW  = (const float*)d_in[13];
    const float* pW1   = (const float*)d_in[14];
    const float* pb1   = (const float*)d_in[15];
    const float* pW2   = (const float*)d_in[16];
    const float* pb2   = (const float*)d_in[17];
    const float* tnW   = (const float*)d_in[18];
    const float* tnV   = (const float*)d_in[19];
    const float* tnb   = (const float*)d_in[20];
    const float* scW1  = (const float*)d_in[21];
    const float* scb1  = (const float*)d_in[22];
    const float* scW2  = (const float*)d_in[23];
    const float* scb2  = (const float*)d_in[24];
    float* out = (float*)d_out;

    // workspace carve (all chunks 16 B aligned)
    char* w = (char*)d_ws;
    float* a    = (float*)w; w += sizeof(float)*(size_t)NN*D;
    float* f    = (float*)w; w += sizeof(float)*(size_t)NN*H;
    float* xws  = (float*)w; w += sizeof(float)*(size_t)NN*H;
    float* dinv = (float*)w; w += sizeof(float)*NN;
    int*   deg  = (int*)w;   w += sizeof(int)*NN;
    int*   rank = (int*)w;   w += sizeof(int)*NE;
    int*   off  = (int*)w;   w += sizeof(int)*(NN+4);
    int*   csrc = (int*)w;   w += sizeof(int)*NE;
    int*   bsum = (int*)w;   w += sizeof(int)*512;
    int*   bs   = (int*)w;   w += sizeof(int)*NG;
    int*   be   = (int*)w;   w += sizeof(int)*NG;
    float* ssum = (float*)w; w += sizeof(float)*NG*D;
    float* tmat = (float*)w; w += sizeof(float)*NG*D;
    float* ap   = (float*)w; w += sizeof(float)*NG*D;
    float* gx   = (float*)w; w += sizeof(float)*NG*H;
    float* hx   = (float*)w; w += sizeof(float)*NG*H;
    float* M    = (float*)w; w += sizeof(float)*NG*H*TN;

    const int B = 256;
    const int gNH   = (NN*H + B - 1)/B;   // 25000
    const int gE    = (NE + B - 1)/B;     // 6250
    const int gN    = (NN + B - 1)/B;     // 391
    const int gT    = (NN + 63)/64;       // 1563 (gemm tiles / segsum blocks)
    const int gCoef = (gT + 3)/4;         // 391

    auto run_side = [&](const int* ei, const int* batch, const float* feat, float* gout){
        const int* src = ei;
        const int* dst = ei + NE;
        k_bounds<<<gN, B, 0, stream>>>(batch, bs, be, deg, ssum, ap);
        k_deg<<<gE, B, 0, stream>>>(dst, deg, rank);
        k_blocksum<<<gN, B, 0, stream>>>(deg, bsum);
        k_scan_bsum<<<1, 512, 0, stream>>>(bsum, gN);
        k_scan_apply<<<gN, B, 0, stream>>>(deg, bsum, off, dinv);
        k_fill<<<gE, B, 0, stream>>>(src, dst, rank, off, csrc);

        k_pre<<<gNH, B, 0, stream>>>(feat, preW, preb, batch, bs, be, delta, f, a);

        const float* xin = f; int xs = H;
        for (int i = 0; i < 3; i++){
            k_gemm64<<<gT, B, 0, stream>>>(xin, xs, convW + i*H*H, dinv, xws);
            float* aout = a + (i + 1)*H;
            k_conv<<<gNH, B, 0, stream>>>(off, csrc, dinv, xws, convb + i*H, xin, xs, aout, i < 2 ? 1 : 0);
            xin = aout; xs = D;
        }
        k_segsum<<<gT, 256, 0, stream>>>(a, batch, ssum);
        k_ctx<<<NG*D/256, 256, 0, stream>>>(ssum, attW, bs, be, tmat);
        k_coef_ap<<<gCoef, 256, 0, stream>>>(a, batch, tmat, ap);
        k_mlp2<<<NG, 128, 0, stream>>>(ap, ssum, mu, pW1, pb1, pW2, pb2, gout);
    };

    run_side(ei1, bat1, feat1, gx);
    run_side(ei2, bat2, feat2, hx);
    k_ntn<<<NG*4, 256, 0, stream>>>(gx, tnW, M);
    k_final<<<NG, 64, 0, stream>>>(gx, hx, M, tnV, tnb, scW1, scb1, scW2, scb2, alpha, out);
}

// Round 5
// 1326.800 us; speedup vs baseline: 3.0959x; 1.0049x over previous
//
#include <hip/hip_runtime.h>
#include <math.h>

#define NN 100000
#define NE 1600000
#define NG 128
#define L 32
#define H 64
#define D 256
#define TN 16

typedef unsigned short u16;

__device__ __forceinline__ float sigm(float x){ return 1.0f/(1.0f+expf(-x)); }
__device__ __forceinline__ float bf2f(u16 x){ return __uint_as_float(((unsigned)x)<<16); }
__device__ __forceinline__ u16 f2bf(float f){
    unsigned u = __float_as_uint(f);
    unsigned r = u + 0x7fffu + ((u>>16)&1u);
    return (u16)(r>>16);
}

// ================= bounds + deg zero =================
__global__ void k_bounds(const int* __restrict__ batch, int* __restrict__ bs, int* __restrict__ be,
                         int* __restrict__ deg){
    int i = blockIdx.x*blockDim.x + threadIdx.x;
    if (i >= NN) return;
    deg[i] = 0;
    int g = batch[i];
    if (i == 0 || batch[i-1] != g) bs[g] = i;
    if (i == NN-1 || batch[i+1] != g) be[g] = i + 1;
}

// ================= degree count + per-edge rank =================
__global__ void k_deg(const int* __restrict__ dst, int* __restrict__ deg, int* __restrict__ rank){
    int i = blockIdx.x*blockDim.x + threadIdx.x;
    if (i < NE) rank[i] = atomicAdd(&deg[dst[i]], 1);
}

// ================= scan =================
__global__ void k_blocksum(const int* __restrict__ deg, int* __restrict__ bsum){
    __shared__ int s[256];
    int t = threadIdx.x; int i = blockIdx.x*256 + t;
    s[t] = (i < NN) ? deg[i] : 0;
    __syncthreads();
    for (int o = 128; o; o >>= 1){ if (t < o) s[t] += s[t+o]; __syncthreads(); }
    if (t == 0) bsum[blockIdx.x] = s[0];
}
__global__ void k_scan_bsum(int* __restrict__ bsum, int nb){
    __shared__ int s[512];
    int t = threadIdx.x;
    s[t] = (t < nb) ? bsum[t] : 0;
    __syncthreads();
    for (int o = 1; o < 512; o <<= 1){
        int u = (t >= o) ? s[t-o] : 0;
        __syncthreads();
        s[t] += u;
        __syncthreads();
    }
    if (t < nb) bsum[t] = (t == 0) ? 0 : s[t-1];
}
__global__ void k_scan_apply(const int* __restrict__ deg, const int* __restrict__ boff,
                             int* __restrict__ off, float* __restrict__ dinv){
    __shared__ int s[256];
    int t = threadIdx.x; int i = blockIdx.x*256 + t;
    int v = (i < NN) ? deg[i] : 0;
    s[t] = v;
    __syncthreads();
    for (int o = 1; o < 256; o <<= 1){
        int u = (t >= o) ? s[t-o] : 0;
        __syncthreads();
        s[t] += u;
        __syncthreads();
    }
    if (i < NN){
        off[i] = boff[blockIdx.x] + s[t] - v;
        dinv[i] = rsqrtf((float)v + 1.0f);
    }
    if (i == 0) off[NN] = NE;
}
__global__ void k_fill(const int* __restrict__ src, const int* __restrict__ dst,
                       const int* __restrict__ rank, const int* __restrict__ off,
                       int* __restrict__ csrc){
    int e = blockIdx.x*blockDim.x + threadIdx.x;
    if (e >= NE) return;
    csrc[off[dst[e]] + rank[e]] = src[e];
}

// ================= pre =================
__global__ void k_pre(const float* __restrict__ feat, const float* __restrict__ W,
                      const float* __restrict__ b, const int* __restrict__ batch,
                      const int* __restrict__ bs, const int* __restrict__ be,
                      const float* __restrict__ delta,
                      float* __restrict__ f, float* __restrict__ a){
    __shared__ float Ws[L*H];
    __shared__ float bsh[H];
    int tid = threadIdx.x;
    for (int i = tid; i < L*H; i += 256) Ws[i] = W[i];
    if (tid < H) bsh[tid] = b[tid];
    __syncthreads();
    long idx = (long)blockIdx.x*256 + tid;
    int n = (int)(idx >> 6); int h = (int)(idx & 63);
    if (n >= NN) return;
    int lane = tid & 63;
    float xv = (lane < L) ? feat[(long)n*L + lane] : 0.f;
    float v = bsh[h];
#pragma unroll
    for (int k = 0; k < L; k++) v += __shfl(xv, k, 64)*Ws[k*H+h];
    int g = batch[n];
    float nrm = rsqrtf(fmaxf((float)(be[g] - bs[g]), 1.0f));
    float fv = v*nrm;
    f[(long)n*H + h] = fv;
    a[(long)n*D + h] = fv*(1.0f + delta[0]);
}

// ================= xws_bf16 = bf16((x @ W) * dinv) : 64-node tile =================
__global__ __launch_bounds__(256) void k_gemm64(const float* __restrict__ x, int xs,
                         const float* __restrict__ W, const float* __restrict__ dinv,
                         u16* __restrict__ xb){
    __shared__ float Xl[64*65];
    __shared__ float Wl[64*64];
    int t = threadIdx.x;
    int n0 = blockIdx.x*64;
    {
        const float4* Wg = (const float4*)W;
        float4* Ws4 = (float4*)Wl;
#pragma unroll
        for (int j = 0; j < 4; j++) Ws4[t + j*256] = Wg[t + j*256];
    }
    int r = t & 15, ig = t >> 4;
#pragma unroll
    for (int p = 0; p < 4; p++){
        int i = p*16 + ig;
        int n = n0 + i;
        float4 v = {0.f,0.f,0.f,0.f};
        if (n < NN) v = *(const float4*)(x + (long)n*xs + r*4);
        Xl[i*65 + r*4 + 0] = v.x;
        Xl[i*65 + r*4 + 1] = v.y;
        Xl[i*65 + r*4 + 2] = v.z;
        Xl[i*65 + r*4 + 3] = v.w;
    }
    __syncthreads();
    float4 a0={0,0,0,0}, a1={0,0,0,0}, a2={0,0,0,0}, a3={0,0,0,0};
    const float4* Wl4 = (const float4*)Wl;
#pragma unroll
    for (int k = 0; k < 64; k++){
        float4 w = Wl4[k*16 + r];
        float x0 = Xl[(ig*4+0)*65 + k];
        float x1 = Xl[(ig*4+1)*65 + k];
        float x2 = Xl[(ig*4+2)*65 + k];
        float x3 = Xl[(ig*4+3)*65 + k];
        a0.x += x0*w.x; a0.y += x0*w.y; a0.z += x0*w.z; a0.w += x0*w.w;
        a1.x += x1*w.x; a1.y += x1*w.y; a1.z += x1*w.z; a1.w += x1*w.w;
        a2.x += x2*w.x; a2.y += x2*w.y; a2.z += x2*w.z; a2.w += x2*w.w;
        a3.x += x3*w.x; a3.y += x3*w.y; a3.z += x3*w.z; a3.w += x3*w.w;
    }
    float4 accs[4] = {a0, a1, a2, a3};
#pragma unroll
    for (int c = 0; c < 4; c++){
        int n = n0 + ig*4 + c;
        if (n < NN){
            float di = dinv[n];
            ushort4 o;
            o.x = f2bf(accs[c].x*di);
            o.y = f2bf(accs[c].y*di);
            o.z = f2bf(accs[c].z*di);
            o.w = f2bf(accs[c].w*di);
            ((ushort4*)(xb + (long)n*H))[r] = o;
        }
    }
}

// ================= fused CSR gather + combine (bf16 rows, 4-edge-parallel) =================
__global__ void k_conv(const int* __restrict__ off, const int* __restrict__ csrc,
                       const float* __restrict__ dinv, const u16* __restrict__ xb,
                       const float* __restrict__ b, const float* __restrict__ xin, int xs,
                       float* __restrict__ aout, int relu_res){
    int wid  = (blockIdx.x*blockDim.x + threadIdx.x) >> 6;
    int lane = threadIdx.x & 63;
    if (wid >= NN) return;
    int q = lane >> 4, r = lane & 15;
    int d = wid;
    int e0 = off[d], e1 = off[d+1];
    const ushort4* X = (const ushort4*)xb;
    float4 acc = {0.f,0.f,0.f,0.f};
    for (int base = e0; base < e1; base += 64){
        int m = min(64, e1 - base);
        int idx = (base + lane < e1) ? csrc[base + lane] : 0;
        for (int j = 0; j < m; j += 4){
            int jq = j + q;
            int s = __shfl(idx, jq, 64);
            if (jq < m){
                ushort4 v = X[(long)s*16 + r];
                acc.x += bf2f(v.x); acc.y += bf2f(v.y);
                acc.z += bf2f(v.z); acc.w += bf2f(v.w);
            }
        }
    }
    acc.x += __shfl_xor(acc.x, 16, 64); acc.x += __shfl_xor(acc.x, 32, 64);
    acc.y += __shfl_xor(acc.y, 16, 64); acc.y += __shfl_xor(acc.y, 32, 64);
    acc.z += __shfl_xor(acc.z, 16, 64); acc.z += __shfl_xor(acc.z, 32, 64);
    acc.w += __shfl_xor(acc.w, 16, 64); acc.w += __shfl_xor(acc.w, 32, 64);
    ushort4 sv = X[(long)d*16 + r];
    float di = dinv[d];
    float4 b4 = ((const float4*)b)[r];
    float4 y;
    y.x = (acc.x + bf2f(sv.x))*di + b4.x;
    y.y = (acc.y + bf2f(sv.y))*di + b4.y;
    y.z = (acc.z + bf2f(sv.z))*di + b4.z;
    y.w = (acc.w + bf2f(sv.w))*di + b4.w;
    if (relu_res){
        float4 xi = *(const float4*)(xin + (long)d*xs + r*4);
        y.x = fmaxf(y.x, 0.f) + xi.x;
        y.y = fmaxf(y.y, 0.f) + xi.y;
        y.z = fmaxf(y.z, 0.f) + xi.z;
        y.w = fmaxf(y.w, 0.f) + xi.w;
    }
    if (q == 0) ((float4*)(aout + (long)d*D))[r] = y;
}

// ================= fused pooling tail: segsum + ctx + coef/attn-pool + mu-mix + post-MLP =================
// one block per graph; graph rows are contiguous (sorted batch)
__global__ __launch_bounds__(256) void k_pool(const float* __restrict__ a,
                       const int* __restrict__ bs, const int* __restrict__ be,
                       const float* __restrict__ attW, const float* __restrict__ mu,
                       const float* __restrict__ W1, const float* __restrict__ b1,
                       const float* __restrict__ W2, const float* __restrict__ b2,
                       float* __restrict__ out){
    __shared__ float sS[D];       // segment sum
    __shared__ float sT[D];       // tanh context
    __shared__ float sAP[4][D];   // per-wave attention-pool partials
    __shared__ float sP[D];
    __shared__ float sHid[128];
    int g = blockIdx.x;
    int tid = threadIdx.x;        // 256
    int n0 = bs[g], n1 = be[g];

    // ---- pass 1: column sums (4-way unroll for MLP) ----
    float c0=0.f, c1=0.f, c2=0.f, c3=0.f;
    int n = n0;
    for (; n + 3 < n1; n += 4){
        c0 += a[(long)n*D + tid];
        c1 += a[(long)(n+1)*D + tid];
        c2 += a[(long)(n+2)*D + tid];
        c3 += a[(long)(n+3)*D + tid];
    }
    for (; n < n1; n++) c0 += a[(long)n*D + tid];
    sS[tid] = (c0+c1)+(c2+c3);
    __syncthreads();

    // ---- ctx: t = tanh((sS @ attW)/cnt) ----
    float cntf = fmaxf((float)(n1 - n0), 1.0f);
    float v = 0.f;
    for (int k = 0; k < D; k++) v += sS[k]*attW[k*D + tid];
    sT[tid] = tanhf(v/cntf);
    __syncthreads();

    // ---- pass 2: coef + weighted pool, wave per node, 2-way unroll ----
    int w = tid >> 6, lane = tid & 63;
    float4 tv = ((const float4*)sT)[lane];
    float4 acc0 = {0,0,0,0}, acc1 = {0,0,0,0};
    n = n0 + w;
    for (; n + 4 < n1; n += 8){
        float4 av0 = ((const float4*)(a + (long)n*D))[lane];
        float4 av1 = ((const float4*)(a + (long)(n+4)*D))[lane];
        float p0 = av0.x*tv.x + av0.y*tv.y + av0.z*tv.z + av0.w*tv.w;
        float p1 = av1.x*tv.x + av1.y*tv.y + av1.z*tv.z + av1.w*tv.w;
#pragma unroll
        for (int o = 32; o; o >>= 1){
            p0 += __shfl_xor(p0, o, 64);
            p1 += __shfl_xor(p1, o, 64);
        }
        float cf0 = sigm(p0), cf1 = sigm(p1);
        acc0.x += cf0*av0.x; acc0.y += cf0*av0.y; acc0.z += cf0*av0.z; acc0.w += cf0*av0.w;
        acc1.x += cf1*av1.x; acc1.y += cf1*av1.y; acc1.z += cf1*av1.z; acc1.w += cf1*av1.w;
    }
    if (n < n1){
        float4 av0 = ((const float4*)(a + (long)n*D))[lane];
        float p0 = av0.x*tv.x + av0.y*tv.y + av0.z*tv.z + av0.w*tv.w;
#pragma unroll
        for (int o = 32; o; o >>= 1) p0 += __shfl_xor(p0, o, 64);
        float cf0 = sigm(p0);
        acc0.x += cf0*av0.x; acc0.y += cf0*av0.y; acc0.z += cf0*av0.z; acc0.w += cf0*av0.w;
    }
    acc0.x += acc1.x; acc0.y += acc1.y; acc0.z += acc1.z; acc0.w += acc1.w;
    ((float4*)sAP[w])[lane] = acc0;
    __syncthreads();

    // ---- mu mix ----
    float apv = sAP[0][tid] + sAP[1][tid] + sAP[2][tid] + sAP[3][tid];
    float m = mu[tid];
    sP[tid] = m*apv + (1.0f - m)*sS[tid];
    __syncthreads();

    // ---- post MLP ----
    if (tid < 128){
        float hv = b1[tid];
        for (int k = 0; k < D; k++) hv += sP[k]*W1[k*128 + tid];
        sHid[tid] = fmaxf(hv, 0.f);
    }
    __syncthreads();
    if (tid < H){
        float o = b2[tid];
        for (int k = 0; k < 128; k++) o += sHid[k]*W2[k*H + tid];
        out[g*H + tid] = o;
    }
}

// ================= NTN stage 1 =================
__global__ void k_ntn(const float* __restrict__ gx, const float* __restrict__ tnW,
                      float* __restrict__ M){
    __shared__ float sgx[H];
    int b = blockIdx.x;
    int g = b >> 2;
    int ek = (b & 3)*256 + threadIdx.x;
    if (threadIdx.x < H) sgx[threadIdx.x] = gx[g*H + threadIdx.x];
    __syncthreads();
    float v = 0.f;
#pragma unroll 8
    for (int d = 0; d < H; d++) v += sgx[d]*tnW[d*(H*TN) + ek];
    M[g*(H*TN) + ek] = v;
}

// ================= final scoring =================
__global__ void k_final(const float* __restrict__ gx, const float* __restrict__ hx,
                        const float* __restrict__ M, const float* __restrict__ tnV,
                        const float* __restrict__ tnb,
                        const float* __restrict__ scW1, const float* __restrict__ scb1,
                        const float* __restrict__ scW2, const float* __restrict__ scb2,
                        const float* __restrict__ alpha, float* __restrict__ outp){
    __shared__ float sg[H], sh[H], sc[TN], h2[TN];
    int g = blockIdx.x; int lane = threadIdx.x;  // 64 threads
    float gv = gx[g*H + lane], hv = hx[g*H + lane];
    sg[lane] = gv; sh[lane] = hv;
    __syncthreads();
    const float* Mg = M + g*(H*TN) + lane*TN;
    float myt1 = 0.f;
#pragma unroll
    for (int k = 0; k < TN; k++){
        float part = Mg[k]*hv;
#pragma unroll
        for (int o = 32; o; o >>= 1) part += __shfl_xor(part, o, 64);
        if (lane == k) myt1 = part;
    }
    if (lane < TN){
        float t2 = tnb[lane];
        for (int d = 0; d < H; d++) t2 += sg[d]*tnV[lane*128 + d];
        for (int e = 0; e < H; e++) t2 += sh[e]*tnV[lane*128 + 64 + e];
        sc[lane] = fmaxf(myt1 + t2, 0.f);
    }
    __syncthreads();
    if (lane < TN){
        float v = scb1[lane];
        for (int j = 0; j < TN; j++) v += sc[j]*scW1[j*TN + lane];
        h2[lane] = fmaxf(v, 0.f);
    }
    __syncthreads();
    float dff = gv - hv;
    float ssq = dff*dff;
#pragma unroll
    for (int o = 32; o; o >>= 1) ssq += __shfl_xor(ssq, o, 64);
    if (lane == 0){
        float score = scb2[0];
        for (int j = 0; j < TN; j++) score += h2[j]*scW2[j];
        float l2 = sqrtf(ssq);
        float al = alpha[0];
        outp[g] = al*sigm(score) + (1.0f - al)*(1.0f/(1.0f + expf(l2)));
    }
}

extern "C" void kernel_launch(void* const* d_in, const int* in_sizes, int n_in,
                              void* d_out, int out_size, void* d_ws, size_t ws_size,
                              hipStream_t stream) {
    const int*   ei1   = (const int*)d_in[0];
    const int*   ei2   = (const int*)d_in[1];
    const int*   bat1  = (const int*)d_in[2];
    const int*   bat2  = (const int*)d_in[3];
    const float* feat1 = (const float*)d_in[4];
    const float* feat2 = (const float*)d_in[5];
    const float* preW  = (const float*)d_in[6];
    const float* preb  = (const float*)d_in[7];
    const float* convW = (const float*)d_in[8];
    const float* convb = (const float*)d_in[9];
    const float* delta = (const float*)d_in[10];
    const float* alpha = (const float*)d_in[11];
    const float* mu    = (const float*)d_in[12];
    const float* attW  = (const float*)d_in[13];
    const float* pW1   = (const float*)d_in[14];
    const float* pb1   = (const float*)d_in[15];
    const float* pW2   = (const float*)d_in[16];
    const float* pb2   = (const float*)d_in[17];
    const float* tnW   = (const float*)d_in[18];
    const float* tnV   = (const float*)d_in[19];
    const float* tnb   = (const float*)d_in[20];
    const float* scW1  = (const float*)d_in[21];
    const float* scb1  = (const float*)d_in[22];
    const float* scW2  = (const float*)d_in[23];
    const float* scb2  = (const float*)d_in[24];
    float* out = (float*)d_out;

    // workspace carve (16 B aligned chunks)
    char* w = (char*)d_ws;
    float* a    = (float*)w; w += sizeof(float)*(size_t)NN*D;
    float* f    = (float*)w; w += sizeof(float)*(size_t)NN*H;
    u16*   xb   = (u16*)w;   w += sizeof(u16)*(size_t)NN*H;
    float* dinv = (float*)w; w += sizeof(float)*NN;
    int*   deg  = (int*)w;   w += sizeof(int)*NN;
    int*   rank = (int*)w;   w += sizeof(int)*NE;
    int*   off  = (int*)w;   w += sizeof(int)*(NN+4);
    int*   csrc = (int*)w;   w += sizeof(int)*NE;
    int*   bsum = (int*)w;   w += sizeof(int)*512;
    int*   bs   = (int*)w;   w += sizeof(int)*NG;
    int*   be   = (int*)w;   w += sizeof(int)*NG;
    float* gx   = (float*)w; w += sizeof(float)*NG*H;
    float* hx   = (float*)w; w += sizeof(float)*NG*H;
    float* M    = (float*)w; w += sizeof(float)*NG*H*TN;

    const int B = 256;
    const int gNH = (NN*H + B - 1)/B;   // 25000
    const int gE  = (NE + B - 1)/B;     // 6250
    const int gN  = (NN + B - 1)/B;     // 391
    const int gT  = (NN + 63)/64;       // 1563

    auto run_side = [&](const int* ei, const int* batch, const float* feat, float* gout){
        const int* src = ei;
        const int* dst = ei + NE;
        k_bounds<<<gN, B, 0, stream>>>(batch, bs, be, deg);
        k_deg<<<gE, B, 0, stream>>>(dst, deg, rank);
        k_blocksum<<<gN, B, 0, stream>>>(deg, bsum);
        k_scan_bsum<<<1, 512, 0, stream>>>(bsum, gN);
        k_scan_apply<<<gN, B, 0, stream>>>(deg, bsum, off, dinv);
        k_fill<<<gE, B, 0, stream>>>(src, dst, rank, off, csrc);

        k_pre<<<gNH, B, 0, stream>>>(feat, preW, preb, batch, bs, be, delta, f, a);

        const float* xin = f; int xs = H;
        for (int i = 0; i < 3; i++){
            k_gemm64<<<gT, B, 0, stream>>>(xin, xs, convW + i*H*H, dinv, xb);
            float* aout = a + (i + 1)*H;
            k_conv<<<gNH, B, 0, stream>>>(off, csrc, dinv, xb, convb + i*H, xin, xs, aout, i < 2 ? 1 : 0);
            xin = aout; xs = D;
        }
        k_pool<<<NG, 256, 0, stream>>>(a, bs, be, attW, mu, pW1, pb1, pW2, pb2, gout);
    };

    run_side(ei1, bat1, feat1, gx);
    run_side(ei2, bat2, feat2, hx);
    k_ntn<<<NG*4, 256, 0, stream>>>(gx, tnW, M);
    k_final<<<NG, 64, 0, stream>>>(gx, hx, M, tnV, tnb, scW1, scb1, scW2, scb2, alpha, out);
}

// Round 6
// 1248.345 us; speedup vs baseline: 3.2905x; 1.0628x over previous
//
#include <hip/hip_runtime.h>
#include <math.h>

#define NN 100000
#define NE 1600000
#define NG 128
#define L 32
#define H 64
#define D 256
#define TN 16

typedef unsigned short u16;

__device__ __forceinline__ float sigm(float x){ return 1.0f/(1.0f+expf(-x)); }
__device__ __forceinline__ float bf2f(u16 x){ return __uint_as_float(((unsigned)x)<<16); }
__device__ __forceinline__ u16 f2bf(float f){
    unsigned u = __float_as_uint(f);
    unsigned r = u + 0x7fffu + ((u>>16)&1u);
    return (u16)(r>>16);
}

// ================= bounds + zero-init =================
__global__ void k_bounds(const int* __restrict__ batch, int* __restrict__ bs, int* __restrict__ be,
                         int* __restrict__ deg, float* __restrict__ ssum, float* __restrict__ ap){
    int i = blockIdx.x*blockDim.x + threadIdx.x;
    if (i < NG*D){ ssum[i] = 0.f; ap[i] = 0.f; }
    if (i >= NN) return;
    deg[i] = 0;
    int g = batch[i];
    if (i == 0 || batch[i-1] != g) bs[g] = i;
    if (i == NN-1 || batch[i+1] != g) be[g] = i + 1;
}

// ================= degree count + per-edge rank =================
__global__ void k_deg(const int* __restrict__ dst, int* __restrict__ deg, int* __restrict__ rank){
    int i = blockIdx.x*blockDim.x + threadIdx.x;
    if (i < NE) rank[i] = atomicAdd(&deg[dst[i]], 1);
}

// ================= scan =================
__global__ void k_blocksum(const int* __restrict__ deg, int* __restrict__ bsum){
    __shared__ int s[256];
    int t = threadIdx.x; int i = blockIdx.x*256 + t;
    s[t] = (i < NN) ? deg[i] : 0;
    __syncthreads();
    for (int o = 128; o; o >>= 1){ if (t < o) s[t] += s[t+o]; __syncthreads(); }
    if (t == 0) bsum[blockIdx.x] = s[0];
}
__global__ void k_scan_bsum(int* __restrict__ bsum, int nb){
    __shared__ int s[512];
    int t = threadIdx.x;
    s[t] = (t < nb) ? bsum[t] : 0;
    __syncthreads();
    for (int o = 1; o < 512; o <<= 1){
        int u = (t >= o) ? s[t-o] : 0;
        __syncthreads();
        s[t] += u;
        __syncthreads();
    }
    if (t < nb) bsum[t] = (t == 0) ? 0 : s[t-1];
}
__global__ void k_scan_apply(const int* __restrict__ deg, const int* __restrict__ boff,
                             int* __restrict__ off, float* __restrict__ dinv){
    __shared__ int s[256];
    int t = threadIdx.x; int i = blockIdx.x*256 + t;
    int v = (i < NN) ? deg[i] : 0;
    s[t] = v;
    __syncthreads();
    for (int o = 1; o < 256; o <<= 1){
        int u = (t >= o) ? s[t-o] : 0;
        __syncthreads();
        s[t] += u;
        __syncthreads();
    }
    if (i < NN){
        off[i] = boff[blockIdx.x] + s[t] - v;
        dinv[i] = rsqrtf((float)v + 1.0f);
    }
    if (i == 0) off[NN] = NE;
}
__global__ void k_fill(const int* __restrict__ src, const int* __restrict__ dst,
                       const int* __restrict__ rank, const int* __restrict__ off,
                       int* __restrict__ csrc){
    int e = blockIdx.x*blockDim.x + threadIdx.x;
    if (e >= NE) return;
    csrc[off[dst[e]] + rank[e]] = src[e];
}

// ================= pre =================
__global__ void k_pre(const float* __restrict__ feat, const float* __restrict__ W,
                      const float* __restrict__ b, const int* __restrict__ batch,
                      const int* __restrict__ bs, const int* __restrict__ be,
                      const float* __restrict__ delta,
                      float* __restrict__ f, float* __restrict__ a){
    __shared__ float Ws[L*H];
    __shared__ float bsh[H];
    int tid = threadIdx.x;
    for (int i = tid; i < L*H; i += 256) Ws[i] = W[i];
    if (tid < H) bsh[tid] = b[tid];
    __syncthreads();
    long idx = (long)blockIdx.x*256 + tid;
    int n = (int)(idx >> 6); int h = (int)(idx & 63);
    if (n >= NN) return;
    int lane = tid & 63;
    float xv = (lane < L) ? feat[(long)n*L + lane] : 0.f;
    float v = bsh[h];
#pragma unroll
    for (int k = 0; k < L; k++) v += __shfl(xv, k, 64)*Ws[k*H+h];
    int g = batch[n];
    float nrm = rsqrtf(fmaxf((float)(be[g] - bs[g]), 1.0f));
    float fv = v*nrm;
    f[(long)n*H + h] = fv;
    a[(long)n*D + h] = fv*(1.0f + delta[0]);
}

// ================= xws_bf16 = bf16((x @ W) * dinv) : 64-node tile =================
__global__ __launch_bounds__(256) void k_gemm64(const float* __restrict__ x, int xs,
                         const float* __restrict__ W, const float* __restrict__ dinv,
                         u16* __restrict__ xb){
    __shared__ float Xl[64*65];
    __shared__ float Wl[64*64];
    int t = threadIdx.x;
    int n0 = blockIdx.x*64;
    {
        const float4* Wg = (const float4*)W;
        float4* Ws4 = (float4*)Wl;
#pragma unroll
        for (int j = 0; j < 4; j++) Ws4[t + j*256] = Wg[t + j*256];
    }
    int r = t & 15, ig = t >> 4;
#pragma unroll
    for (int p = 0; p < 4; p++){
        int i = p*16 + ig;
        int n = n0 + i;
        float4 v = {0.f,0.f,0.f,0.f};
        if (n < NN) v = *(const float4*)(x + (long)n*xs + r*4);
        Xl[i*65 + r*4 + 0] = v.x;
        Xl[i*65 + r*4 + 1] = v.y;
        Xl[i*65 + r*4 + 2] = v.z;
        Xl[i*65 + r*4 + 3] = v.w;
    }
    __syncthreads();
    float4 a0={0,0,0,0}, a1={0,0,0,0}, a2={0,0,0,0}, a3={0,0,0,0};
    const float4* Wl4 = (const float4*)Wl;
#pragma unroll
    for (int k = 0; k < 64; k++){
        float4 w = Wl4[k*16 + r];
        float x0 = Xl[(ig*4+0)*65 + k];
        float x1 = Xl[(ig*4+1)*65 + k];
        float x2 = Xl[(ig*4+2)*65 + k];
        float x3 = Xl[(ig*4+3)*65 + k];
        a0.x += x0*w.x; a0.y += x0*w.y; a0.z += x0*w.z; a0.w += x0*w.w;
        a1.x += x1*w.x; a1.y += x1*w.y; a1.z += x1*w.z; a1.w += x1*w.w;
        a2.x += x2*w.x; a2.y += x2*w.y; a2.z += x2*w.z; a2.w += x2*w.w;
        a3.x += x3*w.x; a3.y += x3*w.y; a3.z += x3*w.z; a3.w += x3*w.w;
    }
    float4 accs[4] = {a0, a1, a2, a3};
#pragma unroll
    for (int c = 0; c < 4; c++){
        int n = n0 + ig*4 + c;
        if (n < NN){
            float di = dinv[n];
            ushort4 o;
            o.x = f2bf(accs[c].x*di);
            o.y = f2bf(accs[c].y*di);
            o.z = f2bf(accs[c].z*di);
            o.w = f2bf(accs[c].w*di);
            ((ushort4*)(xb + (long)n*H))[r] = o;
        }
    }
}

// ================= fused CSR gather + combine (bf16 rows, 4-edge-parallel) =================
__global__ void k_conv(const int* __restrict__ off, const int* __restrict__ csrc,
                       const float* __restrict__ dinv, const u16* __restrict__ xb,
                       const float* __restrict__ b, const float* __restrict__ xin, int xs,
                       float* __restrict__ aout, int relu_res){
    int wid  = (blockIdx.x*blockDim.x + threadIdx.x) >> 6;
    int lane = threadIdx.x & 63;
    if (wid >= NN) return;
    int q = lane >> 4, r = lane & 15;
    int d = wid;
    int e0 = off[d], e1 = off[d+1];
    const ushort4* X = (const ushort4*)xb;
    float4 acc = {0.f,0.f,0.f,0.f};
    for (int base = e0; base < e1; base += 64){
        int m = min(64, e1 - base);
        int idx = (base + lane < e1) ? csrc[base + lane] : 0;
        for (int j = 0; j < m; j += 4){
            int jq = j + q;
            int s = __shfl(idx, jq, 64);
            if (jq < m){
                ushort4 v = X[(long)s*16 + r];
                acc.x += bf2f(v.x); acc.y += bf2f(v.y);
                acc.z += bf2f(v.z); acc.w += bf2f(v.w);
            }
        }
    }
    acc.x += __shfl_xor(acc.x, 16, 64); acc.x += __shfl_xor(acc.x, 32, 64);
    acc.y += __shfl_xor(acc.y, 16, 64); acc.y += __shfl_xor(acc.y, 32, 64);
    acc.z += __shfl_xor(acc.z, 16, 64); acc.z += __shfl_xor(acc.z, 32, 64);
    acc.w += __shfl_xor(acc.w, 16, 64); acc.w += __shfl_xor(acc.w, 32, 64);
    ushort4 sv = X[(long)d*16 + r];
    float di = dinv[d];
    float4 b4 = ((const float4*)b)[r];
    float4 y;
    y.x = (acc.x + bf2f(sv.x))*di + b4.x;
    y.y = (acc.y + bf2f(sv.y))*di + b4.y;
    y.z = (acc.z + bf2f(sv.z))*di + b4.z;
    y.w = (acc.w + bf2f(sv.w))*di + b4.w;
    if (relu_res){
        float4 xi = *(const float4*)(xin + (long)d*xs + r*4);
        y.x = fmaxf(y.x, 0.f) + xi.x;
        y.y = fmaxf(y.y, 0.f) + xi.y;
        y.z = fmaxf(y.z, 0.f) + xi.z;
        y.w = fmaxf(y.w, 0.f) + xi.w;
    }
    if (q == 0) ((float4*)(aout + (long)d*D))[r] = y;
}

// ================= segmented sum over sorted batch (chunk-parallel) =================
__global__ void k_segsum(const float* __restrict__ a, const int* __restrict__ batch,
                         float* __restrict__ s){
    int d = threadIdx.x;                 // 256 = D columns
    int n0 = blockIdx.x*64;
    if (n0 >= NN) return;
    int n1 = min(n0 + 64, NN);
    float acc = 0.f;
    int curg = batch[n0];
    for (int n = n0; n < n1; n++){
        int g = batch[n];
        if (g != curg){ atomicAdd(&s[curg*D + d], acc); acc = 0.f; curg = g; }
        acc += a[(long)n*D + d];
    }
    atomicAdd(&s[curg*D + d], acc);
}

// ================= t = tanh((s @ att_W) / cnt) =================
__global__ void k_ctx(const float* __restrict__ s, const float* __restrict__ attW,
                      const int* __restrict__ bs, const int* __restrict__ be,
                      float* __restrict__ t){
    int idx = blockIdx.x*256 + threadIdx.x;   // G*D
    int g = idx >> 8; int d = idx & 255;
    float inv = 1.0f/fmaxf((float)(be[g] - bs[g]), 1.0f);
    float v = 0.f;
    for (int k = 0; k < D; k++) v += s[g*D + k]*attW[k*D + d];
    t[idx] = tanhf(v*inv);
}

// ================= coef + attention pool (chunk-parallel, float4) =================
__global__ void k_coef_ap(const float* __restrict__ a, const int* __restrict__ batch,
                          const float* __restrict__ t, float* __restrict__ ap){
    int lane = threadIdx.x & 63;
    int wid  = (blockIdx.x*blockDim.x + threadIdx.x) >> 6;
    int n0 = wid*64;
    if (n0 >= NN) return;
    int n1 = min(n0 + 64, NN);
    float ax=0.f, ay=0.f, az=0.f, aw=0.f;
    int curg = batch[n0];
    for (int n = n0; n < n1; n++){
        int g = batch[n];
        const float4* ar = (const float4*)(a + (long)n*D);
        const float4* tr = (const float4*)(t + (long)g*D);
        float4 v = ar[lane];
        float4 tv = tr[lane];
        float part = v.x*tv.x + v.y*tv.y + v.z*tv.z + v.w*tv.w;
#pragma unroll
        for (int o = 32; o; o >>= 1) part += __shfl_xor(part, o, 64);
        float coef = sigm(part);
        if (g != curg){
            atomicAdd(&ap[curg*D + lane*4 + 0], ax);
            atomicAdd(&ap[curg*D + lane*4 + 1], ay);
            atomicAdd(&ap[curg*D + lane*4 + 2], az);
            atomicAdd(&ap[curg*D + lane*4 + 3], aw);
            ax = ay = az = aw = 0.f; curg = g;
        }
        ax += coef*v.x; ay += coef*v.y; az += coef*v.z; aw += coef*v.w;
    }
    atomicAdd(&ap[curg*D + lane*4 + 0], ax);
    atomicAdd(&ap[curg*D + lane*4 + 1], ay);
    atomicAdd(&ap[curg*D + lane*4 + 2], az);
    atomicAdd(&ap[curg*D + lane*4 + 3], aw);
}

// ================= per-graph MLP =================
__global__ void k_mlp2(const float* __restrict__ ap, const float* __restrict__ s,
                       const float* __restrict__ mu,
                       const float* __restrict__ W1, const float* __restrict__ b1,
                       const float* __restrict__ W2, const float* __restrict__ b2,
                       float* __restrict__ out){
    __shared__ float p[D];
    __shared__ float hid[128];
    int g = blockIdx.x; int tid = threadIdx.x;   // 128 threads
    for (int i = tid; i < D; i += 128){
        float m = mu[i];
        p[i] = m*ap[g*D + i] + (1.0f - m)*s[g*D + i];
    }
    __syncthreads();
    float v = b1[tid];
    for (int k = 0; k < D; k++) v += p[k]*W1[k*128 + tid];
    hid[tid] = fmaxf(v, 0.f);
    __syncthreads();
    if (tid < H){
        float o = b2[tid];
        for (int k = 0; k < 128; k++) o += hid[k]*W2[k*H + tid];
        out[g*H + tid] = o;
    }
}

// ================= NTN stage 1 =================
__global__ void k_ntn(const float* __restrict__ gx, const float* __restrict__ tnW,
                      float* __restrict__ M){
    __shared__ float sgx[H];
    int b = blockIdx.x;
    int g = b >> 2;
    int ek = (b & 3)*256 + threadIdx.x;
    if (threadIdx.x < H) sgx[threadIdx.x] = gx[g*H + threadIdx.x];
    __syncthreads();
    float v = 0.f;
#pragma unroll 8
    for (int d = 0; d < H; d++) v += sgx[d]*tnW[d*(H*TN) + ek];
    M[g*(H*TN) + ek] = v;
}

// ================= final scoring =================
__global__ void k_final(const float* __restrict__ gx, const float* __restrict__ hx,
                        const float* __restrict__ M, const float* __restrict__ tnV,
                        const float* __restrict__ tnb,
                        const float* __restrict__ scW1, const float* __restrict__ scb1,
                        const float* __restrict__ scW2, const float* __restrict__ scb2,
                        const float* __restrict__ alpha, float* __restrict__ outp){
    __shared__ float sg[H], sh[H], sc[TN], h2[TN];
    int g = blockIdx.x; int lane = threadIdx.x;  // 64 threads
    float gv = gx[g*H + lane], hv = hx[g*H + lane];
    sg[lane] = gv; sh[lane] = hv;
    __syncthreads();
    const float* Mg = M + g*(H*TN) + lane*TN;
    float myt1 = 0.f;
#pragma unroll
    for (int k = 0; k < TN; k++){
        float part = Mg[k]*hv;
#pragma unroll
        for (int o = 32; o; o >>= 1) part += __shfl_xor(part, o, 64);
        if (lane == k) myt1 = part;
    }
    if (lane < TN){
        float t2 = tnb[lane];
        for (int d = 0; d < H; d++) t2 += sg[d]*tnV[lane*128 + d];
        for (int e = 0; e < H; e++) t2 += sh[e]*tnV[lane*128 + 64 + e];
        sc[lane] = fmaxf(myt1 + t2, 0.f);
    }
    __syncthreads();
    if (lane < TN){
        float v = scb1[lane];
        for (int j = 0; j < TN; j++) v += sc[j]*scW1[j*TN + lane];
        h2[lane] = fmaxf(v, 0.f);
    }
    __syncthreads();
    float dff = gv - hv;
    float ssq = dff*dff;
#pragma unroll
    for (int o = 32; o; o >>= 1) ssq += __shfl_xor(ssq, o, 64);
    if (lane == 0){
        float score = scb2[0];
        for (int j = 0; j < TN; j++) score += h2[j]*scW2[j];
        float l2 = sqrtf(ssq);
        float al = alpha[0];
        outp[g] = al*sigm(score) + (1.0f - al)*(1.0f/(1.0f + expf(l2)));
    }
}

extern "C" void kernel_launch(void* const* d_in, const int* in_sizes, int n_in,
                              void* d_out, int out_size, void* d_ws, size_t ws_size,
                              hipStream_t stream) {
    const int*   ei1   = (const int*)d_in[0];
    const int*   ei2   = (const int*)d_in[1];
    const int*   bat1  = (const int*)d_in[2];
    const int*   bat2  = (const int*)d_in[3];
    const float* feat1 = (const float*)d_in[4];
    const float* feat2 = (const float*)d_in[5];
    const float* preW  = (const float*)d_in[6];
    const float* preb  = (const float*)d_in[7];
    const float* convW = (const float*)d_in[8];
    const float* convb = (const float*)d_in[9];
    const float* delta = (const float*)d_in[10];
    const float* alpha = (const float*)d_in[11];
    const float* mu    = (const float*)d_in[12];
    const float* attW  = (const float*)d_in[13];
    const float* pW1   = (const float*)d_in[14];
    const float* pb1   = (const float*)d_in[15];
    const float* pW2   = (const float*)d_in[16];
    const float* pb2   = (const float*)d_in[17];
    const float* tnW   = (const float*)d_in[18];
    const float* tnV   = (const float*)d_in[19];
    const float* tnb   = (const float*)d_in[20];
    const float* scW1  = (const float*)d_in[21];
    const float* scb1  = (const float*)d_in[22];
    const float* scW2  = (const float*)d_in[23];
    const float* scb2  = (const float*)d_in[24];
    float* out = (float*)d_out;

    // workspace carve (16 B aligned chunks)
    char* w = (char*)d_ws;
    float* a    = (float*)w; w += sizeof(float)*(size_t)NN*D;
    float* f    = (float*)w; w += sizeof(float)*(size_t)NN*H;
    u16*   xb   = (u16*)w;   w += sizeof(u16)*(size_t)NN*H;
    float* dinv = (float*)w; w += sizeof(float)*NN;
    int*   deg  = (int*)w;   w += sizeof(int)*NN;
    int*   rank = (int*)w;   w += sizeof(int)*NE;
    int*   off  = (int*)w;   w += sizeof(int)*(NN+4);
    int*   csrc = (int*)w;   w += sizeof(int)*NE;
    int*   bsum = (int*)w;   w += sizeof(int)*512;
    int*   bs   = (int*)w;   w += sizeof(int)*NG;
    int*   be   = (int*)w;   w += sizeof(int)*NG;
    float* ssum = (float*)w; w += sizeof(float)*NG*D;
    float* tmat = (float*)w; w += sizeof(float)*NG*D;
    float* ap   = (float*)w; w += sizeof(float)*NG*D;
    float* gx   = (float*)w; w += sizeof(float)*NG*H;
    float* hx   = (float*)w; w += sizeof(float)*NG*H;
    float* M    = (float*)w; w += sizeof(float)*NG*H*TN;

    const int B = 256;
    const int gNH = (NN*H + B - 1)/B;   // 25000
    const int gE  = (NE + B - 1)/B;     // 6250
    const int gN  = (NN + B - 1)/B;     // 391
    const int gT  = (NN + 63)/64;       // 1563
    const int gCoef = (gT + 3)/4;       // 391

    auto run_side = [&](const int* ei, const int* batch, const float* feat, float* gout){
        const int* src = ei;
        const int* dst = ei + NE;
        k_bounds<<<gN, B, 0, stream>>>(batch, bs, be, deg, ssum, ap);
        k_deg<<<gE, B, 0, stream>>>(dst, deg, rank);
        k_blocksum<<<gN, B, 0, stream>>>(deg, bsum);
        k_scan_bsum<<<1, 512, 0, stream>>>(bsum, gN);
        k_scan_apply<<<gN, B, 0, stream>>>(deg, bsum, off, dinv);
        k_fill<<<gE, B, 0, stream>>>(src, dst, rank, off, csrc);

        k_pre<<<gNH, B, 0, stream>>>(feat, preW, preb, batch, bs, be, delta, f, a);

        const float* xin = f; int xs = H;
        for (int i = 0; i < 3; i++){
            k_gemm64<<<gT, B, 0, stream>>>(xin, xs, convW + i*H*H, dinv, xb);
            float* aout = a + (i + 1)*H;
            k_conv<<<gNH, B, 0, stream>>>(off, csrc, dinv, xb, convb + i*H, xin, xs, aout, i < 2 ? 1 : 0);
            xin = aout; xs = D;
        }
        k_segsum<<<gT, 256, 0, stream>>>(a, batch, ssum);
        k_ctx<<<NG*D/256, 256, 0, stream>>>(ssum, attW, bs, be, tmat);
        k_coef_ap<<<gCoef, 256, 0, stream>>>(a, batch, tmat, ap);
        k_mlp2<<<NG, 128, 0, stream>>>(ap, ssum, mu, pW1, pb1, pW2, pb2, gout);
    };

    run_side(ei1, bat1, feat1, gx);
    run_side(ei2, bat2, feat2, hx);
    k_ntn<<<NG*4, 256, 0, stream>>>(gx, tnW, M);
    k_final<<<NG, 64, 0, stream>>>(gx, hx, M, tnV, tnb, scW1, scb1, scW2, scb2, alpha, out);
}

// Round 7
// 1208.271 us; speedup vs baseline: 3.3996x; 1.0332x over previous
//
#include <hip/hip_runtime.h>
#include <math.h>

#define NN 100000
#define NE 1600000
#define NG 128
#define L 32
#define H 64
#define D 256
#define TN 16
#define ONN (NN+4)

typedef unsigned short u16;

__device__ __forceinline__ float sigm(float x){ return 1.0f/(1.0f+expf(-x)); }
__device__ __forceinline__ float bf2f(u16 x){ return __uint_as_float(((unsigned)x)<<16); }
__device__ __forceinline__ float blo(unsigned u){ return __uint_as_float(u<<16); }
__device__ __forceinline__ float bhi(unsigned u){ return __uint_as_float(u & 0xffff0000u); }
__device__ __forceinline__ u16 f2bf(float f){
    unsigned u = __float_as_uint(f);
    unsigned r = u + 0x7fffu + ((u>>16)&1u);
    return (u16)(r>>16);
}

// ================= dual-side bounds + zero-init =================
__global__ void k_bounds2(const int* __restrict__ bat1, const int* __restrict__ bat2,
                          int* __restrict__ bs, int* __restrict__ be,
                          int* __restrict__ deg, float* __restrict__ ssum, float* __restrict__ ap,
                          int half){
    int side = blockIdx.x >= half;
    const int* batch = side ? bat2 : bat1;
    int i = (blockIdx.x - side*half)*blockDim.x + threadIdx.x;
    if (i < NG*D){ ssum[side*NG*D + i] = 0.f; ap[side*NG*D + i] = 0.f; }
    if (i >= NN) return;
    deg[side*NN + i] = 0;
    int g = batch[i];
    if (i == 0 || batch[i-1] != g) bs[side*NG + g] = i;
    if (i == NN-1 || batch[i+1] != g) be[side*NG + g] = i + 1;
}

// ================= dual-side degree count + rank =================
__global__ void k_deg2(const int* __restrict__ dst1, const int* __restrict__ dst2,
                       int* __restrict__ deg, int* __restrict__ rank, int half){
    int side = blockIdx.x >= half;
    int e = (blockIdx.x - side*half)*blockDim.x + threadIdx.x;
    if (e >= NE) return;
    const int* dst = side ? dst2 : dst1;
    rank[side*NE + e] = atomicAdd(&deg[side*NN + dst[e]], 1);
}

// ================= dual-side scan =================
__global__ void k_blocksum2(const int* __restrict__ deg, int* __restrict__ bsum, int half){
    __shared__ int s[256];
    int side = blockIdx.x >= half;
    int lb = blockIdx.x - side*half;
    int t = threadIdx.x; int i = lb*256 + t;
    s[t] = (i < NN) ? deg[side*NN + i] : 0;
    __syncthreads();
    for (int o = 128; o; o >>= 1){ if (t < o) s[t] += s[t+o]; __syncthreads(); }
    if (t == 0) bsum[side*512 + lb] = s[0];
}
__global__ void k_scan_bsum2(int* __restrict__ bsum, int nb){
    __shared__ int s[512];
    int side = blockIdx.x;
    int t = threadIdx.x;
    s[t] = (t < nb) ? bsum[side*512 + t] : 0;
    __syncthreads();
    for (int o = 1; o < 512; o <<= 1){
        int u = (t >= o) ? s[t-o] : 0;
        __syncthreads();
        s[t] += u;
        __syncthreads();
    }
    if (t < nb) bsum[side*512 + t] = (t == 0) ? 0 : s[t-1];
}
__global__ void k_scan_apply2(const int* __restrict__ deg, const int* __restrict__ boff,
                              int* __restrict__ off, float* __restrict__ dinv, int half){
    __shared__ int s[256];
    int side = blockIdx.x >= half;
    int lb = blockIdx.x - side*half;
    int t = threadIdx.x; int i = lb*256 + t;
    int v = (i < NN) ? deg[side*NN + i] : 0;
    s[t] = v;
    __syncthreads();
    for (int o = 1; o < 256; o <<= 1){
        int u = (t >= o) ? s[t-o] : 0;
        __syncthreads();
        s[t] += u;
        __syncthreads();
    }
    if (i < NN){
        off[side*ONN + i] = boff[side*512 + lb] + s[t] - v;
        dinv[side*NN + i] = rsqrtf((float)v + 1.0f);
    }
    if (i == 0) off[side*ONN + NN] = NE;
}
__global__ void k_fill2(const int* __restrict__ ei1, const int* __restrict__ ei2,
                        const int* __restrict__ rank, const int* __restrict__ off,
                        int* __restrict__ csrc, int half){
    int side = blockIdx.x >= half;
    int e = (blockIdx.x - side*half)*blockDim.x + threadIdx.x;
    if (e >= NE) return;
    const int* ei = side ? ei2 : ei1;
    csrc[side*NE + off[side*ONN + ei[NE + e]] + rank[side*NE + e]] = ei[e];
}

// ================= pre =================
__global__ void k_pre(const float* __restrict__ feat, const float* __restrict__ W,
                      const float* __restrict__ b, const int* __restrict__ batch,
                      const int* __restrict__ bs, const int* __restrict__ be,
                      const float* __restrict__ delta,
                      float* __restrict__ f, float* __restrict__ a){
    __shared__ float Ws[L*H];
    __shared__ float bsh[H];
    int tid = threadIdx.x;
    for (int i = tid; i < L*H; i += 256) Ws[i] = W[i];
    if (tid < H) bsh[tid] = b[tid];
    __syncthreads();
    long idx = (long)blockIdx.x*256 + tid;
    int n = (int)(idx >> 6); int h = (int)(idx & 63);
    if (n >= NN) return;
    int lane = tid & 63;
    float xv = (lane < L) ? feat[(long)n*L + lane] : 0.f;
    float v = bsh[h];
#pragma unroll
    for (int k = 0; k < L; k++) v += __shfl(xv, k, 64)*Ws[k*H+h];
    int g = batch[n];
    float nrm = rsqrtf(fmaxf((float)(be[g] - bs[g]), 1.0f));
    float fv = v*nrm;
    f[(long)n*H + h] = fv;
    a[(long)n*D + h] = fv*(1.0f + delta[0]);
}

// ================= xws_bf16 = bf16((x @ W) * dinv) : 64-node tile =================
__global__ __launch_bounds__(256) void k_gemm64(const float* __restrict__ x, int xs,
                         const float* __restrict__ W, const float* __restrict__ dinv,
                         u16* __restrict__ xb){
    __shared__ float Xl[64*65];
    __shared__ float Wl[64*64];
    int t = threadIdx.x;
    int n0 = blockIdx.x*64;
    {
        const float4* Wg = (const float4*)W;
        float4* Ws4 = (float4*)Wl;
#pragma unroll
        for (int j = 0; j < 4; j++) Ws4[t + j*256] = Wg[t + j*256];
    }
    int r = t & 15, ig = t >> 4;
#pragma unroll
    for (int p = 0; p < 4; p++){
        int i = p*16 + ig;
        int n = n0 + i;
        float4 v = {0.f,0.f,0.f,0.f};
        if (n < NN) v = *(const float4*)(x + (long)n*xs + r*4);
        Xl[i*65 + r*4 + 0] = v.x;
        Xl[i*65 + r*4 + 1] = v.y;
        Xl[i*65 + r*4 + 2] = v.z;
        Xl[i*65 + r*4 + 3] = v.w;
    }
    __syncthreads();
    float4 a0={0,0,0,0}, a1={0,0,0,0}, a2={0,0,0,0}, a3={0,0,0,0};
    const float4* Wl4 = (const float4*)Wl;
#pragma unroll
    for (int k = 0; k < 64; k++){
        float4 w = Wl4[k*16 + r];
        float x0 = Xl[(ig*4+0)*65 + k];
        float x1 = Xl[(ig*4+1)*65 + k];
        float x2 = Xl[(ig*4+2)*65 + k];
        float x3 = Xl[(ig*4+3)*65 + k];
        a0.x += x0*w.x; a0.y += x0*w.y; a0.z += x0*w.z; a0.w += x0*w.w;
        a1.x += x1*w.x; a1.y += x1*w.y; a1.z += x1*w.z; a1.w += x1*w.w;
        a2.x += x2*w.x; a2.y += x2*w.y; a2.z += x2*w.z; a2.w += x2*w.w;
        a3.x += x3*w.x; a3.y += x3*w.y; a3.z += x3*w.z; a3.w += x3*w.w;
    }
    float4 accs[4] = {a0, a1, a2, a3};
#pragma unroll
    for (int c = 0; c < 4; c++){
        int n = n0 + ig*4 + c;
        if (n < NN){
            float di = dinv[n];
            ushort4 o;
            o.x = f2bf(accs[c].x*di);
            o.y = f2bf(accs[c].y*di);
            o.z = f2bf(accs[c].z*di);
            o.w = f2bf(accs[c].w*di);
            ((ushort4*)(xb + (long)n*H))[r] = o;
        }
    }
}

// ================= fused CSR gather + combine (bf16 rows, 8-edge-parallel uint4) =================
__global__ void k_conv(const int* __restrict__ off, const int* __restrict__ csrc,
                       const float* __restrict__ dinv, const u16* __restrict__ xb,
                       const float* __restrict__ b, const float* __restrict__ xin, int xs,
                       float* __restrict__ aout, int relu_res){
    int wid  = (blockIdx.x*blockDim.x + threadIdx.x) >> 6;
    int lane = threadIdx.x & 63;
    if (wid >= NN) return;
    int q = lane >> 3, r = lane & 7;      // 8 groups x 8 lanes; row = 8 lanes * 16 B
    int d = wid;
    int e0 = off[d], e1 = off[d+1];
    const uint4* X = (const uint4*)xb;
    float acc[8] = {0.f,0.f,0.f,0.f,0.f,0.f,0.f,0.f};
    for (int base = e0; base < e1; base += 64){
        int m = min(64, e1 - base);
        int idx = (base + lane < e1) ? csrc[base + lane] : 0;
        for (int j = 0; j < m; j += 8){
            int jq = j + q;
            int s = __shfl(idx, jq, 64);
            if (jq < m){
                uint4 v = X[(long)s*8 + r];
                acc[0] += blo(v.x); acc[1] += bhi(v.x);
                acc[2] += blo(v.y); acc[3] += bhi(v.y);
                acc[4] += blo(v.z); acc[5] += bhi(v.z);
                acc[6] += blo(v.w); acc[7] += bhi(v.w);
            }
        }
    }
#pragma unroll
    for (int o = 8; o < 64; o <<= 1){
#pragma unroll
        for (int k = 0; k < 8; k++) acc[k] += __shfl_xor(acc[k], o, 64);
    }
    if (q == 0){   // lanes 0..7 hold columns r*8..r*8+7
        uint4 sv = X[(long)d*8 + r];
        float se[8] = {blo(sv.x),bhi(sv.x),blo(sv.y),bhi(sv.y),
                       blo(sv.z),bhi(sv.z),blo(sv.w),bhi(sv.w)};
        float di = dinv[d];
        const float4* bb = (const float4*)b;
        float4 b0 = bb[r*2], b1 = bb[r*2+1];
        float y[8];
#pragma unroll
        for (int k = 0; k < 4; k++) y[k]   = (acc[k]   + se[k])*di   + (&b0.x)[k];
#pragma unroll
        for (int k = 0; k < 4; k++) y[k+4] = (acc[k+4] + se[k+4])*di + (&b1.x)[k];
        if (relu_res){
            float4 x0 = *(const float4*)(xin + (long)d*xs + r*8);
            float4 x1 = *(const float4*)(xin + (long)d*xs + r*8 + 4);
#pragma unroll
            for (int k = 0; k < 4; k++) y[k]   = fmaxf(y[k],   0.f) + (&x0.x)[k];
#pragma unroll
            for (int k = 0; k < 4; k++) y[k+4] = fmaxf(y[k+4], 0.f) + (&x1.x)[k];
        }
        float4 o0 = {y[0],y[1],y[2],y[3]};
        float4 o1 = {y[4],y[5],y[6],y[7]};
        float4* op = (float4*)(aout + (long)d*D + r*8);
        op[0] = o0; op[1] = o1;
    }
}

// ================= segmented sum over sorted batch (chunk-parallel) =================
__global__ void k_segsum(const float* __restrict__ a, const int* __restrict__ batch,
                         float* __restrict__ s){
    int d = threadIdx.x;                 // 256 = D columns
    int n0 = blockIdx.x*64;
    if (n0 >= NN) return;
    int n1 = min(n0 + 64, NN);
    float acc = 0.f;
    int curg = batch[n0];
    for (int n = n0; n < n1; n++){
        int g = batch[n];
        if (g != curg){ atomicAdd(&s[curg*D + d], acc); acc = 0.f; curg = g; }
        acc += a[(long)n*D + d];
    }
    atomicAdd(&s[curg*D + d], acc);
}

// ================= t = tanh((s @ att_W) / cnt) =================
__global__ void k_ctx(const float* __restrict__ s, const float* __restrict__ attW,
                      const int* __restrict__ bs, const int* __restrict__ be,
                      float* __restrict__ t){
    int idx = blockIdx.x*256 + threadIdx.x;   // G*D
    int g = idx >> 8; int d = idx & 255;
    float inv = 1.0f/fmaxf((float)(be[g] - bs[g]), 1.0f);
    float v = 0.f;
    for (int k = 0; k < D; k++) v += s[g*D + k]*attW[k*D + d];
    t[idx] = tanhf(v*inv);
}

// ================= coef + attention pool (chunk-parallel, float4) =================
__global__ void k_coef_ap(const float* __restrict__ a, const int* __restrict__ batch,
                          const float* __restrict__ t, float* __restrict__ ap){
    int lane = threadIdx.x & 63;
    int wid  = (blockIdx.x*blockDim.x + threadIdx.x) >> 6;
    int n0 = wid*64;
    if (n0 >= NN) return;
    int n1 = min(n0 + 64, NN);
    float ax=0.f, ay=0.f, az=0.f, aw=0.f;
    int curg = batch[n0];
    for (int n = n0; n < n1; n++){
        int g = batch[n];
        const float4* ar = (const float4*)(a + (long)n*D);
        const float4* tr = (const float4*)(t + (long)g*D);
        float4 v = ar[lane];
        float4 tv = tr[lane];
        float part = v.x*tv.x + v.y*tv.y + v.z*tv.z + v.w*tv.w;
#pragma unroll
        for (int o = 32; o; o >>= 1) part += __shfl_xor(part, o, 64);
        float coef = sigm(part);
        if (g != curg){
            atomicAdd(&ap[curg*D + lane*4 + 0], ax);
            atomicAdd(&ap[curg*D + lane*4 + 1], ay);
            atomicAdd(&ap[curg*D + lane*4 + 2], az);
            atomicAdd(&ap[curg*D + lane*4 + 3], aw);
            ax = ay = az = aw = 0.f; curg = g;
        }
        ax += coef*v.x; ay += coef*v.y; az += coef*v.z; aw += coef*v.w;
    }
    atomicAdd(&ap[curg*D + lane*4 + 0], ax);
    atomicAdd(&ap[curg*D + lane*4 + 1], ay);
    atomicAdd(&ap[curg*D + lane*4 + 2], az);
    atomicAdd(&ap[curg*D + lane*4 + 3], aw);
}

// ================= per-graph MLP =================
__global__ void k_mlp2(const float* __restrict__ ap, const float* __restrict__ s,
                       const float* __restrict__ mu,
                       const float* __restrict__ W1, const float* __restrict__ b1,
                       const float* __restrict__ W2, const float* __restrict__ b2,
                       float* __restrict__ out){
    __shared__ float p[D];
    __shared__ float hid[128];
    int g = blockIdx.x; int tid = threadIdx.x;   // 128 threads
    for (int i = tid; i < D; i += 128){
        float m = mu[i];
        p[i] = m*ap[g*D + i] + (1.0f - m)*s[g*D + i];
    }
    __syncthreads();
    float v = b1[tid];
    for (int k = 0; k < D; k++) v += p[k]*W1[k*128 + tid];
    hid[tid] = fmaxf(v, 0.f);
    __syncthreads();
    if (tid < H){
        float o = b2[tid];
        for (int k = 0; k < 128; k++) o += hid[k]*W2[k*H + tid];
        out[g*H + tid] = o;
    }
}

// ================= NTN stage 1 =================
__global__ void k_ntn(const float* __restrict__ gx, const float* __restrict__ tnW,
                      float* __restrict__ M){
    __shared__ float sgx[H];
    int b = blockIdx.x;
    int g = b >> 2;
    int ek = (b & 3)*256 + threadIdx.x;
    if (threadIdx.x < H) sgx[threadIdx.x] = gx[g*H + threadIdx.x];
    __syncthreads();
    float v = 0.f;
#pragma unroll 8
    for (int d = 0; d < H; d++) v += sgx[d]*tnW[d*(H*TN) + ek];
    M[g*(H*TN) + ek] = v;
}

// ================= final scoring =================
__global__ void k_final(const float* __restrict__ gx, const float* __restrict__ hx,
                        const float* __restrict__ M, const float* __restrict__ tnV,
                        const float* __restrict__ tnb,
                        const float* __restrict__ scW1, const float* __restrict__ scb1,
                        const float* __restrict__ scW2, const float* __restrict__ scb2,
                        const float* __restrict__ alpha, float* __restrict__ outp){
    __shared__ float sg[H], sh[H], sc[TN], h2[TN];
    int g = blockIdx.x; int lane = threadIdx.x;  // 64 threads
    float gv = gx[g*H + lane], hv = hx[g*H + lane];
    sg[lane] = gv; sh[lane] = hv;
    __syncthreads();
    const float* Mg = M + g*(H*TN) + lane*TN;
    float myt1 = 0.f;
#pragma unroll
    for (int k = 0; k < TN; k++){
        float part = Mg[k]*hv;
#pragma unroll
        for (int o = 32; o; o >>= 1) part += __shfl_xor(part, o, 64);
        if (lane == k) myt1 = part;
    }
    if (lane < TN){
        float t2 = tnb[lane];
        for (int d = 0; d < H; d++) t2 += sg[d]*tnV[lane*128 + d];
        for (int e = 0; e < H; e++) t2 += sh[e]*tnV[lane*128 + 64 + e];
        sc[lane] = fmaxf(myt1 + t2, 0.f);
    }
    __syncthreads();
    if (lane < TN){
        float v = scb1[lane];
        for (int j = 0; j < TN; j++) v += sc[j]*scW1[j*TN + lane];
        h2[lane] = fmaxf(v, 0.f);
    }
    __syncthreads();
    float dff = gv - hv;
    float ssq = dff*dff;
#pragma unroll
    for (int o = 32; o; o >>= 1) ssq += __shfl_xor(ssq, o, 64);
    if (lane == 0){
        float score = scb2[0];
        for (int j = 0; j < TN; j++) score += h2[j]*scW2[j];
        float l2 = sqrtf(ssq);
        float al = alpha[0];
        outp[g] = al*sigm(score) + (1.0f - al)*(1.0f/(1.0f + expf(l2)));
    }
}

extern "C" void kernel_launch(void* const* d_in, const int* in_sizes, int n_in,
                              void* d_out, int out_size, void* d_ws, size_t ws_size,
                              hipStream_t stream) {
    const int*   ei1   = (const int*)d_in[0];
    const int*   ei2   = (const int*)d_in[1];
    const int*   bat1  = (const int*)d_in[2];
    const int*   bat2  = (const int*)d_in[3];
    const float* feat1 = (const float*)d_in[4];
    const float* feat2 = (const float*)d_in[5];
    const float* preW  = (const float*)d_in[6];
    const float* preb  = (const float*)d_in[7];
    const float* convW = (const float*)d_in[8];
    const float* convb = (const float*)d_in[9];
    const float* delta = (const float*)d_in[10];
    const float* alpha = (const float*)d_in[11];
    const float* mu    = (const float*)d_in[12];
    const float* attW  = (const float*)d_in[13];
    const float* pW1   = (const float*)d_in[14];
    const float* pb1   = (const float*)d_in[15];
    const float* pW2   = (const float*)d_in[16];
    const float* pb2   = (const float*)d_in[17];
    const float* tnW   = (const float*)d_in[18];
    const float* tnV   = (const float*)d_in[19];
    const float* tnb   = (const float*)d_in[20];
    const float* scW1  = (const float*)d_in[21];
    const float* scb1  = (const float*)d_in[22];
    const float* scW2  = (const float*)d_in[23];
    const float* scb2  = (const float*)d_in[24];
    float* out = (float*)d_out;

    // workspace carve (16 B aligned chunks); dual-side arrays indexed [side]
    char* w = (char*)d_ws;
    float* a    = (float*)w; w += sizeof(float)*(size_t)NN*D;
    float* f    = (float*)w; w += sizeof(float)*(size_t)NN*H;
    u16*   xb   = (u16*)w;   w += sizeof(u16)*(size_t)NN*H;
    float* dinv = (float*)w; w += sizeof(float)*2*NN;
    int*   deg  = (int*)w;   w += sizeof(int)*2*NN;
    int*   rank = (int*)w;   w += sizeof(int)*2*(size_t)NE;
    int*   off  = (int*)w;   w += sizeof(int)*2*ONN;
    int*   csrc = (int*)w;   w += sizeof(int)*2*(size_t)NE;
    int*   bsum = (int*)w;   w += sizeof(int)*2*512;
    int*   bs   = (int*)w;   w += sizeof(int)*2*NG;
    int*   be   = (int*)w;   w += sizeof(int)*2*NG;
    float* ssum = (float*)w; w += sizeof(float)*2*NG*D;
    float* tmat = (float*)w; w += sizeof(float)*NG*D;
    float* ap   = (float*)w; w += sizeof(float)*2*NG*D;
    float* gx   = (float*)w; w += sizeof(float)*NG*H;
    float* hx   = (float*)w; w += sizeof(float)*NG*H;
    float* M    = (float*)w; w += sizeof(float)*NG*H*TN;

    const int B = 256;
    const int gNH = (NN*H + B - 1)/B;   // 25000
    const int gE  = (NE + B - 1)/B;     // 6250
    const int gN  = (NN + B - 1)/B;     // 391
    const int gT  = (NN + 63)/64;       // 1563
    const int gCoef = (gT + 3)/4;       // 391

    // ---- dual-side CSR build ----
    k_bounds2<<<2*gN, B, 0, stream>>>(bat1, bat2, bs, be, deg, ssum, ap, gN);
    k_deg2<<<2*gE, B, 0, stream>>>(ei1 + NE, ei2 + NE, deg, rank, gE);
    k_blocksum2<<<2*gN, B, 0, stream>>>(deg, bsum, gN);
    k_scan_bsum2<<<2, 512, 0, stream>>>(bsum, gN);
    k_scan_apply2<<<2*gN, B, 0, stream>>>(deg, bsum, off, dinv, gN);
    k_fill2<<<2*gE, B, 0, stream>>>(ei1, ei2, rank, off, csrc, gE);

    auto run_side = [&](int side, const int* batch, const float* feat, float* gout){
        const int*   off_s  = off  + side*ONN;
        const int*   csrc_s = csrc + side*NE;
        const float* dinv_s = dinv + side*NN;
        const int*   bs_s   = bs   + side*NG;
        const int*   be_s   = be   + side*NG;
        float*       ssum_s = ssum + side*NG*D;
        float*       ap_s   = ap   + side*NG*D;

        k_pre<<<gNH, B, 0, stream>>>(feat, preW, preb, batch, bs_s, be_s, delta, f, a);

        const float* xin = f; int xs = H;
        for (int i = 0; i < 3; i++){
            k_gemm64<<<gT, B, 0, stream>>>(xin, xs, convW + i*H*H, dinv_s, xb);
            float* aout = a + (i + 1)*H;
            k_conv<<<gNH, B, 0, stream>>>(off_s, csrc_s, dinv_s, xb, convb + i*H, xin, xs, aout, i < 2 ? 1 : 0);
            xin = aout; xs = D;
        }
        k_segsum<<<gT, 256, 0, stream>>>(a, batch, ssum_s);
        k_ctx<<<NG*D/256, 256, 0, stream>>>(ssum_s, attW, bs_s, be_s, tmat);
        k_coef_ap<<<gCoef, 256, 0, stream>>>(a, batch, tmat, ap_s);
        k_mlp2<<<NG, 128, 0, stream>>>(ap_s, ssum_s, mu, pW1, pb1, pW2, pb2, gout);
    };

    run_side(0, bat1, feat1, gx);
    run_side(1, bat2, feat2, hx);
    k_ntn<<<NG*4, 256, 0, stream>>>(gx, tnW, M);
    k_final<<<NG, 64, 0, stream>>>(gx, hx, M, tnV, tnb, scW1, scb1, scW2, scb2, alpha, out);
}

// Round 8
// 1085.478 us; speedup vs baseline: 3.7842x; 1.1131x over previous
//
#include <hip/hip_runtime.h>
#include <math.h>

#define NN 100000
#define NE 1600000
#define NG 128
#define L 32
#define H 64
#define D 256
#define TN 16
#define ONN (NN+4)

// binned CSR build params
#define BK 512                      // nodes per bucket
#define NB ((NN + BK - 1)/BK)       // 196 buckets per side
#define CAP 10240                   // staging capacity per bucket (mean 8163, +23 sigma)
#define ACH 8192                    // edges per phase-A block
#define NAB ((NE + ACH - 1)/ACH)    // 196 blocks per side

typedef unsigned short u16;

__device__ __forceinline__ float sigm(float x){ return 1.0f/(1.0f+expf(-x)); }
__device__ __forceinline__ float blo(unsigned u){ return __uint_as_float(u<<16); }
__device__ __forceinline__ float bhi(unsigned u){ return __uint_as_float(u & 0xffff0000u); }
__device__ __forceinline__ u16 f2bf(float f){
    unsigned u = __float_as_uint(f);
    unsigned r = u + 0x7fffu + ((u>>16)&1u);
    return (u16)(r>>16);
}

// ================= dual-side bounds + zero-init =================
__global__ void k_bounds2(const int* __restrict__ bat1, const int* __restrict__ bat2,
                          int* __restrict__ bs, int* __restrict__ be,
                          int* __restrict__ gcur, float* __restrict__ ssum, float* __restrict__ ap,
                          int half){
    int side = blockIdx.x >= half;
    const int* batch = side ? bat2 : bat1;
    int i = (blockIdx.x - side*half)*blockDim.x + threadIdx.x;
    if (i < NG*D){ ssum[side*NG*D + i] = 0.f; ap[side*NG*D + i] = 0.f; }
    if (i < NB) gcur[side*NB + i] = 0;
    if (i >= NN) return;
    int g = batch[i];
    if (i == 0 || batch[i-1] != g) bs[side*NG + g] = i;
    if (i == NN-1 || batch[i+1] != g) be[side*NG + g] = i + 1;
}

// ================= phase A: bin edges into 512-node buckets (staged, packed) =================
__global__ __launch_bounds__(256) void k_binA(const int* __restrict__ ei1, const int* __restrict__ ei2,
                        int* __restrict__ gcur, unsigned* __restrict__ staged, int half){
    __shared__ int hist[NB];
    __shared__ int basb[NB];
    int side = blockIdx.x >= half;
    int lb = blockIdx.x - side*half;
    const int* ei = side ? ei2 : ei1;
    const int* srcp = ei;
    const int* dstp = ei + NE;
    int e0 = lb*ACH, e1 = min(e0 + ACH, NE);
    int t = threadIdx.x;
    if (t < NB){ hist[t] = 0; }
    __syncthreads();
    for (int e = e0 + t; e < e1; e += 256)
        atomicAdd(&hist[dstp[e] >> 9], 1);
    __syncthreads();
    if (t < NB){
        int c = hist[t];
        basb[t] = (c > 0) ? atomicAdd(&gcur[side*NB + t], c) : 0;
        hist[t] = 0;
    }
    __syncthreads();
    for (int e = e0 + t; e < e1; e += 256){
        int d = dstp[e];
        int s = srcp[e];
        int b = d >> 9;
        int r = atomicAdd(&hist[b], 1);
        int pos = basb[b] + r;
        if (pos < CAP)
            staged[((size_t)(side*NB + b))*CAP + pos] = ((unsigned)s << 9) | (unsigned)(d & 511);
    }
}

// ================= bucket-base scan =================
__global__ void k_bscan(const int* __restrict__ gcur, int* __restrict__ gbase){
    __shared__ int s[256];
    int side = blockIdx.x;
    int t = threadIdx.x;
    int v = (t < NB) ? gcur[side*NB + t] : 0;
    s[t] = v;
    __syncthreads();
    for (int o = 1; o < 256; o <<= 1){
        int u = (t >= o) ? s[t-o] : 0;
        __syncthreads();
        s[t] += u;
        __syncthreads();
    }
    if (t < NB) gbase[side*NB + t] = s[t] - v;   // exclusive
}

// ================= phase B: per-bucket degree count + scan + csrc scatter =================
__global__ __launch_bounds__(256) void k_binB(const int* __restrict__ gcur, const int* __restrict__ gbase,
                        const unsigned* __restrict__ staged,
                        int* __restrict__ off, float* __restrict__ dinv, int* __restrict__ csrc){
    __shared__ int cnt[BK];
    __shared__ int loc[BK];
    __shared__ int ps[256];
    int side = blockIdx.x >= NB;
    int b = blockIdx.x - side*NB;
    int t = threadIdx.x;
    int ne = gcur[side*NB + b];
    if (ne > CAP) ne = CAP;
    int base = gbase[side*NB + b];
    const unsigned* st = staged + ((size_t)(side*NB + b))*CAP;
    cnt[2*t] = 0; cnt[2*t+1] = 0;
    __syncthreads();
    for (int e = t; e < ne; e += 256)
        atomicAdd(&cnt[st[e] & 511], 1);
    __syncthreads();
    // exclusive scan of cnt[512] with 256 threads
    int c0 = cnt[2*t], c1 = cnt[2*t+1];
    ps[t] = c0 + c1;
    __syncthreads();
    for (int o = 1; o < 256; o <<= 1){
        int u = (t >= o) ? ps[t-o] : 0;
        __syncthreads();
        ps[t] += u;
        __syncthreads();
    }
    int excl = ps[t] - (c0 + c1);
    loc[2*t] = excl;
    loc[2*t+1] = excl + c0;
    // per-node outputs
#pragma unroll
    for (int j = 0; j < 2; j++){
        int i = 2*t + j;
        int node = b*BK + i;
        if (node < NN){
            off[side*ONN + node] = base + loc[i];
            dinv[side*NN + node] = rsqrtf((float)cnt[i] + 1.0f);
        }
    }
    if (b == 0 && t == 0) off[side*ONN + NN] = NE;
    __syncthreads();
    cnt[2*t] = 0; cnt[2*t+1] = 0;
    __syncthreads();
    for (int e = t; e < ne; e += 256){
        unsigned v = st[e];
        int ld = v & 511;
        int r = atomicAdd(&cnt[ld], 1);
        csrc[side*NE + base + loc[ld] + r] = (int)(v >> 9);
    }
}

// ================= pre =================
__global__ void k_pre(const float* __restrict__ feat, const float* __restrict__ W,
                      const float* __restrict__ b, const int* __restrict__ batch,
                      const int* __restrict__ bs, const int* __restrict__ be,
                      const float* __restrict__ delta,
                      float* __restrict__ f, float* __restrict__ a){
    __shared__ float Ws[L*H];
    __shared__ float bsh[H];
    int tid = threadIdx.x;
    for (int i = tid; i < L*H; i += 256) Ws[i] = W[i];
    if (tid < H) bsh[tid] = b[tid];
    __syncthreads();
    long idx = (long)blockIdx.x*256 + tid;
    int n = (int)(idx >> 6); int h = (int)(idx & 63);
    if (n >= NN) return;
    int lane = tid & 63;
    float xv = (lane < L) ? feat[(long)n*L + lane] : 0.f;
    float v = bsh[h];
#pragma unroll
    for (int k = 0; k < L; k++) v += __shfl(xv, k, 64)*Ws[k*H+h];
    int g = batch[n];
    float nrm = rsqrtf(fmaxf((float)(be[g] - bs[g]), 1.0f));
    float fv = v*nrm;
    f[(long)n*H + h] = fv;
    a[(long)n*D + h] = fv*(1.0f + delta[0]);
}

// ================= xws_bf16 = bf16((x @ W) * dinv) : 64-node tile =================
__global__ __launch_bounds__(256) void k_gemm64(const float* __restrict__ x, int xs,
                         const float* __restrict__ W, const float* __restrict__ dinv,
                         u16* __restrict__ xb){
    __shared__ float Xl[64*65];
    __shared__ float Wl[64*64];
    int t = threadIdx.x;
    int n0 = blockIdx.x*64;
    {
        const float4* Wg = (const float4*)W;
        float4* Ws4 = (float4*)Wl;
#pragma unroll
        for (int j = 0; j < 4; j++) Ws4[t + j*256] = Wg[t + j*256];
    }
    int r = t & 15, ig = t >> 4;
#pragma unroll
    for (int p = 0; p < 4; p++){
        int i = p*16 + ig;
        int n = n0 + i;
        float4 v = {0.f,0.f,0.f,0.f};
        if (n < NN) v = *(const float4*)(x + (long)n*xs + r*4);
        Xl[i*65 + r*4 + 0] = v.x;
        Xl[i*65 + r*4 + 1] = v.y;
        Xl[i*65 + r*4 + 2] = v.z;
        Xl[i*65 + r*4 + 3] = v.w;
    }
    __syncthreads();
    float4 a0={0,0,0,0}, a1={0,0,0,0}, a2={0,0,0,0}, a3={0,0,0,0};
    const float4* Wl4 = (const float4*)Wl;
#pragma unroll
    for (int k = 0; k < 64; k++){
        float4 w = Wl4[k*16 + r];
        float x0 = Xl[(ig*4+0)*65 + k];
        float x1 = Xl[(ig*4+1)*65 + k];
        float x2 = Xl[(ig*4+2)*65 + k];
        float x3 = Xl[(ig*4+3)*65 + k];
        a0.x += x0*w.x; a0.y += x0*w.y; a0.z += x0*w.z; a0.w += x0*w.w;
        a1.x += x1*w.x; a1.y += x1*w.y; a1.z += x1*w.z; a1.w += x1*w.w;
        a2.x += x2*w.x; a2.y += x2*w.y; a2.z += x2*w.z; a2.w += x2*w.w;
        a3.x += x3*w.x; a3.y += x3*w.y; a3.z += x3*w.z; a3.w += x3*w.w;
    }
    float4 accs[4] = {a0, a1, a2, a3};
#pragma unroll
    for (int c = 0; c < 4; c++){
        int n = n0 + ig*4 + c;
        if (n < NN){
            float di = dinv[n];
            ushort4 o;
            o.x = f2bf(accs[c].x*di);
            o.y = f2bf(accs[c].y*di);
            o.z = f2bf(accs[c].z*di);
            o.w = f2bf(accs[c].w*di);
            ((ushort4*)(xb + (long)n*H))[r] = o;
        }
    }
}

// ================= fused CSR gather + combine (bf16 rows, 8-edge-parallel uint4) =================
__global__ void k_conv(const int* __restrict__ off, const int* __restrict__ csrc,
                       const float* __restrict__ dinv, const u16* __restrict__ xb,
                       const float* __restrict__ b, const float* __restrict__ xin, int xs,
                       float* __restrict__ aout, int relu_res){
    int wid  = (blockIdx.x*blockDim.x + threadIdx.x) >> 6;
    int lane = threadIdx.x & 63;
    if (wid >= NN) return;
    int q = lane >> 3, r = lane & 7;      // 8 groups x 8 lanes; row = 8 lanes * 16 B
    int d = wid;
    int e0 = off[d], e1 = off[d+1];
    const uint4* X = (const uint4*)xb;
    float acc[8] = {0.f,0.f,0.f,0.f,0.f,0.f,0.f,0.f};
    for (int base = e0; base < e1; base += 64){
        int m = min(64, e1 - base);
        int idx = (base + lane < e1) ? csrc[base + lane] : 0;
        for (int j = 0; j < m; j += 8){
            int jq = j + q;
            int s = __shfl(idx, jq, 64);
            if (jq < m){
                uint4 v = X[(long)s*8 + r];
                acc[0] += blo(v.x); acc[1] += bhi(v.x);
                acc[2] += blo(v.y); acc[3] += bhi(v.y);
                acc[4] += blo(v.z); acc[5] += bhi(v.z);
                acc[6] += blo(v.w); acc[7] += bhi(v.w);
            }
        }
    }
#pragma unroll
    for (int o = 8; o < 64; o <<= 1){
#pragma unroll
        for (int k = 0; k < 8; k++) acc[k] += __shfl_xor(acc[k], o, 64);
    }
    if (q == 0){   // lanes 0..7 hold columns r*8..r*8+7
        uint4 sv = X[(long)d*8 + r];
        float se[8] = {blo(sv.x),bhi(sv.x),blo(sv.y),bhi(sv.y),
                       blo(sv.z),bhi(sv.z),blo(sv.w),bhi(sv.w)};
        float di = dinv[d];
        const float4* bb = (const float4*)b;
        float4 b0 = bb[r*2], b1 = bb[r*2+1];
        float y[8];
#pragma unroll
        for (int k = 0; k < 4; k++) y[k]   = (acc[k]   + se[k])*di   + (&b0.x)[k];
#pragma unroll
        for (int k = 0; k < 4; k++) y[k+4] = (acc[k+4] + se[k+4])*di + (&b1.x)[k];
        if (relu_res){
            float4 x0 = *(const float4*)(xin + (long)d*xs + r*8);
            float4 x1 = *(const float4*)(xin + (long)d*xs + r*8 + 4);
#pragma unroll
            for (int k = 0; k < 4; k++) y[k]   = fmaxf(y[k],   0.f) + (&x0.x)[k];
#pragma unroll
            for (int k = 0; k < 4; k++) y[k+4] = fmaxf(y[k+4], 0.f) + (&x1.x)[k];
        }
        float4 o0 = {y[0],y[1],y[2],y[3]};
        float4 o1 = {y[4],y[5],y[6],y[7]};
        float4* op = (float4*)(aout + (long)d*D + r*8);
        op[0] = o0; op[1] = o1;
    }
}

// ================= segmented sum over sorted batch (chunk-parallel) =================
__global__ void k_segsum(const float* __restrict__ a, const int* __restrict__ batch,
                         float* __restrict__ s){
    int d = threadIdx.x;                 // 256 = D columns
    int n0 = blockIdx.x*64;
    if (n0 >= NN) return;
    int n1 = min(n0 + 64, NN);
    float acc = 0.f;
    int curg = batch[n0];
    for (int n = n0; n < n1; n++){
        int g = batch[n];
        if (g != curg){ atomicAdd(&s[curg*D + d], acc); acc = 0.f; curg = g; }
        acc += a[(long)n*D + d];
    }
    atomicAdd(&s[curg*D + d], acc);
}

// ================= t = tanh((s @ att_W) / cnt) =================
__global__ void k_ctx(const float* __restrict__ s, const float* __restrict__ attW,
                      const int* __restrict__ bs, const int* __restrict__ be,
                      float* __restrict__ t){
    int idx = blockIdx.x*256 + threadIdx.x;   // G*D
    int g = idx >> 8; int d = idx & 255;
    float inv = 1.0f/fmaxf((float)(be[g] - bs[g]), 1.0f);
    float v = 0.f;
    for (int k = 0; k < D; k++) v += s[g*D + k]*attW[k*D + d];
    t[idx] = tanhf(v*inv);
}

// ================= coef + attention pool (chunk-parallel, float4) =================
__global__ void k_coef_ap(const float* __restrict__ a, const int* __restrict__ batch,
                          const float* __restrict__ t, float* __restrict__ ap){
    int lane = threadIdx.x & 63;
    int wid  = (blockIdx.x*blockDim.x + threadIdx.x) >> 6;
    int n0 = wid*64;
    if (n0 >= NN) return;
    int n1 = min(n0 + 64, NN);
    float ax=0.f, ay=0.f, az=0.f, aw=0.f;
    int curg = batch[n0];
    for (int n = n0; n < n1; n++){
        int g = batch[n];
        const float4* ar = (const float4*)(a + (long)n*D);
        const float4* tr = (const float4*)(t + (long)g*D);
        float4 v = ar[lane];
        float4 tv = tr[lane];
        float part = v.x*tv.x + v.y*tv.y + v.z*tv.z + v.w*tv.w;
#pragma unroll
        for (int o = 32; o; o >>= 1) part += __shfl_xor(part, o, 64);
        float coef = sigm(part);
        if (g != curg){
            atomicAdd(&ap[curg*D + lane*4 + 0], ax);
            atomicAdd(&ap[curg*D + lane*4 + 1], ay);
            atomicAdd(&ap[curg*D + lane*4 + 2], az);
            atomicAdd(&ap[curg*D + lane*4 + 3], aw);
            ax = ay = az = aw = 0.f; curg = g;
        }
        ax += coef*v.x; ay += coef*v.y; az += coef*v.z; aw += coef*v.w;
    }
    atomicAdd(&ap[curg*D + lane*4 + 0], ax);
    atomicAdd(&ap[curg*D + lane*4 + 1], ay);
    atomicAdd(&ap[curg*D + lane*4 + 2], az);
    atomicAdd(&ap[curg*D + lane*4 + 3], aw);
}

// ================= per-graph MLP =================
__global__ void k_mlp2(const float* __restrict__ ap, const float* __restrict__ s,
                       const float* __restrict__ mu,
                       const float* __restrict__ W1, const float* __restrict__ b1,
                       const float* __restrict__ W2, const float* __restrict__ b2,
                       float* __restrict__ out){
    __shared__ float p[D];
    __shared__ float hid[128];
    int g = blockIdx.x; int tid = threadIdx.x;   // 128 threads
    for (int i = tid; i < D; i += 128){
        float m = mu[i];
        p[i] = m*ap[g*D + i] + (1.0f - m)*s[g*D + i];
    }
    __syncthreads();
    float v = b1[tid];
    for (int k = 0; k < D; k++) v += p[k]*W1[k*128 + tid];
    hid[tid] = fmaxf(v, 0.f);
    __syncthreads();
    if (tid < H){
        float o = b2[tid];
        for (int k = 0; k < 128; k++) o += hid[k]*W2[k*H + tid];
        out[g*H + tid] = o;
    }
}

// ================= NTN stage 1 =================
__global__ void k_ntn(const float* __restrict__ gx, const float* __restrict__ tnW,
                      float* __restrict__ M){
    __shared__ float sgx[H];
    int b = blockIdx.x;
    int g = b >> 2;
    int ek = (b & 3)*256 + threadIdx.x;
    if (threadIdx.x < H) sgx[threadIdx.x] = gx[g*H + threadIdx.x];
    __syncthreads();
    float v = 0.f;
#pragma unroll 8
    for (int d = 0; d < H; d++) v += sgx[d]*tnW[d*(H*TN) + ek];
    M[g*(H*TN) + ek] = v;
}

// ================= final scoring =================
__global__ void k_final(const float* __restrict__ gx, const float* __restrict__ hx,
                        const float* __restrict__ M, const float* __restrict__ tnV,
                        const float* __restrict__ tnb,
                        const float* __restrict__ scW1, const float* __restrict__ scb1,
                        const float* __restrict__ scW2, const float* __restrict__ scb2,
                        const float* __restrict__ alpha, float* __restrict__ outp){
    __shared__ float sg[H], sh[H], sc[TN], h2[TN];
    int g = blockIdx.x; int lane = threadIdx.x;  // 64 threads
    float gv = gx[g*H + lane], hv = hx[g*H + lane];
    sg[lane] = gv; sh[lane] = hv;
    __syncthreads();
    const float* Mg = M + g*(H*TN) + lane*TN;
    float myt1 = 0.f;
#pragma unroll
    for (int k = 0; k < TN; k++){
        float part = Mg[k]*hv;
#pragma unroll
        for (int o = 32; o; o >>= 1) part += __shfl_xor(part, o, 64);
        if (lane == k) myt1 = part;
    }
    if (lane < TN){
        float t2 = tnb[lane];
        for (int d = 0; d < H; d++) t2 += sg[d]*tnV[lane*128 + d];
        for (int e = 0; e < H; e++) t2 += sh[e]*tnV[lane*128 + 64 + e];
        sc[lane] = fmaxf(myt1 + t2, 0.f);
    }
    __syncthreads();
    if (lane < TN){
        float v = scb1[lane];
        for (int j = 0; j < TN; j++) v += sc[j]*scW1[j*TN + lane];
        h2[lane] = fmaxf(v, 0.f);
    }
    __syncthreads();
    float dff = gv - hv;
    float ssq = dff*dff;
#pragma unroll
    for (int o = 32; o; o >>= 1) ssq += __shfl_xor(ssq, o, 64);
    if (lane == 0){
        float score = scb2[0];
        for (int j = 0; j < TN; j++) score += h2[j]*scW2[j];
        float l2 = sqrtf(ssq);
        float al = alpha[0];
        outp[g] = al*sigm(score) + (1.0f - al)*(1.0f/(1.0f + expf(l2)));
    }
}

extern "C" void kernel_launch(void* const* d_in, const int* in_sizes, int n_in,
                              void* d_out, int out_size, void* d_ws, size_t ws_size,
                              hipStream_t stream) {
    const int*   ei1   = (const int*)d_in[0];
    const int*   ei2   = (const int*)d_in[1];
    const int*   bat1  = (const int*)d_in[2];
    const int*   bat2  = (const int*)d_in[3];
    const float* feat1 = (const float*)d_in[4];
    const float* feat2 = (const float*)d_in[5];
    const float* preW  = (const float*)d_in[6];
    const float* preb  = (const float*)d_in[7];
    const float* convW = (const float*)d_in[8];
    const float* convb = (const float*)d_in[9];
    const float* delta = (const float*)d_in[10];
    const float* alpha = (const float*)d_in[11];
    const float* mu    = (const float*)d_in[12];
    const float* attW  = (const float*)d_in[13];
    const float* pW1   = (const float*)d_in[14];
    const float* pb1   = (const float*)d_in[15];
    const float* pW2   = (const float*)d_in[16];
    const float* pb2   = (const float*)d_in[17];
    const float* tnW   = (const float*)d_in[18];
    const float* tnV   = (const float*)d_in[19];
    const float* tnb   = (const float*)d_in[20];
    const float* scW1  = (const float*)d_in[21];
    const float* scb1  = (const float*)d_in[22];
    const float* scW2  = (const float*)d_in[23];
    const float* scb2  = (const float*)d_in[24];
    float* out = (float*)d_out;

    // workspace carve (16 B aligned chunks); dual-side arrays indexed [side]
    char* w = (char*)d_ws;
    float*    a      = (float*)w;    w += sizeof(float)*(size_t)NN*D;
    float*    f      = (float*)w;    w += sizeof(float)*(size_t)NN*H;
    u16*      xb     = (u16*)w;      w += sizeof(u16)*(size_t)NN*H;
    float*    dinv   = (float*)w;    w += sizeof(float)*2*NN;
    int*      off    = (int*)w;      w += sizeof(int)*2*ONN;
    int*      csrc   = (int*)w;      w += sizeof(int)*2*(size_t)NE;
    unsigned* staged = (unsigned*)w; w += sizeof(unsigned)*2*(size_t)NB*CAP;
    int*      gcur   = (int*)w;      w += sizeof(int)*2*NB;
    int*      gbase  = (int*)w;      w += sizeof(int)*2*NB;
    int*      bs     = (int*)w;      w += sizeof(int)*2*NG;
    int*      be     = (int*)w;      w += sizeof(int)*2*NG;
    float*    ssum   = (float*)w;    w += sizeof(float)*2*NG*D;
    float*    tmat   = (float*)w;    w += sizeof(float)*NG*D;
    float*    ap     = (float*)w;    w += sizeof(float)*2*NG*D;
    float*    gx     = (float*)w;    w += sizeof(float)*NG*H;
    float*    hx     = (float*)w;    w += sizeof(float)*NG*H;
    float*    M      = (float*)w;    w += sizeof(float)*NG*H*TN;

    const int B = 256;
    const int gNH = (NN*H + B - 1)/B;   // 25000
    const int gN  = (NN + B - 1)/B;     // 391
    const int gT  = (NN + 63)/64;       // 1563
    const int gCoef = (gT + 3)/4;       // 391

    // ---- dual-side binned CSR build ----
    k_bounds2<<<2*gN, B, 0, stream>>>(bat1, bat2, bs, be, gcur, ssum, ap, gN);
    k_binA<<<2*NAB, B, 0, stream>>>(ei1, ei2, gcur, staged, NAB);
    k_bscan<<<2, 256, 0, stream>>>(gcur, gbase);
    k_binB<<<2*NB, B, 0, stream>>>(gcur, gbase, staged, off, dinv, csrc);

    auto run_side = [&](int side, const int* batch, const float* feat, float* gout){
        const int*   off_s  = off  + side*ONN;
        const int*   csrc_s = csrc + side*NE;
        const float* dinv_s = dinv + side*NN;
        const int*   bs_s   = bs   + side*NG;
        const int*   be_s   = be   + side*NG;
        float*       ssum_s = ssum + side*NG*D;
        float*       ap_s   = ap   + side*NG*D;

        k_pre<<<gNH, B, 0, stream>>>(feat, preW, preb, batch, bs_s, be_s, delta, f, a);

        const float* xin = f; int xs = H;
        for (int i = 0; i < 3; i++){
            k_gemm64<<<gT, B, 0, stream>>>(xin, xs, convW + i*H*H, dinv_s, xb);
            float* aout = a + (i + 1)*H;
            k_conv<<<gNH, B, 0, stream>>>(off_s, csrc_s, dinv_s, xb, convb + i*H, xin, xs, aout, i < 2 ? 1 : 0);
            xin = aout; xs = D;
        }
        k_segsum<<<gT, 256, 0, stream>>>(a, batch, ssum_s);
        k_ctx<<<NG*D/256, 256, 0, stream>>>(ssum_s, attW, bs_s, be_s, tmat);
        k_coef_ap<<<gCoef, 256, 0, stream>>>(a, batch, tmat, ap_s);
        k_mlp2<<<NG, 128, 0, stream>>>(ap_s, ssum_s, mu, pW1, pb1, pW2, pb2, gout);
    };

    run_side(0, bat1, feat1, gx);
    run_side(1, bat2, feat2, hx);
    k_ntn<<<NG*4, 256, 0, stream>>>(gx, tnW, M);
    k_final<<<NG, 64, 0, stream>>>(gx, hx, M, tnV, tnb, scW1, scb1, scW2, scb2, alpha, out);
}

// Round 9
// 1030.030 us; speedup vs baseline: 3.9879x; 1.0538x over previous
//
#include <hip/hip_runtime.h>
#include <math.h>

#define NN 100000
#define NE 1600000
#define NG 128
#define L 32
#define H 64
#define D 256
#define TN 16
#define ONN (NN+4)

// binned CSR build params
#define BK 512
#define NB ((NN + BK - 1)/BK)
#define CAP 10240
#define ACH 8192
#define NAB ((NE + ACH - 1)/ACH)

typedef unsigned short u16;

__device__ __forceinline__ float sigm(float x){ return 1.0f/(1.0f+expf(-x)); }
__device__ __forceinline__ float blo(unsigned u){ return __uint_as_float(u<<16); }
__device__ __forceinline__ float bhi(unsigned u){ return __uint_as_float(u & 0xffff0000u); }
__device__ __forceinline__ u16 f2bf(float f){
    unsigned u = __float_as_uint(f);
    unsigned r = u + 0x7fffu + ((u>>16)&1u);
    return (u16)(r>>16);
}

// ================= dual-side bounds + zero-init =================
__global__ void k_bounds2(const int* __restrict__ bat1, const int* __restrict__ bat2,
                          int* __restrict__ bs, int* __restrict__ be,
                          int* __restrict__ gcur, float* __restrict__ ssum, float* __restrict__ ap,
                          int half){
    int side = blockIdx.x >= half;
    const int* batch = side ? bat2 : bat1;
    int i = (blockIdx.x - side*half)*blockDim.x + threadIdx.x;
    if (i < NG*D){ ssum[side*NG*D + i] = 0.f; ap[side*NG*D + i] = 0.f; }
    if (i < NB) gcur[side*NB + i] = 0;
    if (i >= NN) return;
    int g = batch[i];
    if (i == 0 || batch[i-1] != g) bs[side*NG + g] = i;
    if (i == NN-1 || batch[i+1] != g) be[side*NG + g] = i + 1;
}

// ================= phase A: bin edges into 512-node buckets =================
__global__ __launch_bounds__(256) void k_binA(const int* __restrict__ ei1, const int* __restrict__ ei2,
                        int* __restrict__ gcur, unsigned* __restrict__ staged, int half){
    __shared__ int hist[NB];
    __shared__ int basb[NB];
    int side = blockIdx.x >= half;
    int lb = blockIdx.x - side*half;
    const int* ei = side ? ei2 : ei1;
    const int* srcp = ei;
    const int* dstp = ei + NE;
    int e0 = lb*ACH, e1 = min(e0 + ACH, NE);
    int t = threadIdx.x;
    if (t < NB){ hist[t] = 0; }
    __syncthreads();
    for (int e = e0 + t; e < e1; e += 256)
        atomicAdd(&hist[dstp[e] >> 9], 1);
    __syncthreads();
    if (t < NB){
        int c = hist[t];
        basb[t] = (c > 0) ? atomicAdd(&gcur[side*NB + t], c) : 0;
        hist[t] = 0;
    }
    __syncthreads();
    for (int e = e0 + t; e < e1; e += 256){
        int d = dstp[e];
        int s = srcp[e];
        int b = d >> 9;
        int r = atomicAdd(&hist[b], 1);
        int pos = basb[b] + r;
        if (pos < CAP)
            staged[((size_t)(side*NB + b))*CAP + pos] = ((unsigned)s << 9) | (unsigned)(d & 511);
    }
}

// ================= bucket-base scan =================
__global__ void k_bscan(const int* __restrict__ gcur, int* __restrict__ gbase){
    __shared__ int s[256];
    int side = blockIdx.x;
    int t = threadIdx.x;
    int v = (t < NB) ? gcur[side*NB + t] : 0;
    s[t] = v;
    __syncthreads();
    for (int o = 1; o < 256; o <<= 1){
        int u = (t >= o) ? s[t-o] : 0;
        __syncthreads();
        s[t] += u;
        __syncthreads();
    }
    if (t < NB) gbase[side*NB + t] = s[t] - v;
}

// ================= phase B: per-bucket count + scan + scatter =================
__global__ __launch_bounds__(256) void k_binB(const int* __restrict__ gcur, const int* __restrict__ gbase,
                        const unsigned* __restrict__ staged,
                        int* __restrict__ off, float* __restrict__ dinv, int* __restrict__ csrc){
    __shared__ int cnt[BK];
    __shared__ int loc[BK];
    __shared__ int ps[256];
    int side = blockIdx.x >= NB;
    int b = blockIdx.x - side*NB;
    int t = threadIdx.x;
    int ne = gcur[side*NB + b];
    if (ne > CAP) ne = CAP;
    int base = gbase[side*NB + b];
    const unsigned* st = staged + ((size_t)(side*NB + b))*CAP;
    cnt[2*t] = 0; cnt[2*t+1] = 0;
    __syncthreads();
    for (int e = t; e < ne; e += 256)
        atomicAdd(&cnt[st[e] & 511], 1);
    __syncthreads();
    int c0 = cnt[2*t], c1 = cnt[2*t+1];
    ps[t] = c0 + c1;
    __syncthreads();
    for (int o = 1; o < 256; o <<= 1){
        int u = (t >= o) ? ps[t-o] : 0;
        __syncthreads();
        ps[t] += u;
        __syncthreads();
    }
    int excl = ps[t] - (c0 + c1);
    loc[2*t] = excl;
    loc[2*t+1] = excl + c0;
#pragma unroll
    for (int j = 0; j < 2; j++){
        int i = 2*t + j;
        int node = b*BK + i;
        if (node < NN){
            off[side*ONN + node] = base + loc[i];
            dinv[side*NN + node] = rsqrtf((float)cnt[i] + 1.0f);
        }
    }
    if (b == 0 && t == 0) off[side*ONN + NN] = NE;
    __syncthreads();
    cnt[2*t] = 0; cnt[2*t+1] = 0;
    __syncthreads();
    for (int e = t; e < ne; e += 256){
        unsigned v = st[e];
        int ld = v & 511;
        int r = atomicAdd(&cnt[ld], 1);
        csrc[side*NE + base + loc[ld] + r] = (int)(v >> 9);
    }
}

// ================= pre (GEMM-style, 64-node tile, 4x4 blocking) =================
__global__ __launch_bounds__(256) void k_pre(const float* __restrict__ feat, const float* __restrict__ W,
                      const float* __restrict__ b, const int* __restrict__ batch,
                      const int* __restrict__ bs, const int* __restrict__ be,
                      const float* __restrict__ delta,
                      float* __restrict__ f, float* __restrict__ a){
    __shared__ float Xl[64*33];   // 64 nodes x 32 feats, stride 33
    __shared__ float Wl[L*H];     // k-major: Wl[k*64+h]
    __shared__ float bsh[H];
    int t = threadIdx.x;
    int n0 = blockIdx.x*64;
    {   // W: 2048 floats = 512 float4
        const float4* Wg = (const float4*)W;
        float4* Wv = (float4*)Wl;
        Wv[t] = Wg[t];
        Wv[t+256] = Wg[t+256];
        if (t < H) bsh[t] = b[t];
    }
    {   // X: 64 rows x 32 floats = 512 float4
        int rr = t & 7;
        int ii = t >> 3;          // 0..31
#pragma unroll
        for (int p = 0; p < 2; p++){
            int i = p*32 + ii;
            int n = n0 + i;
            float4 v = {0.f,0.f,0.f,0.f};
            if (n < NN) v = *(const float4*)(feat + (long)n*L + rr*4);
            Xl[i*33 + rr*4 + 0] = v.x;
            Xl[i*33 + rr*4 + 1] = v.y;
            Xl[i*33 + rr*4 + 2] = v.z;
            Xl[i*33 + rr*4 + 3] = v.w;
        }
    }
    __syncthreads();
    int r = t & 15, ig = t >> 4;
    float4 a0={0,0,0,0}, a1={0,0,0,0}, a2={0,0,0,0}, a3={0,0,0,0};
    const float4* Wl4 = (const float4*)Wl;
#pragma unroll
    for (int k = 0; k < L; k++){
        float4 w = Wl4[k*16 + r];
        float x0 = Xl[(ig*4+0)*33 + k];
        float x1 = Xl[(ig*4+1)*33 + k];
        float x2 = Xl[(ig*4+2)*33 + k];
        float x3 = Xl[(ig*4+3)*33 + k];
        a0.x += x0*w.x; a0.y += x0*w.y; a0.z += x0*w.z; a0.w += x0*w.w;
        a1.x += x1*w.x; a1.y += x1*w.y; a1.z += x1*w.z; a1.w += x1*w.w;
        a2.x += x2*w.x; a2.y += x2*w.y; a2.z += x2*w.z; a2.w += x2*w.w;
        a3.x += x3*w.x; a3.y += x3*w.y; a3.z += x3*w.z; a3.w += x3*w.w;
    }
    float4 accs[4] = {a0, a1, a2, a3};
    float4 bv = ((const float4*)bsh)[r];
    float dl = 1.0f + delta[0];
#pragma unroll
    for (int c = 0; c < 4; c++){
        int n = n0 + ig*4 + c;
        if (n < NN){
            int g = batch[n];
            float nrm = rsqrtf(fmaxf((float)(be[g] - bs[g]), 1.0f));
            float4 fv;
            fv.x = (accs[c].x + bv.x)*nrm;
            fv.y = (accs[c].y + bv.y)*nrm;
            fv.z = (accs[c].z + bv.z)*nrm;
            fv.w = (accs[c].w + bv.w)*nrm;
            *(float4*)(f + (long)n*H + r*4) = fv;
            float4 av; av.x = fv.x*dl; av.y = fv.y*dl; av.z = fv.z*dl; av.w = fv.w*dl;
            *(float4*)(a + (long)n*D + r*4) = av;
        }
    }
}

// ================= xws_bf16 = bf16((x @ W) * dinv) : 64-node tile =================
__global__ __launch_bounds__(256) void k_gemm64(const float* __restrict__ x, int xs,
                         const float* __restrict__ W, const float* __restrict__ dinv,
                         u16* __restrict__ xb){
    __shared__ float Xl[64*65];
    __shared__ float Wl[64*64];
    int t = threadIdx.x;
    int n0 = blockIdx.x*64;
    {
        const float4* Wg = (const float4*)W;
        float4* Ws4 = (float4*)Wl;
#pragma unroll
        for (int j = 0; j < 4; j++) Ws4[t + j*256] = Wg[t + j*256];
    }
    int r = t & 15, ig = t >> 4;
#pragma unroll
    for (int p = 0; p < 4; p++){
        int i = p*16 + ig;
        int n = n0 + i;
        float4 v = {0.f,0.f,0.f,0.f};
        if (n < NN) v = *(const float4*)(x + (long)n*xs + r*4);
        Xl[i*65 + r*4 + 0] = v.x;
        Xl[i*65 + r*4 + 1] = v.y;
        Xl[i*65 + r*4 + 2] = v.z;
        Xl[i*65 + r*4 + 3] = v.w;
    }
    __syncthreads();
    float4 a0={0,0,0,0}, a1={0,0,0,0}, a2={0,0,0,0}, a3={0,0,0,0};
    const float4* Wl4 = (const float4*)Wl;
#pragma unroll
    for (int k = 0; k < 64; k++){
        float4 w = Wl4[k*16 + r];
        float x0 = Xl[(ig*4+0)*65 + k];
        float x1 = Xl[(ig*4+1)*65 + k];
        float x2 = Xl[(ig*4+2)*65 + k];
        float x3 = Xl[(ig*4+3)*65 + k];
        a0.x += x0*w.x; a0.y += x0*w.y; a0.z += x0*w.z; a0.w += x0*w.w;
        a1.x += x1*w.x; a1.y += x1*w.y; a1.z += x1*w.z; a1.w += x1*w.w;
        a2.x += x2*w.x; a2.y += x2*w.y; a2.z += x2*w.z; a2.w += x2*w.w;
        a3.x += x3*w.x; a3.y += x3*w.y; a3.z += x3*w.z; a3.w += x3*w.w;
    }
    float4 accs[4] = {a0, a1, a2, a3};
#pragma unroll
    for (int c = 0; c < 4; c++){
        int n = n0 + ig*4 + c;
        if (n < NN){
            float di = dinv[n];
            ushort4 o;
            o.x = f2bf(accs[c].x*di);
            o.y = f2bf(accs[c].y*di);
            o.z = f2bf(accs[c].z*di);
            o.w = f2bf(accs[c].w*di);
            ((ushort4*)(xb + (long)n*H))[r] = o;
        }
    }
}

// ================= fused CSR gather + combine (bf16 rows, 8-edge-parallel uint4) =================
__global__ void k_conv(const int* __restrict__ off, const int* __restrict__ csrc,
                       const float* __restrict__ dinv, const u16* __restrict__ xb,
                       const float* __restrict__ b, const float* __restrict__ xin, int xs,
                       float* __restrict__ aout, int relu_res){
    int wid  = (blockIdx.x*blockDim.x + threadIdx.x) >> 6;
    int lane = threadIdx.x & 63;
    if (wid >= NN) return;
    int q = lane >> 3, r = lane & 7;
    int d = wid;
    int e0 = off[d], e1 = off[d+1];
    const uint4* X = (const uint4*)xb;
    float acc[8] = {0.f,0.f,0.f,0.f,0.f,0.f,0.f,0.f};
    for (int base = e0; base < e1; base += 64){
        int m = min(64, e1 - base);
        int idx = (base + lane < e1) ? csrc[base + lane] : 0;
        for (int j = 0; j < m; j += 8){
            int jq = j + q;
            int s = __shfl(idx, jq, 64);
            if (jq < m){
                uint4 v = X[(long)s*8 + r];
                acc[0] += blo(v.x); acc[1] += bhi(v.x);
                acc[2] += blo(v.y); acc[3] += bhi(v.y);
                acc[4] += blo(v.z); acc[5] += bhi(v.z);
                acc[6] += blo(v.w); acc[7] += bhi(v.w);
            }
        }
    }
#pragma unroll
    for (int o = 8; o < 64; o <<= 1){
#pragma unroll
        for (int k = 0; k < 8; k++) acc[k] += __shfl_xor(acc[k], o, 64);
    }
    if (q == 0){
        uint4 sv = X[(long)d*8 + r];
        float se[8] = {blo(sv.x),bhi(sv.x),blo(sv.y),bhi(sv.y),
                       blo(sv.z),bhi(sv.z),blo(sv.w),bhi(sv.w)};
        float di = dinv[d];
        const float4* bb = (const float4*)b;
        float4 b0 = bb[r*2], b1 = bb[r*2+1];
        float y[8];
#pragma unroll
        for (int k = 0; k < 4; k++) y[k]   = (acc[k]   + se[k])*di   + (&b0.x)[k];
#pragma unroll
        for (int k = 0; k < 4; k++) y[k+4] = (acc[k+4] + se[k+4])*di + (&b1.x)[k];
        if (relu_res){
            float4 x0 = *(const float4*)(xin + (long)d*xs + r*8);
            float4 x1 = *(const float4*)(xin + (long)d*xs + r*8 + 4);
#pragma unroll
            for (int k = 0; k < 4; k++) y[k]   = fmaxf(y[k],   0.f) + (&x0.x)[k];
#pragma unroll
            for (int k = 0; k < 4; k++) y[k+4] = fmaxf(y[k+4], 0.f) + (&x1.x)[k];
        }
        float4 o0 = {y[0],y[1],y[2],y[3]};
        float4 o1 = {y[4],y[5],y[6],y[7]};
        float4* op = (float4*)(aout + (long)d*D + r*8);
        op[0] = o0; op[1] = o1;
    }
}

// ================= segmented sum over sorted batch =================
__global__ void k_segsum(const float* __restrict__ a, const int* __restrict__ batch,
                         float* __restrict__ s){
    int d = threadIdx.x;
    int n0 = blockIdx.x*64;
    if (n0 >= NN) return;
    int n1 = min(n0 + 64, NN);
    float acc = 0.f;
    int curg = batch[n0];
    for (int n = n0; n < n1; n++){
        int g = batch[n];
        if (g != curg){ atomicAdd(&s[curg*D + d], acc); acc = 0.f; curg = g; }
        acc += a[(long)n*D + d];
    }
    atomicAdd(&s[curg*D + d], acc);
}

// ================= t = tanh((s @ att_W) / cnt) =================
__global__ void k_ctx(const float* __restrict__ s, const float* __restrict__ attW,
                      const int* __restrict__ bs, const int* __restrict__ be,
                      float* __restrict__ t){
    int idx = blockIdx.x*256 + threadIdx.x;
    int g = idx >> 8; int d = idx & 255;
    float inv = 1.0f/fmaxf((float)(be[g] - bs[g]), 1.0f);
    float v = 0.f;
    for (int k = 0; k < D; k++) v += s[g*D + k]*attW[k*D + d];
    t[idx] = tanhf(v*inv);
}

// ================= coef + attention pool =================
__global__ void k_coef_ap(const float* __restrict__ a, const int* __restrict__ batch,
                          const float* __restrict__ t, float* __restrict__ ap){
    int lane = threadIdx.x & 63;
    int wid  = (blockIdx.x*blockDim.x + threadIdx.x) >> 6;
    int n0 = wid*64;
    if (n0 >= NN) return;
    int n1 = min(n0 + 64, NN);
    float ax=0.f, ay=0.f, az=0.f, aw=0.f;
    int curg = batch[n0];
    for (int n = n0; n < n1; n++){
        int g = batch[n];
        const float4* ar = (const float4*)(a + (long)n*D);
        const float4* tr = (const float4*)(t + (long)g*D);
        float4 v = ar[lane];
        float4 tv = tr[lane];
        float part = v.x*tv.x + v.y*tv.y + v.z*tv.z + v.w*tv.w;
#pragma unroll
        for (int o = 32; o; o >>= 1) part += __shfl_xor(part, o, 64);
        float coef = sigm(part);
        if (g != curg){
            atomicAdd(&ap[curg*D + lane*4 + 0], ax);
            atomicAdd(&ap[curg*D + lane*4 + 1], ay);
            atomicAdd(&ap[curg*D + lane*4 + 2], az);
            atomicAdd(&ap[curg*D + lane*4 + 3], aw);
            ax = ay = az = aw = 0.f; curg = g;
        }
        ax += coef*v.x; ay += coef*v.y; az += coef*v.z; aw += coef*v.w;
    }
    atomicAdd(&ap[curg*D + lane*4 + 0], ax);
    atomicAdd(&ap[curg*D + lane*4 + 1], ay);
    atomicAdd(&ap[curg*D + lane*4 + 2], az);
    atomicAdd(&ap[curg*D + lane*4 + 3], aw);
}

// ================= per-graph MLP =================
__global__ void k_mlp2(const float* __restrict__ ap, const float* __restrict__ s,
                       const float* __restrict__ mu,
                       const float* __restrict__ W1, const float* __restrict__ b1,
                       const float* __restrict__ W2, const float* __restrict__ b2,
                       float* __restrict__ out){
    __shared__ float p[D];
    __shared__ float hid[128];
    int g = blockIdx.x; int tid = threadIdx.x;
    for (int i = tid; i < D; i += 128){
        float m = mu[i];
        p[i] = m*ap[g*D + i] + (1.0f - m)*s[g*D + i];
    }
    __syncthreads();
    float v = b1[tid];
    for (int k = 0; k < D; k++) v += p[k]*W1[k*128 + tid];
    hid[tid] = fmaxf(v, 0.f);
    __syncthreads();
    if (tid < H){
        float o = b2[tid];
        for (int k = 0; k < 128; k++) o += hid[k]*W2[k*H + tid];
        out[g*H + tid] = o;
    }
}

// ================= NTN stage 1 =================
__global__ void k_ntn(const float* __restrict__ gx, const float* __restrict__ tnW,
                      float* __restrict__ M){
    __shared__ float sgx[H];
    int b = blockIdx.x;
    int g = b >> 2;
    int ek = (b & 3)*256 + threadIdx.x;
    if (threadIdx.x < H) sgx[threadIdx.x] = gx[g*H + threadIdx.x];
    __syncthreads();
    float v = 0.f;
#pragma unroll 8
    for (int d = 0; d < H; d++) v += sgx[d]*tnW[d*(H*TN) + ek];
    M[g*(H*TN) + ek] = v;
}

// ================= final scoring =================
__global__ void k_final(const float* __restrict__ gx, const float* __restrict__ hx,
                        const float* __restrict__ M, const float* __restrict__ tnV,
                        const float* __restrict__ tnb,
                        const float* __restrict__ scW1, const float* __restrict__ scb1,
                        const float* __restrict__ scW2, const float* __restrict__ scb2,
                        const float* __restrict__ alpha, float* __restrict__ outp){
    __shared__ float sg[H], sh[H], sc[TN], h2[TN];
    int g = blockIdx.x; int lane = threadIdx.x;
    float gv = gx[g*H + lane], hv = hx[g*H + lane];
    sg[lane] = gv; sh[lane] = hv;
    __syncthreads();
    const float* Mg = M + g*(H*TN) + lane*TN;
    float myt1 = 0.f;
#pragma unroll
    for (int k = 0; k < TN; k++){
        float part = Mg[k]*hv;
#pragma unroll
        for (int o = 32; o; o >>= 1) part += __shfl_xor(part, o, 64);
        if (lane == k) myt1 = part;
    }
    if (lane < TN){
        float t2 = tnb[lane];
        for (int d = 0; d < H; d++) t2 += sg[d]*tnV[lane*128 + d];
        for (int e = 0; e < H; e++) t2 += sh[e]*tnV[lane*128 + 64 + e];
        sc[lane] = fmaxf(myt1 + t2, 0.f);
    }
    __syncthreads();
    if (lane < TN){
        float v = scb1[lane];
        for (int j = 0; j < TN; j++) v += sc[j]*scW1[j*TN + lane];
        h2[lane] = fmaxf(v, 0.f);
    }
    __syncthreads();
    float dff = gv - hv;
    float ssq = dff*dff;
#pragma unroll
    for (int o = 32; o; o >>= 1) ssq += __shfl_xor(ssq, o, 64);
    if (lane == 0){
        float score = scb2[0];
        for (int j = 0; j < TN; j++) score += h2[j]*scW2[j];
        float l2 = sqrtf(ssq);
        float al = alpha[0];
        outp[g] = al*sigm(score) + (1.0f - al)*(1.0f/(1.0f + expf(l2)));
    }
}

extern "C" void kernel_launch(void* const* d_in, const int* in_sizes, int n_in,
                              void* d_out, int out_size, void* d_ws, size_t ws_size,
                              hipStream_t stream) {
    const int*   ei1   = (const int*)d_in[0];
    const int*   ei2   = (const int*)d_in[1];
    const int*   bat1  = (const int*)d_in[2];
    const int*   bat2  = (const int*)d_in[3];
    const float* feat1 = (const float*)d_in[4];
    const float* feat2 = (const float*)d_in[5];
    const float* preW  = (const float*)d_in[6];
    const float* preb  = (const float*)d_in[7];
    const float* convW = (const float*)d_in[8];
    const float* convb = (const float*)d_in[9];
    const float* delta = (const float*)d_in[10];
    const float* alpha = (const float*)d_in[11];
    const float* mu    = (const float*)d_in[12];
    const float* attW  = (const float*)d_in[13];
    const float* pW1   = (const float*)d_in[14];
    const float* pb1   = (const float*)d_in[15];
    const float* pW2   = (const float*)d_in[16];
    const float* pb2   = (const float*)d_in[17];
    const float* tnW   = (const float*)d_in[18];
    const float* tnV   = (const float*)d_in[19];
    const float* tnb   = (const float*)d_in[20];
    const float* scW1  = (const float*)d_in[21];
    const float* scb1  = (const float*)d_in[22];
    const float* scW2  = (const float*)d_in[23];
    const float* scb2  = (const float*)d_in[24];
    float* out = (float*)d_out;

    // workspace carve (16 B aligned chunks); dual-side arrays indexed [side]
    char* w = (char*)d_ws;
    float*    a      = (float*)w;    w += sizeof(float)*(size_t)NN*D;
    float*    f      = (float*)w;    w += sizeof(float)*(size_t)NN*H;
    u16*      xb     = (u16*)w;      w += sizeof(u16)*(size_t)NN*H;
    float*    dinv   = (float*)w;    w += sizeof(float)*2*NN;
    int*      off    = (int*)w;      w += sizeof(int)*2*ONN;
    int*      csrc   = (int*)w;      w += sizeof(int)*2*(size_t)NE;
    unsigned* staged = (unsigned*)w; w += sizeof(unsigned)*2*(size_t)NB*CAP;
    int*      gcur   = (int*)w;      w += sizeof(int)*2*NB;
    int*      gbase  = (int*)w;      w += sizeof(int)*2*NB;
    int*      bs     = (int*)w;      w += sizeof(int)*2*NG;
    int*      be     = (int*)w;      w += sizeof(int)*2*NG;
    float*    ssum   = (float*)w;    w += sizeof(float)*2*NG*D;
    float*    tmat   = (float*)w;    w += sizeof(float)*NG*D;
    float*    ap     = (float*)w;    w += sizeof(float)*2*NG*D;
    float*    gx     = (float*)w;    w += sizeof(float)*NG*H;
    float*    hx     = (float*)w;    w += sizeof(float)*NG*H;
    float*    M      = (float*)w;    w += sizeof(float)*NG*H*TN;

    const int B = 256;
    const int gNH = (NN*H + B - 1)/B;   // 25000
    const int gN  = (NN + B - 1)/B;     // 391
    const int gT  = (NN + 63)/64;       // 1563
    const int gCoef = (gT + 3)/4;       // 391

    // ---- dual-side binned CSR build ----
    k_bounds2<<<2*gN, B, 0, stream>>>(bat1, bat2, bs, be, gcur, ssum, ap, gN);
    k_binA<<<2*NAB, B, 0, stream>>>(ei1, ei2, gcur, staged, NAB);
    k_bscan<<<2, 256, 0, stream>>>(gcur, gbase);
    k_binB<<<2*NB, B, 0, stream>>>(gcur, gbase, staged, off, dinv, csrc);

    auto run_side = [&](int side, const int* batch, const float* feat, float* gout){
        const int*   off_s  = off  + side*ONN;
        const int*   csrc_s = csrc + side*NE;
        const float* dinv_s = dinv + side*NN;
        const int*   bs_s   = bs   + side*NG;
        const int*   be_s   = be   + side*NG;
        float*       ssum_s = ssum + side*NG*D;
        float*       ap_s   = ap   + side*NG*D;

        k_pre<<<gT, B, 0, stream>>>(feat, preW, preb, batch, bs_s, be_s, delta, f, a);

        const float* xin = f; int xs = H;
        for (int i = 0; i < 3; i++){
            k_gemm64<<<gT, B, 0, stream>>>(xin, xs, convW + i*H*H, dinv_s, xb);
            float* aout = a + (i + 1)*H;
            k_conv<<<gNH, B, 0, stream>>>(off_s, csrc_s, dinv_s, xb, convb + i*H, xin, xs, aout, i < 2 ? 1 : 0);
            xin = aout; xs = D;
        }
        k_segsum<<<gT, 256, 0, stream>>>(a, batch, ssum_s);
        k_ctx<<<NG*D/256, 256, 0, stream>>>(ssum_s, attW, bs_s, be_s, tmat);
        k_coef_ap<<<gCoef, 256, 0, stream>>>(a, batch, tmat, ap_s);
        k_mlp2<<<NG, 128, 0, stream>>>(ap_s, ssum_s, mu, pW1, pb1, pW2, pb2, gout);
    };

    run_side(0, bat1, feat1, gx);
    run_side(1, bat2, feat2, hx);
    k_ntn<<<NG*4, 256, 0, stream>>>(gx, tnW, M);
    k_final<<<NG, 64, 0, stream>>>(gx, hx, M, tnV, tnb, scW1, scb1, scW2, scb2, alpha, out);
}

// Round 10
// 840.279 us; speedup vs baseline: 4.8885x; 1.2258x over previous
//
#include <hip/hip_runtime.h>
#include <math.h>

#define NN 100000
#define NE 1600000
#define NG 128
#define L 32
#define H 64
#define D 256
#define TN 16
#define ONN (NN+4)

// binned CSR build params
#define BK 512
#define NB ((NN + BK - 1)/BK)
#define CAP 10240
#define ACH 8192
#define NAB ((NE + ACH - 1)/ACH)

// MFMA gemm tile
#define GB 128                       // nodes per block (2 row-tiles per wave)

typedef unsigned short u16;
typedef __attribute__((ext_vector_type(8))) short bf16x8;
typedef __attribute__((ext_vector_type(4))) float f32x4;

__device__ __forceinline__ float sigm(float x){ return 1.0f/(1.0f+expf(-x)); }
__device__ __forceinline__ float blo(unsigned u){ return __uint_as_float(u<<16); }
__device__ __forceinline__ float bhi(unsigned u){ return __uint_as_float(u & 0xffff0000u); }
__device__ __forceinline__ u16 f2bf(float f){
    unsigned u = __float_as_uint(f);
    unsigned r = u + 0x7fffu + ((u>>16)&1u);
    return (u16)(r>>16);
}

// ================= dual-side bounds + zero-init =================
__global__ void k_bounds2(const int* __restrict__ bat1, const int* __restrict__ bat2,
                          int* __restrict__ bs, int* __restrict__ be,
                          int* __restrict__ gcur, float* __restrict__ ssum, float* __restrict__ ap,
                          int half){
    int side = blockIdx.x >= half;
    const int* batch = side ? bat2 : bat1;
    int i = (blockIdx.x - side*half)*blockDim.x + threadIdx.x;
    if (i < NG*D){ ssum[side*NG*D + i] = 0.f; ap[side*NG*D + i] = 0.f; }
    if (i < NB) gcur[side*NB + i] = 0;
    if (i >= NN) return;
    int g = batch[i];
    if (i == 0 || batch[i-1] != g) bs[side*NG + g] = i;
    if (i == NN-1 || batch[i+1] != g) be[side*NG + g] = i + 1;
}

// ================= phase A: bin edges into 512-node buckets =================
__global__ __launch_bounds__(256) void k_binA(const int* __restrict__ ei1, const int* __restrict__ ei2,
                        int* __restrict__ gcur, unsigned* __restrict__ staged, int half){
    __shared__ int hist[NB];
    __shared__ int basb[NB];
    int side = blockIdx.x >= half;
    int lb = blockIdx.x - side*half;
    const int* ei = side ? ei2 : ei1;
    const int* srcp = ei;
    const int* dstp = ei + NE;
    int e0 = lb*ACH, e1 = min(e0 + ACH, NE);
    int t = threadIdx.x;
    if (t < NB){ hist[t] = 0; }
    __syncthreads();
    for (int e = e0 + t; e < e1; e += 256)
        atomicAdd(&hist[dstp[e] >> 9], 1);
    __syncthreads();
    if (t < NB){
        int c = hist[t];
        basb[t] = (c > 0) ? atomicAdd(&gcur[side*NB + t], c) : 0;
        hist[t] = 0;
    }
    __syncthreads();
    for (int e = e0 + t; e < e1; e += 256){
        int d = dstp[e];
        int s = srcp[e];
        int b = d >> 9;
        int r = atomicAdd(&hist[b], 1);
        int pos = basb[b] + r;
        if (pos < CAP)
            staged[((size_t)(side*NB + b))*CAP + pos] = ((unsigned)s << 9) | (unsigned)(d & 511);
    }
}

// ================= bucket-base scan =================
__global__ void k_bscan(const int* __restrict__ gcur, int* __restrict__ gbase){
    __shared__ int s[256];
    int side = blockIdx.x;
    int t = threadIdx.x;
    int v = (t < NB) ? gcur[side*NB + t] : 0;
    s[t] = v;
    __syncthreads();
    for (int o = 1; o < 256; o <<= 1){
        int u = (t >= o) ? s[t-o] : 0;
        __syncthreads();
        s[t] += u;
        __syncthreads();
    }
    if (t < NB) gbase[side*NB + t] = s[t] - v;
}

// ================= phase B: per-bucket count + scan + scatter =================
__global__ __launch_bounds__(256) void k_binB(const int* __restrict__ gcur, const int* __restrict__ gbase,
                        const unsigned* __restrict__ staged,
                        int* __restrict__ off, float* __restrict__ dinv, int* __restrict__ csrc){
    __shared__ int cnt[BK];
    __shared__ int loc[BK];
    __shared__ int ps[256];
    int side = blockIdx.x >= NB;
    int b = blockIdx.x - side*NB;
    int t = threadIdx.x;
    int ne = gcur[side*NB + b];
    if (ne > CAP) ne = CAP;
    int base = gbase[side*NB + b];
    const unsigned* st = staged + ((size_t)(side*NB + b))*CAP;
    cnt[2*t] = 0; cnt[2*t+1] = 0;
    __syncthreads();
    for (int e = t; e < ne; e += 256)
        atomicAdd(&cnt[st[e] & 511], 1);
    __syncthreads();
    int c0 = cnt[2*t], c1 = cnt[2*t+1];
    ps[t] = c0 + c1;
    __syncthreads();
    for (int o = 1; o < 256; o <<= 1){
        int u = (t >= o) ? ps[t-o] : 0;
        __syncthreads();
        ps[t] += u;
        __syncthreads();
    }
    int excl = ps[t] - (c0 + c1);
    loc[2*t] = excl;
    loc[2*t+1] = excl + c0;
#pragma unroll
    for (int j = 0; j < 2; j++){
        int i = 2*t + j;
        int node = b*BK + i;
        if (node < NN){
            off[side*ONN + node] = base + loc[i];
            dinv[side*NN + node] = rsqrtf((float)cnt[i] + 1.0f);
        }
    }
    if (b == 0 && t == 0) off[side*ONN + NN] = NE;
    __syncthreads();
    cnt[2*t] = 0; cnt[2*t+1] = 0;
    __syncthreads();
    for (int e = t; e < ne; e += 256){
        unsigned v = st[e];
        int ld = v & 511;
        int r = atomicAdd(&cnt[ld], 1);
        csrc[side*NE + base + loc[ld] + r] = (int)(v >> 9);
    }
}

// ================= pre (GEMM-style, 64-node tile, 4x4 blocking) =================
__global__ __launch_bounds__(256) void k_pre(const float* __restrict__ feat, const float* __restrict__ W,
                      const float* __restrict__ b, const int* __restrict__ batch,
                      const int* __restrict__ bs, const int* __restrict__ be,
                      const float* __restrict__ delta,
                      float* __restrict__ f, float* __restrict__ a){
    __shared__ float Xl[64*33];
    __shared__ float Wl[L*H];
    __shared__ float bsh[H];
    int t = threadIdx.x;
    int n0 = blockIdx.x*64;
    {
        const float4* Wg = (const float4*)W;
        float4* Wv = (float4*)Wl;
        Wv[t] = Wg[t];
        Wv[t+256] = Wg[t+256];
        if (t < H) bsh[t] = b[t];
    }
    {
        int rr = t & 7;
        int ii = t >> 3;
#pragma unroll
        for (int p = 0; p < 2; p++){
            int i = p*32 + ii;
            int n = n0 + i;
            float4 v = {0.f,0.f,0.f,0.f};
            if (n < NN) v = *(const float4*)(feat + (long)n*L + rr*4);
            Xl[i*33 + rr*4 + 0] = v.x;
            Xl[i*33 + rr*4 + 1] = v.y;
            Xl[i*33 + rr*4 + 2] = v.z;
            Xl[i*33 + rr*4 + 3] = v.w;
        }
    }
    __syncthreads();
    int r = t & 15, ig = t >> 4;
    float4 a0={0,0,0,0}, a1={0,0,0,0}, a2={0,0,0,0}, a3={0,0,0,0};
    const float4* Wl4 = (const float4*)Wl;
#pragma unroll
    for (int k = 0; k < L; k++){
        float4 w = Wl4[k*16 + r];
        float x0 = Xl[(ig*4+0)*33 + k];
        float x1 = Xl[(ig*4+1)*33 + k];
        float x2 = Xl[(ig*4+2)*33 + k];
        float x3 = Xl[(ig*4+3)*33 + k];
        a0.x += x0*w.x; a0.y += x0*w.y; a0.z += x0*w.z; a0.w += x0*w.w;
        a1.x += x1*w.x; a1.y += x1*w.y; a1.z += x1*w.z; a1.w += x1*w.w;
        a2.x += x2*w.x; a2.y += x2*w.y; a2.z += x2*w.z; a2.w += x2*w.w;
        a3.x += x3*w.x; a3.y += x3*w.y; a3.z += x3*w.z; a3.w += x3*w.w;
    }
    float4 accs[4] = {a0, a1, a2, a3};
    float4 bv = ((const float4*)bsh)[r];
    float dl = 1.0f + delta[0];
#pragma unroll
    for (int c = 0; c < 4; c++){
        int n = n0 + ig*4 + c;
        if (n < NN){
            int g = batch[n];
            float nrm = rsqrtf(fmaxf((float)(be[g] - bs[g]), 1.0f));
            float4 fv;
            fv.x = (accs[c].x + bv.x)*nrm;
            fv.y = (accs[c].y + bv.y)*nrm;
            fv.z = (accs[c].z + bv.z)*nrm;
            fv.w = (accs[c].w + bv.w)*nrm;
            *(float4*)(f + (long)n*H + r*4) = fv;
            float4 av; av.x = fv.x*dl; av.y = fv.y*dl; av.z = fv.z*dl; av.w = fv.w*dl;
            *(float4*)(a + (long)n*D + r*4) = av;
        }
    }
}

// ================= xws_bf16 = bf16((x @ W) * dinv) : MFMA, 128-node block =================
// W fp32 [k*64+n] -> LDS W^T bf16 Wt[n*72+k]; wave computes 32 rows x 64 cols
__global__ __launch_bounds__(256) void k_gemm64(const float* __restrict__ x, int xs,
                         const float* __restrict__ W, const float* __restrict__ dinv,
                         u16* __restrict__ xb){
    __shared__ u16 Wt[64*72];
    int t = threadIdx.x;
    int n0 = blockIdx.x*GB;
    {   // stage W^T bf16: lanes sweep n for fixed k (coalesced global read)
        int n = t & 63;
        int k0 = (t >> 6)*16;
#pragma unroll
        for (int i = 0; i < 16; i++){
            int k = k0 + i;
            Wt[n*72 + k] = f2bf(W[k*64 + n]);
        }
    }
    __syncthreads();
    int wv = t >> 6;
    int lane = t & 63;
    int m = lane & 15, q = lane >> 4;
    // B-frags: B[k=q*8+j][n=tile*16+m] = Wt[n*72 + kk + q*8 + j] (contiguous b128)
    bf16x8 Bf[4][2];
#pragma unroll
    for (int tn = 0; tn < 4; tn++)
#pragma unroll
        for (int h = 0; h < 2; h++)
            Bf[tn][h] = *(const bf16x8*)&Wt[(tn*16 + m)*72 + h*32 + q*8];
#pragma unroll
    for (int rt = 0; rt < 2; rt++){
        int rbase = n0 + wv*32 + rt*16;
        const float* xr = x + (size_t)(rbase + m)*xs;
        bf16x8 Af[2];
#pragma unroll
        for (int h = 0; h < 2; h++){
            float4 v0 = *(const float4*)(xr + h*32 + q*8);
            float4 v1 = *(const float4*)(xr + h*32 + q*8 + 4);
            bf16x8 af;
            af[0]=(short)f2bf(v0.x); af[1]=(short)f2bf(v0.y);
            af[2]=(short)f2bf(v0.z); af[3]=(short)f2bf(v0.w);
            af[4]=(short)f2bf(v1.x); af[5]=(short)f2bf(v1.y);
            af[6]=(short)f2bf(v1.z); af[7]=(short)f2bf(v1.w);
            Af[h] = af;
        }
        float4 dv = *(const float4*)(dinv + rbase + q*4);   // rows q*4..q*4+3 of this tile
#pragma unroll
        for (int tn = 0; tn < 4; tn++){
            f32x4 c = {0.f,0.f,0.f,0.f};
            c = __builtin_amdgcn_mfma_f32_16x16x32_bf16(Af[0], Bf[tn][0], c, 0,0,0);
            c = __builtin_amdgcn_mfma_f32_16x16x32_bf16(Af[1], Bf[tn][1], c, 0,0,0);
#pragma unroll
            for (int rg = 0; rg < 4; rg++){
                int node = rbase + q*4 + rg;
                if (node < NN)
                    xb[(size_t)node*H + tn*16 + m] = f2bf(c[rg]*(&dv.x)[rg]);
            }
        }
    }
}

// ================= fused CSR gather + combine (bf16 rows, 8-edge-parallel uint4) =================
__global__ void k_conv(const int* __restrict__ off, const int* __restrict__ csrc,
                       const float* __restrict__ dinv, const u16* __restrict__ xb,
                       const float* __restrict__ b, const float* __restrict__ xin, int xs,
                       float* __restrict__ aout, int relu_res){
    int wid  = (blockIdx.x*blockDim.x + threadIdx.x) >> 6;
    int lane = threadIdx.x & 63;
    if (wid >= NN) return;
    int q = lane >> 3, r = lane & 7;
    int d = wid;
    int e0 = off[d], e1 = off[d+1];
    const uint4* X = (const uint4*)xb;
    float acc[8] = {0.f,0.f,0.f,0.f,0.f,0.f,0.f,0.f};
    for (int base = e0; base < e1; base += 64){
        int m = min(64, e1 - base);
        int idx = (base + lane < e1) ? csrc[base + lane] : 0;
        for (int j = 0; j < m; j += 8){
            int jq = j + q;
            int s = __shfl(idx, jq, 64);
            if (jq < m){
                uint4 v = X[(long)s*8 + r];
                acc[0] += blo(v.x); acc[1] += bhi(v.x);
                acc[2] += blo(v.y); acc[3] += bhi(v.y);
                acc[4] += blo(v.z); acc[5] += bhi(v.z);
                acc[6] += blo(v.w); acc[7] += bhi(v.w);
            }
        }
    }
#pragma unroll
    for (int o = 8; o < 64; o <<= 1){
#pragma unroll
        for (int k = 0; k < 8; k++) acc[k] += __shfl_xor(acc[k], o, 64);
    }
    if (q == 0){
        uint4 sv = X[(long)d*8 + r];
        float se[8] = {blo(sv.x),bhi(sv.x),blo(sv.y),bhi(sv.y),
                       blo(sv.z),bhi(sv.z),blo(sv.w),bhi(sv.w)};
        float di = dinv[d];
        const float4* bb = (const float4*)b;
        float4 b0 = bb[r*2], b1 = bb[r*2+1];
        float y[8];
#pragma unroll
        for (int k = 0; k < 4; k++) y[k]   = (acc[k]   + se[k])*di   + (&b0.x)[k];
#pragma unroll
        for (int k = 0; k < 4; k++) y[k+4] = (acc[k+4] + se[k+4])*di + (&b1.x)[k];
        if (relu_res){
            float4 x0 = *(const float4*)(xin + (long)d*xs + r*8);
            float4 x1 = *(const float4*)(xin + (long)d*xs + r*8 + 4);
#pragma unroll
            for (int k = 0; k < 4; k++) y[k]   = fmaxf(y[k],   0.f) + (&x0.x)[k];
#pragma unroll
            for (int k = 0; k < 4; k++) y[k+4] = fmaxf(y[k+4], 0.f) + (&x1.x)[k];
        }
        float4 o0 = {y[0],y[1],y[2],y[3]};
        float4 o1 = {y[4],y[5],y[6],y[7]};
        float4* op = (float4*)(aout + (long)d*D + r*8);
        op[0] = o0; op[1] = o1;
    }
}

// ================= segmented sum over sorted batch =================
__global__ void k_segsum(const float* __restrict__ a, const int* __restrict__ batch,
                         float* __restrict__ s){
    int d = threadIdx.x;
    int n0 = blockIdx.x*64;
    if (n0 >= NN) return;
    int n1 = min(n0 + 64, NN);
    float acc = 0.f;
    int curg = batch[n0];
    for (int n = n0; n < n1; n++){
        int g = batch[n];
        if (g != curg){ atomicAdd(&s[curg*D + d], acc); acc = 0.f; curg = g; }
        acc += a[(long)n*D + d];
    }
    atomicAdd(&s[curg*D + d], acc);
}

// ================= t = tanh((s @ att_W) / cnt) =================
__global__ void k_ctx(const float* __restrict__ s, const float* __restrict__ attW,
                      const int* __restrict__ bs, const int* __restrict__ be,
                      float* __restrict__ t){
    int idx = blockIdx.x*256 + threadIdx.x;
    int g = idx >> 8; int d = idx & 255;
    float inv = 1.0f/fmaxf((float)(be[g] - bs[g]), 1.0f);
    float v = 0.f;
    for (int k = 0; k < D; k++) v += s[g*D + k]*attW[k*D + d];
    t[idx] = tanhf(v*inv);
}

// ================= coef + attention pool =================
__global__ void k_coef_ap(const float* __restrict__ a, const int* __restrict__ batch,
                          const float* __restrict__ t, float* __restrict__ ap){
    int lane = threadIdx.x & 63;
    int wid  = (blockIdx.x*blockDim.x + threadIdx.x) >> 6;
    int n0 = wid*64;
    if (n0 >= NN) return;
    int n1 = min(n0 + 64, NN);
    float ax=0.f, ay=0.f, az=0.f, aw=0.f;
    int curg = batch[n0];
    for (int n = n0; n < n1; n++){
        int g = batch[n];
        const float4* ar = (const float4*)(a + (long)n*D);
        const float4* tr = (const float4*)(t + (long)g*D);
        float4 v = ar[lane];
        float4 tv = tr[lane];
        float part = v.x*tv.x + v.y*tv.y + v.z*tv.z + v.w*tv.w;
#pragma unroll
        for (int o = 32; o; o >>= 1) part += __shfl_xor(part, o, 64);
        float coef = sigm(part);
        if (g != curg){
            atomicAdd(&ap[curg*D + lane*4 + 0], ax);
            atomicAdd(&ap[curg*D + lane*4 + 1], ay);
            atomicAdd(&ap[curg*D + lane*4 + 2], az);
            atomicAdd(&ap[curg*D + lane*4 + 3], aw);
            ax = ay = az = aw = 0.f; curg = g;
        }
        ax += coef*v.x; ay += coef*v.y; az += coef*v.z; aw += coef*v.w;
    }
    atomicAdd(&ap[curg*D + lane*4 + 0], ax);
    atomicAdd(&ap[curg*D + lane*4 + 1], ay);
    atomicAdd(&ap[curg*D + lane*4 + 2], az);
    atomicAdd(&ap[curg*D + lane*4 + 3], aw);
}

// ================= per-graph MLP =================
__global__ void k_mlp2(const float* __restrict__ ap, const float* __restrict__ s,
                       const float* __restrict__ mu,
                       const float* __restrict__ W1, const float* __restrict__ b1,
                       const float* __restrict__ W2, const float* __restrict__ b2,
                       float* __restrict__ out){
    __shared__ float p[D];
    __shared__ float hid[128];
    int g = blockIdx.x; int tid = threadIdx.x;
    for (int i = tid; i < D; i += 128){
        float m = mu[i];
        p[i] = m*ap[g*D + i] + (1.0f - m)*s[g*D + i];
    }
    __syncthreads();
    float v = b1[tid];
    for (int k = 0; k < D; k++) v += p[k]*W1[k*128 + tid];
    hid[tid] = fmaxf(v, 0.f);
    __syncthreads();
    if (tid < H){
        float o = b2[tid];
        for (int k = 0; k < 128; k++) o += hid[k]*W2[k*H + tid];
        out[g*H + tid] = o;
    }
}

// ================= NTN stage 1 =================
__global__ void k_ntn(const float* __restrict__ gx, const float* __restrict__ tnW,
                      float* __restrict__ M){
    __shared__ float sgx[H];
    int b = blockIdx.x;
    int g = b >> 2;
    int ek = (b & 3)*256 + threadIdx.x;
    if (threadIdx.x < H) sgx[threadIdx.x] = gx[g*H + threadIdx.x];
    __syncthreads();
    float v = 0.f;
#pragma unroll 8
    for (int d = 0; d < H; d++) v += sgx[d]*tnW[d*(H*TN) + ek];
    M[g*(H*TN) + ek] = v;
}

// ================= final scoring =================
__global__ void k_final(const float* __restrict__ gx, const float* __restrict__ hx,
                        const float* __restrict__ M, const float* __restrict__ tnV,
                        const float* __restrict__ tnb,
                        const float* __restrict__ scW1, const float* __restrict__ scb1,
                        const float* __restrict__ scW2, const float* __restrict__ scb2,
                        const float* __restrict__ alpha, float* __restrict__ outp){
    __shared__ float sg[H], sh[H], sc[TN], h2[TN];
    int g = blockIdx.x; int lane = threadIdx.x;
    float gv = gx[g*H + lane], hv = hx[g*H + lane];
    sg[lane] = gv; sh[lane] = hv;
    __syncthreads();
    const float* Mg = M + g*(H*TN) + lane*TN;
    float myt1 = 0.f;
#pragma unroll
    for (int k = 0; k < TN; k++){
        float part = Mg[k]*hv;
#pragma unroll
        for (int o = 32; o; o >>= 1) part += __shfl_xor(part, o, 64);
        if (lane == k) myt1 = part;
    }
    if (lane < TN){
        float t2 = tnb[lane];
        for (int d = 0; d < H; d++) t2 += sg[d]*tnV[lane*128 + d];
        for (int e = 0; e < H; e++) t2 += sh[e]*tnV[lane*128 + 64 + e];
        sc[lane] = fmaxf(myt1 + t2, 0.f);
    }
    __syncthreads();
    if (lane < TN){
        float v = scb1[lane];
        for (int j = 0; j < TN; j++) v += sc[j]*scW1[j*TN + lane];
        h2[lane] = fmaxf(v, 0.f);
    }
    __syncthreads();
    float dff = gv - hv;
    float ssq = dff*dff;
#pragma unroll
    for (int o = 32; o; o >>= 1) ssq += __shfl_xor(ssq, o, 64);
    if (lane == 0){
        float score = scb2[0];
        for (int j = 0; j < TN; j++) score += h2[j]*scW2[j];
        float l2 = sqrtf(ssq);
        float al = alpha[0];
        outp[g] = al*sigm(score) + (1.0f - al)*(1.0f/(1.0f + expf(l2)));
    }
}

extern "C" void kernel_launch(void* const* d_in, const int* in_sizes, int n_in,
                              void* d_out, int out_size, void* d_ws, size_t ws_size,
                              hipStream_t stream) {
    const int*   ei1   = (const int*)d_in[0];
    const int*   ei2   = (const int*)d_in[1];
    const int*   bat1  = (const int*)d_in[2];
    const int*   bat2  = (const int*)d_in[3];
    const float* feat1 = (const float*)d_in[4];
    const float* feat2 = (const float*)d_in[5];
    const float* preW  = (const float*)d_in[6];
    const float* preb  = (const float*)d_in[7];
    const float* convW = (const float*)d_in[8];
    const float* convb = (const float*)d_in[9];
    const float* delta = (const float*)d_in[10];
    const float* alpha = (const float*)d_in[11];
    const float* mu    = (const float*)d_in[12];
    const float* attW  = (const float*)d_in[13];
    const float* pW1   = (const float*)d_in[14];
    const float* pb1   = (const float*)d_in[15];
    const float* pW2   = (const float*)d_in[16];
    const float* pb2   = (const float*)d_in[17];
    const float* tnW   = (const float*)d_in[18];
    const float* tnV   = (const float*)d_in[19];
    const float* tnb   = (const float*)d_in[20];
    const float* scW1  = (const float*)d_in[21];
    const float* scb1  = (const float*)d_in[22];
    const float* scW2  = (const float*)d_in[23];
    const float* scb2  = (const float*)d_in[24];
    float* out = (float*)d_out;

    // workspace carve (16 B aligned chunks); dual-side arrays indexed [side]
    char* w = (char*)d_ws;
    float*    a      = (float*)w;    w += sizeof(float)*(size_t)NN*D;
    float*    f      = (float*)w;    w += sizeof(float)*(size_t)NN*H;
    u16*      xb     = (u16*)w;      w += sizeof(u16)*(size_t)NN*H;
    float*    dinv   = (float*)w;    w += sizeof(float)*2*NN;
    int*      off    = (int*)w;      w += sizeof(int)*2*ONN;
    int*      csrc   = (int*)w;      w += sizeof(int)*2*(size_t)NE;
    unsigned* staged = (unsigned*)w; w += sizeof(unsigned)*2*(size_t)NB*CAP;
    int*      gcur   = (int*)w;      w += sizeof(int)*2*NB;
    int*      gbase  = (int*)w;      w += sizeof(int)*2*NB;
    int*      bs     = (int*)w;      w += sizeof(int)*2*NG;
    int*      be     = (int*)w;      w += sizeof(int)*2*NG;
    float*    ssum   = (float*)w;    w += sizeof(float)*2*NG*D;
    float*    tmat   = (float*)w;    w += sizeof(float)*NG*D;
    float*    ap     = (float*)w;    w += sizeof(float)*2*NG*D;
    float*    gx     = (float*)w;    w += sizeof(float)*NG*H;
    float*    hx     = (float*)w;    w += sizeof(float)*NG*H;
    float*    M      = (float*)w;    w += sizeof(float)*NG*H*TN;

    const int B = 256;
    const int gNH = (NN*H + B - 1)/B;   // 25000
    const int gN  = (NN + B - 1)/B;     // 391
    const int gT  = (NN + 63)/64;       // 1563
    const int gGm = (NN + GB - 1)/GB;   // 782 (mfma gemm)
    const int gCoef = (gT + 3)/4;       // 391

    // ---- dual-side binned CSR build ----
    k_bounds2<<<2*gN, B, 0, stream>>>(bat1, bat2, bs, be, gcur, ssum, ap, gN);
    k_binA<<<2*NAB, B, 0, stream>>>(ei1, ei2, gcur, staged, NAB);
    k_bscan<<<2, 256, 0, stream>>>(gcur, gbase);
    k_binB<<<2*NB, B, 0, stream>>>(gcur, gbase, staged, off, dinv, csrc);

    auto run_side = [&](int side, const int* batch, const float* feat, float* gout){
        const int*   off_s  = off  + side*ONN;
        const int*   csrc_s = csrc + side*NE;
        const float* dinv_s = dinv + side*NN;
        const int*   bs_s   = bs   + side*NG;
        const int*   be_s   = be   + side*NG;
        float*       ssum_s = ssum + side*NG*D;
        float*       ap_s   = ap   + side*NG*D;

        k_pre<<<gT, B, 0, stream>>>(feat, preW, preb, batch, bs_s, be_s, delta, f, a);

        const float* xin = f; int xs = H;
        for (int i = 0; i < 3; i++){
            k_gemm64<<<gGm, B, 0, stream>>>(xin, xs, convW + i*H*H, dinv_s, xb);
            float* aout = a + (i + 1)*H;
            k_conv<<<gNH, B, 0, stream>>>(off_s, csrc_s, dinv_s, xb, convb + i*H, xin, xs, aout, i < 2 ? 1 : 0);
            xin = aout; xs = D;
        }
        k_segsum<<<gT, 256, 0, stream>>>(a, batch, ssum_s);
        k_ctx<<<NG*D/256, 256, 0, stream>>>(ssum_s, attW, bs_s, be_s, tmat);
        k_coef_ap<<<gCoef, 256, 0, stream>>>(a, batch, tmat, ap_s);
        k_mlp2<<<NG, 128, 0, stream>>>(ap_s, ssum_s, mu, pW1, pb1, pW2, pb2, gout);
    };

    run_side(0, bat1, feat1, gx);
    run_side(1, bat2, feat2, hx);
    k_ntn<<<NG*4, 256, 0, stream>>>(gx, tnW, M);
    k_final<<<NG, 64, 0, stream>>>(gx, hx, M, tnV, tnb, scW1, scb1, scW2, scb2, alpha, out);
}

// Round 11
// 822.031 us; speedup vs baseline: 4.9970x; 1.0222x over previous
//
#include <hip/hip_runtime.h>
#include <math.h>

#define NN 100000
#define NE 1600000
#define NG 128
#define L 32
#define H 64
#define D 256
#define TN 16
#define ONN (NN+4)

// binned CSR build params
#define BK 512
#define NB ((NN + BK - 1)/BK)
#define CAP 10240
#define ACH 8192
#define NAB ((NE + ACH - 1)/ACH)

// MFMA gemm tile
#define GB 128

typedef unsigned short u16;
typedef __attribute__((ext_vector_type(8))) short bf16x8;
typedef __attribute__((ext_vector_type(4))) float f32x4;

__device__ __forceinline__ float sigm(float x){ return 1.0f/(1.0f+expf(-x)); }
__device__ __forceinline__ float blo(unsigned u){ return __uint_as_float(u<<16); }
__device__ __forceinline__ float bhi(unsigned u){ return __uint_as_float(u & 0xffff0000u); }
__device__ __forceinline__ u16 f2bf(float f){
    unsigned u = __float_as_uint(f);
    unsigned r = u + 0x7fffu + ((u>>16)&1u);
    return (u16)(r>>16);
}

// ================= dual-side bounds + zero-init =================
__global__ void k_bounds2(const int* __restrict__ bat1, const int* __restrict__ bat2,
                          int* __restrict__ bs, int* __restrict__ be,
                          int* __restrict__ gcur, float* __restrict__ ssum, float* __restrict__ ap,
                          int half){
    int side = blockIdx.x >= half;
    const int* batch = side ? bat2 : bat1;
    int i = (blockIdx.x - side*half)*blockDim.x + threadIdx.x;
    if (i < NG*D){ ssum[side*NG*D + i] = 0.f; ap[side*NG*D + i] = 0.f; }
    if (i < NB) gcur[side*NB + i] = 0;
    if (i >= NN) return;
    int g = batch[i];
    if (i == 0 || batch[i-1] != g) bs[side*NG + g] = i;
    if (i == NN-1 || batch[i+1] != g) be[side*NG + g] = i + 1;
}

// ================= phase A: bin edges, single LDS-atomic pass, register ranks =================
__global__ __launch_bounds__(256) void k_binA(const int* __restrict__ ei1, const int* __restrict__ ei2,
                        int* __restrict__ gcur, unsigned* __restrict__ staged, int half){
    __shared__ int hist[NB];
    __shared__ int basb[NB];
    int side = blockIdx.x >= half;
    int lb = blockIdx.x - side*half;
    const int* ei = side ? ei2 : ei1;
    const int* srcp = ei;
    const int* dstp = ei + NE;
    int e0 = lb*ACH, e1 = min(e0 + ACH, NE);
    int t = threadIdx.x;
    if (t < NB) hist[t] = 0;
    __syncthreads();
    unsigned val[32];
    int br[32];
#pragma unroll
    for (int i = 0; i < 32; i++){
        int e = e0 + t + i*256;
        br[i] = -1;
        if (e < e1){
            int d = dstp[e];
            int s = srcp[e];
            int b = d >> 9;
            int r = atomicAdd(&hist[b], 1);
            val[i] = ((unsigned)s << 9) | (unsigned)(d & 511);
            br[i] = (b << 16) | r;
        }
    }
    __syncthreads();
    if (t < NB){
        int c = hist[t];
        basb[t] = (c > 0) ? atomicAdd(&gcur[side*NB + t], c) : 0;
    }
    __syncthreads();
#pragma unroll
    for (int i = 0; i < 32; i++){
        if (br[i] >= 0){
            int b = br[i] >> 16;
            int pos = basb[b] + (br[i] & 0xffff);
            if (pos < CAP)
                staged[((size_t)(side*NB + b))*CAP + pos] = val[i];
        }
    }
}

// ================= bucket-base scan =================
__global__ void k_bscan(const int* __restrict__ gcur, int* __restrict__ gbase){
    __shared__ int s[256];
    int side = blockIdx.x;
    int t = threadIdx.x;
    int v = (t < NB) ? gcur[side*NB + t] : 0;
    s[t] = v;
    __syncthreads();
    for (int o = 1; o < 256; o <<= 1){
        int u = (t >= o) ? s[t-o] : 0;
        __syncthreads();
        s[t] += u;
        __syncthreads();
    }
    if (t < NB) gbase[side*NB + t] = s[t] - v;
}

// ================= phase B: per-bucket count (1 atomic pass) + scan + rank-scatter =================
__global__ __launch_bounds__(256) void k_binB(const int* __restrict__ gcur, const int* __restrict__ gbase,
                        const unsigned* __restrict__ staged,
                        int* __restrict__ off, float* __restrict__ dinv, int* __restrict__ csrc){
    __shared__ int cnt[BK];
    __shared__ int loc[BK];
    __shared__ int ps[256];
    int side = blockIdx.x >= NB;
    int b = blockIdx.x - side*NB;
    int t = threadIdx.x;
    int ne = gcur[side*NB + b];
    if (ne > CAP) ne = CAP;
    int base = gbase[side*NB + b];
    const unsigned* st = staged + ((size_t)(side*NB + b))*CAP;
    cnt[2*t] = 0; cnt[2*t+1] = 0;
    __syncthreads();
    unsigned vv[40];
    int rr[40];
#pragma unroll
    for (int i = 0; i < 40; i++){
        int e = t + i*256;
        rr[i] = -1;
        if (e < ne){
            unsigned v = st[e];
            vv[i] = v;
            rr[i] = atomicAdd(&cnt[v & 511], 1);
        }
    }
    __syncthreads();
    int c0 = cnt[2*t], c1 = cnt[2*t+1];
    ps[t] = c0 + c1;
    __syncthreads();
    for (int o = 1; o < 256; o <<= 1){
        int u = (t >= o) ? ps[t-o] : 0;
        __syncthreads();
        ps[t] += u;
        __syncthreads();
    }
    int excl = ps[t] - (c0 + c1);
    loc[2*t] = excl;
    loc[2*t+1] = excl + c0;
#pragma unroll
    for (int j = 0; j < 2; j++){
        int i = 2*t + j;
        int node = b*BK + i;
        if (node < NN){
            off[side*ONN + node] = base + loc[i];
            dinv[side*NN + node] = rsqrtf((float)cnt[i] + 1.0f);
        }
    }
    if (b == 0 && t == 0) off[side*ONN + NN] = NE;
    __syncthreads();
#pragma unroll
    for (int i = 0; i < 40; i++){
        if (rr[i] >= 0){
            int ld = vv[i] & 511;
            csrc[side*NE + base + loc[ld] + rr[i]] = (int)(vv[i] >> 9);
        }
    }
}

// ================= pre (GEMM-style, 64-node tile, 4x4 blocking) =================
__global__ __launch_bounds__(256) void k_pre(const float* __restrict__ feat, const float* __restrict__ W,
                      const float* __restrict__ b, const int* __restrict__ batch,
                      const int* __restrict__ bs, const int* __restrict__ be,
                      const float* __restrict__ delta,
                      float* __restrict__ f, float* __restrict__ a){
    __shared__ float Xl[64*33];
    __shared__ float Wl[L*H];
    __shared__ float bsh[H];
    int t = threadIdx.x;
    int n0 = blockIdx.x*64;
    {
        const float4* Wg = (const float4*)W;
        float4* Wv = (float4*)Wl;
        Wv[t] = Wg[t];
        Wv[t+256] = Wg[t+256];
        if (t < H) bsh[t] = b[t];
    }
    {
        int rr = t & 7;
        int ii = t >> 3;
#pragma unroll
        for (int p = 0; p < 2; p++){
            int i = p*32 + ii;
            int n = n0 + i;
            float4 v = {0.f,0.f,0.f,0.f};
            if (n < NN) v = *(const float4*)(feat + (long)n*L + rr*4);
            Xl[i*33 + rr*4 + 0] = v.x;
            Xl[i*33 + rr*4 + 1] = v.y;
            Xl[i*33 + rr*4 + 2] = v.z;
            Xl[i*33 + rr*4 + 3] = v.w;
        }
    }
    __syncthreads();
    int r = t & 15, ig = t >> 4;
    float4 a0={0,0,0,0}, a1={0,0,0,0}, a2={0,0,0,0}, a3={0,0,0,0};
    const float4* Wl4 = (const float4*)Wl;
#pragma unroll
    for (int k = 0; k < L; k++){
        float4 w = Wl4[k*16 + r];
        float x0 = Xl[(ig*4+0)*33 + k];
        float x1 = Xl[(ig*4+1)*33 + k];
        float x2 = Xl[(ig*4+2)*33 + k];
        float x3 = Xl[(ig*4+3)*33 + k];
        a0.x += x0*w.x; a0.y += x0*w.y; a0.z += x0*w.z; a0.w += x0*w.w;
        a1.x += x1*w.x; a1.y += x1*w.y; a1.z += x1*w.z; a1.w += x1*w.w;
        a2.x += x2*w.x; a2.y += x2*w.y; a2.z += x2*w.z; a2.w += x2*w.w;
        a3.x += x3*w.x; a3.y += x3*w.y; a3.z += x3*w.z; a3.w += x3*w.w;
    }
    float4 accs[4] = {a0, a1, a2, a3};
    float4 bv = ((const float4*)bsh)[r];
    float dl = 1.0f + delta[0];
#pragma unroll
    for (int c = 0; c < 4; c++){
        int n = n0 + ig*4 + c;
        if (n < NN){
            int g = batch[n];
            float nrm = rsqrtf(fmaxf((float)(be[g] - bs[g]), 1.0f));
            float4 fv;
            fv.x = (accs[c].x + bv.x)*nrm;
            fv.y = (accs[c].y + bv.y)*nrm;
            fv.z = (accs[c].z + bv.z)*nrm;
            fv.w = (accs[c].w + bv.w)*nrm;
            *(float4*)(f + (long)n*H + r*4) = fv;
            float4 av; av.x = fv.x*dl; av.y = fv.y*dl; av.z = fv.z*dl; av.w = fv.w*dl;
            *(float4*)(a + (long)n*D + r*4) = av;
        }
    }
}

// ================= xws_bf16 = bf16((x @ W) * dinv) : MFMA, 128-node block =================
__global__ __launch_bounds__(256) void k_gemm64(const float* __restrict__ x, int xs,
                         const float* __restrict__ W, const float* __restrict__ dinv,
                         u16* __restrict__ xb){
    __shared__ u16 Wt[64*72];
    int t = threadIdx.x;
    int n0 = blockIdx.x*GB;
    {
        int n = t & 63;
        int k0 = (t >> 6)*16;
#pragma unroll
        for (int i = 0; i < 16; i++){
            int k = k0 + i;
            Wt[n*72 + k] = f2bf(W[k*64 + n]);
        }
    }
    __syncthreads();
    int wv = t >> 6;
    int lane = t & 63;
    int m = lane & 15, q = lane >> 4;
    bf16x8 Bf[4][2];
#pragma unroll
    for (int tn = 0; tn < 4; tn++)
#pragma unroll
        for (int h = 0; h < 2; h++)
            Bf[tn][h] = *(const bf16x8*)&Wt[(tn*16 + m)*72 + h*32 + q*8];
#pragma unroll
    for (int rt = 0; rt < 2; rt++){
        int rbase = n0 + wv*32 + rt*16;
        const float* xr = x + (size_t)(rbase + m)*xs;
        bf16x8 Af[2];
#pragma unroll
        for (int h = 0; h < 2; h++){
            float4 v0 = *(const float4*)(xr + h*32 + q*8);
            float4 v1 = *(const float4*)(xr + h*32 + q*8 + 4);
            bf16x8 af;
            af[0]=(short)f2bf(v0.x); af[1]=(short)f2bf(v0.y);
            af[2]=(short)f2bf(v0.z); af[3]=(short)f2bf(v0.w);
            af[4]=(short)f2bf(v1.x); af[5]=(short)f2bf(v1.y);
            af[6]=(short)f2bf(v1.z); af[7]=(short)f2bf(v1.w);
            Af[h] = af;
        }
        float4 dv = *(const float4*)(dinv + rbase + q*4);
#pragma unroll
        for (int tn = 0; tn < 4; tn++){
            f32x4 c = {0.f,0.f,0.f,0.f};
            c = __builtin_amdgcn_mfma_f32_16x16x32_bf16(Af[0], Bf[tn][0], c, 0,0,0);
            c = __builtin_amdgcn_mfma_f32_16x16x32_bf16(Af[1], Bf[tn][1], c, 0,0,0);
#pragma unroll
            for (int rg = 0; rg < 4; rg++){
                int node = rbase + q*4 + rg;
                if (node < NN)
                    xb[(size_t)node*H + tn*16 + m] = f2bf(c[rg]*(&dv.x)[rg]);
            }
        }
    }
}

// ================= fused CSR gather + combine (bf16 rows, 8-edge-parallel uint4) =================
__global__ void k_conv(const int* __restrict__ off, const int* __restrict__ csrc,
                       const float* __restrict__ dinv, const u16* __restrict__ xb,
                       const float* __restrict__ b, const float* __restrict__ xin, int xs,
                       float* __restrict__ aout, int relu_res){
    int wid  = (blockIdx.x*blockDim.x + threadIdx.x) >> 6;
    int lane = threadIdx.x & 63;
    if (wid >= NN) return;
    int q = lane >> 3, r = lane & 7;
    int d = wid;
    int e0 = off[d], e1 = off[d+1];
    const uint4* X = (const uint4*)xb;
    float acc[8] = {0.f,0.f,0.f,0.f,0.f,0.f,0.f,0.f};
    for (int base = e0; base < e1; base += 64){
        int m = min(64, e1 - base);
        int idx = (base + lane < e1) ? csrc[base + lane] : 0;
        for (int j = 0; j < m; j += 8){
            int jq = j + q;
            int s = __shfl(idx, jq, 64);
            if (jq < m){
                uint4 v = X[(long)s*8 + r];
                acc[0] += blo(v.x); acc[1] += bhi(v.x);
                acc[2] += blo(v.y); acc[3] += bhi(v.y);
                acc[4] += blo(v.z); acc[5] += bhi(v.z);
                acc[6] += blo(v.w); acc[7] += bhi(v.w);
            }
        }
    }
#pragma unroll
    for (int o = 8; o < 64; o <<= 1){
#pragma unroll
        for (int k = 0; k < 8; k++) acc[k] += __shfl_xor(acc[k], o, 64);
    }
    if (q == 0){
        uint4 sv = X[(long)d*8 + r];
        float se[8] = {blo(sv.x),bhi(sv.x),blo(sv.y),bhi(sv.y),
                       blo(sv.z),bhi(sv.z),blo(sv.w),bhi(sv.w)};
        float di = dinv[d];
        const float4* bb = (const float4*)b;
        float4 b0 = bb[r*2], b1 = bb[r*2+1];
        float y[8];
#pragma unroll
        for (int k = 0; k < 4; k++) y[k]   = (acc[k]   + se[k])*di   + (&b0.x)[k];
#pragma unroll
        for (int k = 0; k < 4; k++) y[k+4] = (acc[k+4] + se[k+4])*di + (&b1.x)[k];
        if (relu_res){
            float4 x0 = *(const float4*)(xin + (long)d*xs + r*8);
            float4 x1 = *(const float4*)(xin + (long)d*xs + r*8 + 4);
#pragma unroll
            for (int k = 0; k < 4; k++) y[k]   = fmaxf(y[k],   0.f) + (&x0.x)[k];
#pragma unroll
            for (int k = 0; k < 4; k++) y[k+4] = fmaxf(y[k+4], 0.f) + (&x1.x)[k];
        }
        float4 o0 = {y[0],y[1],y[2],y[3]};
        float4 o1 = {y[4],y[5],y[6],y[7]};
        float4* op = (float4*)(aout + (long)d*D + r*8);
        op[0] = o0; op[1] = o1;
    }
}

// ================= segmented sum over sorted batch =================
__global__ void k_segsum(const float* __restrict__ a, const int* __restrict__ batch,
                         float* __restrict__ s){
    int d = threadIdx.x;
    int n0 = blockIdx.x*64;
    if (n0 >= NN) return;
    int n1 = min(n0 + 64, NN);
    float acc = 0.f;
    int curg = batch[n0];
    for (int n = n0; n < n1; n++){
        int g = batch[n];
        if (g != curg){ atomicAdd(&s[curg*D + d], acc); acc = 0.f; curg = g; }
        acc += a[(long)n*D + d];
    }
    atomicAdd(&s[curg*D + d], acc);
}

// ================= t = tanh((s @ att_W) / cnt) =================
__global__ void k_ctx(const float* __restrict__ s, const float* __restrict__ attW,
                      const int* __restrict__ bs, const int* __restrict__ be,
                      float* __restrict__ t){
    int idx = blockIdx.x*256 + threadIdx.x;
    int g = idx >> 8; int d = idx & 255;
    float inv = 1.0f/fmaxf((float)(be[g] - bs[g]), 1.0f);
    float v = 0.f;
    for (int k = 0; k < D; k++) v += s[g*D + k]*attW[k*D + d];
    t[idx] = tanhf(v*inv);
}

// ================= coef + attention pool =================
__global__ void k_coef_ap(const float* __restrict__ a, const int* __restrict__ batch,
                          const float* __restrict__ t, float* __restrict__ ap){
    int lane = threadIdx.x & 63;
    int wid  = (blockIdx.x*blockDim.x + threadIdx.x) >> 6;
    int n0 = wid*64;
    if (n0 >= NN) return;
    int n1 = min(n0 + 64, NN);
    float ax=0.f, ay=0.f, az=0.f, aw=0.f;
    int curg = batch[n0];
    for (int n = n0; n < n1; n++){
        int g = batch[n];
        const float4* ar = (const float4*)(a + (long)n*D);
        const float4* tr = (const float4*)(t + (long)g*D);
        float4 v = ar[lane];
        float4 tv = tr[lane];
        float part = v.x*tv.x + v.y*tv.y + v.z*tv.z + v.w*tv.w;
#pragma unroll
        for (int o = 32; o; o >>= 1) part += __shfl_xor(part, o, 64);
        float coef = sigm(part);
        if (g != curg){
            atomicAdd(&ap[curg*D + lane*4 + 0], ax);
            atomicAdd(&ap[curg*D + lane*4 + 1], ay);
            atomicAdd(&ap[curg*D + lane*4 + 2], az);
            atomicAdd(&ap[curg*D + lane*4 + 3], aw);
            ax = ay = az = aw = 0.f; curg = g;
        }
        ax += coef*v.x; ay += coef*v.y; az += coef*v.z; aw += coef*v.w;
    }
    atomicAdd(&ap[curg*D + lane*4 + 0], ax);
    atomicAdd(&ap[curg*D + lane*4 + 1], ay);
    atomicAdd(&ap[curg*D + lane*4 + 2], az);
    atomicAdd(&ap[curg*D + lane*4 + 3], aw);
}

// ================= per-graph MLP =================
__global__ void k_mlp2(const float* __restrict__ ap, const float* __restrict__ s,
                       const float* __restrict__ mu,
                       const float* __restrict__ W1, const float* __restrict__ b1,
                       const float* __restrict__ W2, const float* __restrict__ b2,
                       float* __restrict__ out){
    __shared__ float p[D];
    __shared__ float hid[128];
    int g = blockIdx.x; int tid = threadIdx.x;
    for (int i = tid; i < D; i += 128){
        float m = mu[i];
        p[i] = m*ap[g*D + i] + (1.0f - m)*s[g*D + i];
    }
    __syncthreads();
    float v = b1[tid];
    for (int k = 0; k < D; k++) v += p[k]*W1[k*128 + tid];
    hid[tid] = fmaxf(v, 0.f);
    __syncthreads();
    if (tid < H){
        float o = b2[tid];
        for (int k = 0; k < 128; k++) o += hid[k]*W2[k*H + tid];
        out[g*H + tid] = o;
    }
}

// ================= NTN stage 1 =================
__global__ void k_ntn(const float* __restrict__ gx, const float* __restrict__ tnW,
                      float* __restrict__ M){
    __shared__ float sgx[H];
    int b = blockIdx.x;
    int g = b >> 2;
    int ek = (b & 3)*256 + threadIdx.x;
    if (threadIdx.x < H) sgx[threadIdx.x] = gx[g*H + threadIdx.x];
    __syncthreads();
    float v = 0.f;
#pragma unroll 8
    for (int d = 0; d < H; d++) v += sgx[d]*tnW[d*(H*TN) + ek];
    M[g*(H*TN) + ek] = v;
}

// ================= final scoring =================
__global__ void k_final(const float* __restrict__ gx, const float* __restrict__ hx,
                        const float* __restrict__ M, const float* __restrict__ tnV,
                        const float* __restrict__ tnb,
                        const float* __restrict__ scW1, const float* __restrict__ scb1,
                        const float* __restrict__ scW2, const float* __restrict__ scb2,
                        const float* __restrict__ alpha, float* __restrict__ outp){
    __shared__ float sg[H], sh[H], sc[TN], h2[TN];
    int g = blockIdx.x; int lane = threadIdx.x;
    float gv = gx[g*H + lane], hv = hx[g*H + lane];
    sg[lane] = gv; sh[lane] = hv;
    __syncthreads();
    const float* Mg = M + g*(H*TN) + lane*TN;
    float myt1 = 0.f;
#pragma unroll
    for (int k = 0; k < TN; k++){
        float part = Mg[k]*hv;
#pragma unroll
        for (int o = 32; o; o >>= 1) part += __shfl_xor(part, o, 64);
        if (lane == k) myt1 = part;
    }
    if (lane < TN){
        float t2 = tnb[lane];
        for (int d = 0; d < H; d++) t2 += sg[d]*tnV[lane*128 + d];
        for (int e = 0; e < H; e++) t2 += sh[e]*tnV[lane*128 + 64 + e];
        sc[lane] = fmaxf(myt1 + t2, 0.f);
    }
    __syncthreads();
    if (lane < TN){
        float v = scb1[lane];
        for (int j = 0; j < TN; j++) v += sc[j]*scW1[j*TN + lane];
        h2[lane] = fmaxf(v, 0.f);
    }
    __syncthreads();
    float dff = gv - hv;
    float ssq = dff*dff;
#pragma unroll
    for (int o = 32; o; o >>= 1) ssq += __shfl_xor(ssq, o, 64);
    if (lane == 0){
        float score = scb2[0];
        for (int j = 0; j < TN; j++) score += h2[j]*scW2[j];
        float l2 = sqrtf(ssq);
        float al = alpha[0];
        outp[g] = al*sigm(score) + (1.0f - al)*(1.0f/(1.0f + expf(l2)));
    }
}

extern "C" void kernel_launch(void* const* d_in, const int* in_sizes, int n_in,
                              void* d_out, int out_size, void* d_ws, size_t ws_size,
                              hipStream_t stream) {
    const int*   ei1   = (const int*)d_in[0];
    const int*   ei2   = (const int*)d_in[1];
    const int*   bat1  = (const int*)d_in[2];
    const int*   bat2  = (const int*)d_in[3];
    const float* feat1 = (const float*)d_in[4];
    const float* feat2 = (const float*)d_in[5];
    const float* preW  = (const float*)d_in[6];
    const float* preb  = (const float*)d_in[7];
    const float* convW = (const float*)d_in[8];
    const float* convb = (const float*)d_in[9];
    const float* delta = (const float*)d_in[10];
    const float* alpha = (const float*)d_in[11];
    const float* mu    = (const float*)d_in[12];
    const float* attW  = (const float*)d_in[13];
    const float* pW1   = (const float*)d_in[14];
    const float* pb1   = (const float*)d_in[15];
    const float* pW2   = (const float*)d_in[16];
    const float* pb2   = (const float*)d_in[17];
    const float* tnW   = (const float*)d_in[18];
    const float* tnV   = (const float*)d_in[19];
    const float* tnb   = (const float*)d_in[20];
    const float* scW1  = (const float*)d_in[21];
    const float* scb1  = (const float*)d_in[22];
    const float* scW2  = (const float*)d_in[23];
    const float* scb2  = (const float*)d_in[24];
    float* out = (float*)d_out;

    // workspace carve (16 B aligned chunks); dual-side arrays indexed [side]
    char* w = (char*)d_ws;
    float*    a      = (float*)w;    w += sizeof(float)*(size_t)NN*D;
    float*    f      = (float*)w;    w += sizeof(float)*(size_t)NN*H;
    u16*      xb     = (u16*)w;      w += sizeof(u16)*(size_t)NN*H;
    float*    dinv   = (float*)w;    w += sizeof(float)*2*NN;
    int*      off    = (int*)w;      w += sizeof(int)*2*ONN;
    int*      csrc   = (int*)w;      w += sizeof(int)*2*(size_t)NE;
    unsigned* staged = (unsigned*)w; w += sizeof(unsigned)*2*(size_t)NB*CAP;
    int*      gcur   = (int*)w;      w += sizeof(int)*2*NB;
    int*      gbase  = (int*)w;      w += sizeof(int)*2*NB;
    int*      bs     = (int*)w;      w += sizeof(int)*2*NG;
    int*      be     = (int*)w;      w += sizeof(int)*2*NG;
    float*    ssum   = (float*)w;    w += sizeof(float)*2*NG*D;
    float*    tmat   = (float*)w;    w += sizeof(float)*NG*D;
    float*    ap     = (float*)w;    w += sizeof(float)*2*NG*D;
    float*    gx     = (float*)w;    w += sizeof(float)*NG*H;
    float*    hx     = (float*)w;    w += sizeof(float)*NG*H;
    float*    M      = (float*)w;    w += sizeof(float)*NG*H*TN;

    const int B = 256;
    const int gNH = (NN*H + B - 1)/B;   // 25000
    const int gN  = (NN + B - 1)/B;     // 391
    const int gT  = (NN + 63)/64;       // 1563
    const int gGm = (NN + GB - 1)/GB;   // 782 (mfma gemm)
    const int gCoef = (gT + 3)/4;       // 391

    // ---- dual-side binned CSR build ----
    k_bounds2<<<2*gN, B, 0, stream>>>(bat1, bat2, bs, be, gcur, ssum, ap, gN);
    k_binA<<<2*NAB, B, 0, stream>>>(ei1, ei2, gcur, staged, NAB);
    k_bscan<<<2, 256, 0, stream>>>(gcur, gbase);
    k_binB<<<2*NB, B, 0, stream>>>(gcur, gbase, staged, off, dinv, csrc);

    auto run_side = [&](int side, const int* batch, const float* feat, float* gout){
        const int*   off_s  = off  + side*ONN;
        const int*   csrc_s = csrc + side*NE;
        const float* dinv_s = dinv + side*NN;
        const int*   bs_s   = bs   + side*NG;
        const int*   be_s   = be   + side*NG;
        float*       ssum_s = ssum + side*NG*D;
        float*       ap_s   = ap   + side*NG*D;

        k_pre<<<gT, B, 0, stream>>>(feat, preW, preb, batch, bs_s, be_s, delta, f, a);

        const float* xin = f; int xs = H;
        for (int i = 0; i < 3; i++){
            k_gemm64<<<gGm, B, 0, stream>>>(xin, xs, convW + i*H*H, dinv_s, xb);
            float* aout = a + (i + 1)*H;
            k_conv<<<gNH, B, 0, stream>>>(off_s, csrc_s, dinv_s, xb, convb + i*H, xin, xs, aout, i < 2 ? 1 : 0);
            xin = aout; xs = D;
        }
        k_segsum<<<gT, 256, 0, stream>>>(a, batch, ssum_s);
        k_ctx<<<NG*D/256, 256, 0, stream>>>(ssum_s, attW, bs_s, be_s, tmat);
        k_coef_ap<<<gCoef, 256, 0, stream>>>(a, batch, tmat, ap_s);
        k_mlp2<<<NG, 128, 0, stream>>>(ap_s, ssum_s, mu, pW1, pb1, pW2, pb2, gout);
    };

    run_side(0, bat1, feat1, gx);
    run_side(1, bat2, feat2, hx);
    k_ntn<<<NG*4, 256, 0, stream>>>(gx, tnW, M);
    k_final<<<NG, 64, 0, stream>>>(gx, hx, M, tnV, tnb, scW1, scb1, scW2, scb2, alpha, out);
}

// Round 13
// 797.838 us; speedup vs baseline: 5.1485x; 1.0303x over previous
//
#include <hip/hip_runtime.h>
#include <math.h>

#define NN 100000
#define NE 1600000
#define NG 128
#define L 32
#define H 64
#define D 256
#define TN 16
#define ONN (NN+4)

// binned CSR build params
#define BK 512
#define NB ((NN + BK - 1)/BK)
#define CAP 10240
#define ACH 8192
#define NAB ((NE + ACH - 1)/ACH)

// MFMA gemm tile
#define GB 128

typedef unsigned short u16;
typedef __attribute__((ext_vector_type(8))) short bf16x8;
typedef __attribute__((ext_vector_type(4))) float f32x4;

__device__ __forceinline__ float sigm(float x){ return 1.0f/(1.0f+expf(-x)); }
__device__ __forceinline__ float blo(unsigned u){ return __uint_as_float(u<<16); }
__device__ __forceinline__ float bhi(unsigned u){ return __uint_as_float(u & 0xffff0000u); }
__device__ __forceinline__ u16 f2bf(float f){
    unsigned u = __float_as_uint(f);
    unsigned r = u + 0x7fffu + ((u>>16)&1u);
    return (u16)(r>>16);
}

// ================= dual-side bounds + zero-init =================
__global__ void k_bounds2(const int* __restrict__ bat1, const int* __restrict__ bat2,
                          int* __restrict__ bs, int* __restrict__ be,
                          int* __restrict__ gcur, float* __restrict__ ssum, float* __restrict__ ap,
                          int half){
    int side = blockIdx.x >= half;
    const int* batch = side ? bat2 : bat1;
    int i = (blockIdx.x - side*half)*blockDim.x + threadIdx.x;
    if (i < NG*D){ ssum[side*NG*D + i] = 0.f; ap[side*NG*D + i] = 0.f; }
    if (i < NB) gcur[side*NB + i] = 0;
    if (i >= NN) return;
    int g = batch[i];
    if (i == 0 || batch[i-1] != g) bs[side*NG + g] = i;
    if (i == NN-1 || batch[i+1] != g) be[side*NG + g] = i + 1;
}

// ================= phase A: bin edges, per-wave LDS hists, register ranks =================
__global__ __launch_bounds__(256) void k_binA(const int* __restrict__ ei1, const int* __restrict__ ei2,
                        int* __restrict__ gcur, unsigned* __restrict__ staged, int half){
    __shared__ int h4[4][NB];
    int side = blockIdx.x >= half;
    int lb = blockIdx.x - side*half;
    const int* ei = side ? ei2 : ei1;
    const int* srcp = ei;
    const int* dstp = ei + NE;
    int e0 = lb*ACH, e1 = min(e0 + ACH, NE);
    int t = threadIdx.x;
    int wv = t >> 6;
    if (t < NB){ h4[0][t] = 0; h4[1][t] = 0; h4[2][t] = 0; h4[3][t] = 0; }
    __syncthreads();
    unsigned val[32];
    int br[32];
#pragma unroll
    for (int i = 0; i < 32; i++){
        int e = e0 + t + i*256;
        br[i] = -1;
        if (e < e1){
            int d = dstp[e];
            int s = srcp[e];
            int b = d >> 9;
            int r = atomicAdd(&h4[wv][b], 1);
            val[i] = ((unsigned)s << 9) | (unsigned)(d & 511);
            br[i] = (b << 16) | r;
        }
    }
    __syncthreads();
    if (t < NB){
        int c0 = h4[0][t], c1 = h4[1][t], c2 = h4[2][t], c3 = h4[3][t];
        int c = c0 + c1 + c2 + c3;
        int base = (c > 0) ? atomicAdd(&gcur[side*NB + t], c) : 0;
        h4[0][t] = base;
        h4[1][t] = base + c0;
        h4[2][t] = base + c0 + c1;
        h4[3][t] = base + c0 + c1 + c2;
    }
    __syncthreads();
#pragma unroll
    for (int i = 0; i < 32; i++){
        if (br[i] >= 0){
            int b = br[i] >> 16;
            int pos = h4[wv][b] + (br[i] & 0xffff);
            if (pos < CAP)
                staged[((size_t)(side*NB + b))*CAP + pos] = val[i];
        }
    }
}

// ================= bucket-base scan =================
__global__ void k_bscan(const int* __restrict__ gcur, int* __restrict__ gbase){
    __shared__ int s[256];
    int side = blockIdx.x;
    int t = threadIdx.x;
    int v = (t < NB) ? gcur[side*NB + t] : 0;
    s[t] = v;
    __syncthreads();
    for (int o = 1; o < 256; o <<= 1){
        int u = (t >= o) ? s[t-o] : 0;
        __syncthreads();
        s[t] += u;
        __syncthreads();
    }
    if (t < NB) gbase[side*NB + t] = s[t] - v;
}

// ================= phase B: per-bucket count (per-wave hists) + scan + rank-scatter =================
__global__ __launch_bounds__(256) void k_binB(const int* __restrict__ gcur, const int* __restrict__ gbase,
                        const unsigned* __restrict__ staged,
                        int* __restrict__ off, float* __restrict__ dinv, int* __restrict__ csrc){
    __shared__ int c4[4][BK];
    __shared__ int ps[256];
    int side = blockIdx.x >= NB;
    int b = blockIdx.x - side*NB;
    int t = threadIdx.x;
    int wv = t >> 6;
    int ne = gcur[side*NB + b];
    if (ne > CAP) ne = CAP;
    int base = gbase[side*NB + b];
    const unsigned* st = staged + ((size_t)(side*NB + b))*CAP;
    for (int i = t; i < 4*BK; i += 256) ((int*)c4)[i] = 0;
    __syncthreads();
    unsigned vv[40];
    int rr[40];
#pragma unroll
    for (int i = 0; i < 40; i++){
        int e = t + i*256;
        rr[i] = -1;
        if (e < ne){
            unsigned v = st[e];
            vv[i] = v;
            rr[i] = atomicAdd(&c4[wv][v & 511], 1);
        }
    }
    __syncthreads();
    int i0 = 2*t, i1 = 2*t + 1;
    int a0 = c4[0][i0], a1 = c4[1][i0], a2 = c4[2][i0], a3 = c4[3][i0];
    int b0 = c4[0][i1], b1 = c4[1][i1], b2 = c4[2][i1], b3 = c4[3][i1];
    int t0 = a0+a1+a2+a3, t1 = b0+b1+b2+b3;
    ps[t] = t0 + t1;
    __syncthreads();
    for (int o = 1; o < 256; o <<= 1){
        int u = (t >= o) ? ps[t-o] : 0;
        __syncthreads();
        ps[t] += u;
        __syncthreads();
    }
    int excl = ps[t] - (t0 + t1);
    int l0 = excl, l1 = excl + t0;
    {
        int node0 = b*BK + i0;
        if (node0 < NN){
            off[side*ONN + node0] = base + l0;
            dinv[side*NN + node0] = rsqrtf((float)t0 + 1.0f);
        }
        int node1 = b*BK + i1;
        if (node1 < NN){
            off[side*ONN + node1] = base + l1;
            dinv[side*NN + node1] = rsqrtf((float)t1 + 1.0f);
        }
    }
    if (b == 0 && t == 0) off[side*ONN + NN] = NE;
    // overwrite c4 with per-wave scatter bases (global position)
    c4[0][i0] = base + l0;
    c4[1][i0] = base + l0 + a0;
    c4[2][i0] = base + l0 + a0 + a1;
    c4[3][i0] = base + l0 + a0 + a1 + a2;
    c4[0][i1] = base + l1;
    c4[1][i1] = base + l1 + b0;
    c4[2][i1] = base + l1 + b0 + b1;
    c4[3][i1] = base + l1 + b0 + b1 + b2;
    __syncthreads();
#pragma unroll
    for (int i = 0; i < 40; i++){
        if (rr[i] >= 0){
            int ld = vv[i] & 511;
            csrc[side*NE + c4[wv][ld] + rr[i]] = (int)(vv[i] >> 9);
        }
    }
}

// ================= pre (GEMM-style, 64-node tile, 4x4 blocking) =================
__global__ __launch_bounds__(256) void k_pre(const float* __restrict__ feat, const float* __restrict__ W,
                      const float* __restrict__ b, const int* __restrict__ batch,
                      const int* __restrict__ bs, const int* __restrict__ be,
                      const float* __restrict__ delta,
                      float* __restrict__ f, float* __restrict__ a){
    __shared__ float Xl[64*33];
    __shared__ float Wl[L*H];
    __shared__ float bsh[H];
    int t = threadIdx.x;
    int n0 = blockIdx.x*64;
    {
        const float4* Wg = (const float4*)W;
        float4* Wv = (float4*)Wl;
        Wv[t] = Wg[t];
        Wv[t+256] = Wg[t+256];
        if (t < H) bsh[t] = b[t];
    }
    {
        int rr = t & 7;
        int ii = t >> 3;
#pragma unroll
        for (int p = 0; p < 2; p++){
            int i = p*32 + ii;
            int n = n0 + i;
            float4 v = {0.f,0.f,0.f,0.f};
            if (n < NN) v = *(const float4*)(feat + (long)n*L + rr*4);
            Xl[i*33 + rr*4 + 0] = v.x;
            Xl[i*33 + rr*4 + 1] = v.y;
            Xl[i*33 + rr*4 + 2] = v.z;
            Xl[i*33 + rr*4 + 3] = v.w;
        }
    }
    __syncthreads();
    int r = t & 15, ig = t >> 4;
    float4 a0={0,0,0,0}, a1={0,0,0,0}, a2={0,0,0,0}, a3={0,0,0,0};
    const float4* Wl4 = (const float4*)Wl;
#pragma unroll
    for (int k = 0; k < L; k++){
        float4 w = Wl4[k*16 + r];
        float x0 = Xl[(ig*4+0)*33 + k];
        float x1 = Xl[(ig*4+1)*33 + k];
        float x2 = Xl[(ig*4+2)*33 + k];
        float x3 = Xl[(ig*4+3)*33 + k];
        a0.x += x0*w.x; a0.y += x0*w.y; a0.z += x0*w.z; a0.w += x0*w.w;
        a1.x += x1*w.x; a1.y += x1*w.y; a1.z += x1*w.z; a1.w += x1*w.w;
        a2.x += x2*w.x; a2.y += x2*w.y; a2.z += x2*w.z; a2.w += x2*w.w;
        a3.x += x3*w.x; a3.y += x3*w.y; a3.z += x3*w.z; a3.w += x3*w.w;
    }
    float4 accs[4] = {a0, a1, a2, a3};
    float4 bv = ((const float4*)bsh)[r];
    float dl = 1.0f + delta[0];
#pragma unroll
    for (int c = 0; c < 4; c++){
        int n = n0 + ig*4 + c;
        if (n < NN){
            int g = batch[n];
            float nrm = rsqrtf(fmaxf((float)(be[g] - bs[g]), 1.0f));
            float4 fv;
            fv.x = (accs[c].x + bv.x)*nrm;
            fv.y = (accs[c].y + bv.y)*nrm;
            fv.z = (accs[c].z + bv.z)*nrm;
            fv.w = (accs[c].w + bv.w)*nrm;
            *(float4*)(f + (long)n*H + r*4) = fv;
            float4 av; av.x = fv.x*dl; av.y = fv.y*dl; av.z = fv.z*dl; av.w = fv.w*dl;
            *(float4*)(a + (long)n*D + r*4) = av;
        }
    }
}

// ================= xws_bf16 = bf16((x @ W) * dinv) : MFMA, 128-node block =================
__global__ __launch_bounds__(256) void k_gemm64(const float* __restrict__ x, int xs,
                         const float* __restrict__ W, const float* __restrict__ dinv,
                         u16* __restrict__ xb){
    __shared__ u16 Wt[64*72];
    int t = threadIdx.x;
    int n0 = blockIdx.x*GB;
    {
        int n = t & 63;
        int k0 = (t >> 6)*16;
#pragma unroll
        for (int i = 0; i < 16; i++){
            int k = k0 + i;
            Wt[n*72 + k] = f2bf(W[k*64 + n]);
        }
    }
    __syncthreads();
    int wv = t >> 6;
    int lane = t & 63;
    int m = lane & 15, q = lane >> 4;
    bf16x8 Bf[4][2];
#pragma unroll
    for (int tn = 0; tn < 4; tn++)
#pragma unroll
        for (int h = 0; h < 2; h++)
            Bf[tn][h] = *(const bf16x8*)&Wt[(tn*16 + m)*72 + h*32 + q*8];
#pragma unroll
    for (int rt = 0; rt < 2; rt++){
        int rbase = n0 + wv*32 + rt*16;
        const float* xr = x + (size_t)(rbase + m)*xs;
        bf16x8 Af[2];
#pragma unroll
        for (int h = 0; h < 2; h++){
            float4 v0 = *(const float4*)(xr + h*32 + q*8);
            float4 v1 = *(const float4*)(xr + h*32 + q*8 + 4);
            bf16x8 af;
            af[0]=(short)f2bf(v0.x); af[1]=(short)f2bf(v0.y);
            af[2]=(short)f2bf(v0.z); af[3]=(short)f2bf(v0.w);
            af[4]=(short)f2bf(v1.x); af[5]=(short)f2bf(v1.y);
            af[6]=(short)f2bf(v1.z); af[7]=(short)f2bf(v1.w);
            Af[h] = af;
        }
        float4 dv = *(const float4*)(dinv + rbase + q*4);
#pragma unroll
        for (int tn = 0; tn < 4; tn++){
            f32x4 c = {0.f,0.f,0.f,0.f};
            c = __builtin_amdgcn_mfma_f32_16x16x32_bf16(Af[0], Bf[tn][0], c, 0,0,0);
            c = __builtin_amdgcn_mfma_f32_16x16x32_bf16(Af[1], Bf[tn][1], c, 0,0,0);
#pragma unroll
            for (int rg = 0; rg < 4; rg++){
                int node = rbase + q*4 + rg;
                if (node < NN)
                    xb[(size_t)node*H + tn*16 + m] = f2bf(c[rg]*(&dv.x)[rg]);
            }
        }
    }
}

// ================= fused CSR gather + combine (bf16 rows, 8-edge-parallel uint4) =================
__global__ void k_conv(const int* __restrict__ off, const int* __restrict__ csrc,
                       const float* __restrict__ dinv, const u16* __restrict__ xb,
                       const float* __restrict__ b, const float* __restrict__ xin, int xs,
                       float* __restrict__ aout, int relu_res){
    int wid  = (blockIdx.x*blockDim.x + threadIdx.x) >> 6;
    int lane = threadIdx.x & 63;
    if (wid >= NN) return;
    int q = lane >> 3, r = lane & 7;
    int d = wid;
    int e0 = off[d], e1 = off[d+1];
    const uint4* X = (const uint4*)xb;
    // hoisted epilogue loads (q==0 lanes) — overlap their latency with the gather loop
    uint4 sv = {0,0,0,0};
    float4 b0 = {0,0,0,0}, b1 = {0,0,0,0};
    float di = 0.f;
    if (q == 0){
        sv = X[(long)d*8 + r];
        const float4* bb = (const float4*)b;
        b0 = bb[r*2]; b1 = bb[r*2+1];
        di = dinv[d];
    }
    float acc[8] = {0.f,0.f,0.f,0.f,0.f,0.f,0.f,0.f};
    for (int base = e0; base < e1; base += 64){
        int m = min(64, e1 - base);
        int idx = (base + lane < e1) ? csrc[base + lane] : 0;
        for (int j = 0; j < m; j += 8){
            int jq = j + q;
            int s = __shfl(idx, jq, 64);
            if (jq < m){
                uint4 v = X[(long)s*8 + r];
                acc[0] += blo(v.x); acc[1] += bhi(v.x);
                acc[2] += blo(v.y); acc[3] += bhi(v.y);
                acc[4] += blo(v.z); acc[5] += bhi(v.z);
                acc[6] += blo(v.w); acc[7] += bhi(v.w);
            }
        }
    }
#pragma unroll
    for (int o = 8; o < 64; o <<= 1){
#pragma unroll
        for (int k = 0; k < 8; k++) acc[k] += __shfl_xor(acc[k], o, 64);
    }
    if (q == 0){
        float se[8] = {blo(sv.x),bhi(sv.x),blo(sv.y),bhi(sv.y),
                       blo(sv.z),bhi(sv.z),blo(sv.w),bhi(sv.w)};
        float y[8];
#pragma unroll
        for (int k = 0; k < 4; k++) y[k]   = (acc[k]   + se[k])*di   + (&b0.x)[k];
#pragma unroll
        for (int k = 0; k < 4; k++) y[k+4] = (acc[k+4] + se[k+4])*di + (&b1.x)[k];
        if (relu_res){
            float4 x0 = *(const float4*)(xin + (long)d*xs + r*8);
            float4 x1 = *(const float4*)(xin + (long)d*xs + r*8 + 4);
#pragma unroll
            for (int k = 0; k < 4; k++) y[k]   = fmaxf(y[k],   0.f) + (&x0.x)[k];
#pragma unroll
            for (int k = 0; k < 4; k++) y[k+4] = fmaxf(y[k+4], 0.f) + (&x1.x)[k];
        }
        float4 o0 = {y[0],y[1],y[2],y[3]};
        float4 o1 = {y[4],y[5],y[6],y[7]};
        float4* op = (float4*)(aout + (long)d*D + r*8);
        op[0] = o0; op[1] = o1;
    }
}

// ================= segmented sum over sorted batch =================
__global__ void k_segsum(const float* __restrict__ a, const int* __restrict__ batch,
                         float* __restrict__ s){
    int d = threadIdx.x;
    int n0 = blockIdx.x*64;
    if (n0 >= NN) return;
    int n1 = min(n0 + 64, NN);
    float acc = 0.f;
    int curg = batch[n0];
    for (int n = n0; n < n1; n++){
        int g = batch[n];
        if (g != curg){ atomicAdd(&s[curg*D + d], acc); acc = 0.f; curg = g; }
        acc += a[(long)n*D + d];
    }
    atomicAdd(&s[curg*D + d], acc);
}

// ================= t = tanh((s @ att_W) / cnt) =================
__global__ void k_ctx(const float* __restrict__ s, const float* __restrict__ attW,
                      const int* __restrict__ bs, const int* __restrict__ be,
                      float* __restrict__ t){
    int idx = blockIdx.x*256 + threadIdx.x;
    int g = idx >> 8; int d = idx & 255;
    float inv = 1.0f/fmaxf((float)(be[g] - bs[g]), 1.0f);
    float v = 0.f;
    for (int k = 0; k < D; k++) v += s[g*D + k]*attW[k*D + d];
    t[idx] = tanhf(v*inv);
}

// ================= coef + attention pool =================
__global__ void k_coef_ap(const float* __restrict__ a, const int* __restrict__ batch,
                          const float* __restrict__ t, float* __restrict__ ap){
    int lane = threadIdx.x & 63;
    int wid  = (blockIdx.x*blockDim.x + threadIdx.x) >> 6;
    int n0 = wid*64;
    if (n0 >= NN) return;
    int n1 = min(n0 + 64, NN);
    float ax=0.f, ay=0.f, az=0.f, aw=0.f;
    int curg = batch[n0];
    for (int n = n0; n < n1; n++){
        int g = batch[n];
        const float4* ar = (const float4*)(a + (long)n*D);
        const float4* tr = (const float4*)(t + (long)g*D);
        float4 v = ar[lane];
        float4 tv = tr[lane];
        float part = v.x*tv.x + v.y*tv.y + v.z*tv.z + v.w*tv.w;
#pragma unroll
        for (int o = 32; o; o >>= 1) part += __shfl_xor(part, o, 64);
        float coef = sigm(part);
        if (g != curg){
            atomicAdd(&ap[curg*D + lane*4 + 0], ax);
            atomicAdd(&ap[curg*D + lane*4 + 1], ay);
            atomicAdd(&ap[curg*D + lane*4 + 2], az);
            atomicAdd(&ap[curg*D + lane*4 + 3], aw);
            ax = ay = az = aw = 0.f; curg = g;
        }
        ax += coef*v.x; ay += coef*v.y; az += coef*v.z; aw += coef*v.w;
    }
    atomicAdd(&ap[curg*D + lane*4 + 0], ax);
    atomicAdd(&ap[curg*D + lane*4 + 1], ay);
    atomicAdd(&ap[curg*D + lane*4 + 2], az);
    atomicAdd(&ap[curg*D + lane*4 + 3], aw);
}

// ================= per-graph MLP =================
__global__ void k_mlp2(const float* __restrict__ ap, const float* __restrict__ s,
                       const float* __restrict__ mu,
                       const float* __restrict__ W1, const float* __restrict__ b1,
                       const float* __restrict__ W2, const float* __restrict__ b2,
                       float* __restrict__ out){
    __shared__ float p[D];
    __shared__ float hid[128];
    int g = blockIdx.x; int tid = threadIdx.x;
    for (int i = tid; i < D; i += 128){
        float m = mu[i];
        p[i] = m*ap[g*D + i] + (1.0f - m)*s[g*D + i];
    }
    __syncthreads();
    float v = b1[tid];
    for (int k = 0; k < D; k++) v += p[k]*W1[k*128 + tid];
    hid[tid] = fmaxf(v, 0.f);
    __syncthreads();
    if (tid < H){
        float o = b2[tid];
        for (int k = 0; k < 128; k++) o += hid[k]*W2[k*H + tid];
        out[g*H + tid] = o;
    }
}

// ================= NTN stage 1 =================
__global__ void k_ntn(const float* __restrict__ gx, const float* __restrict__ tnW,
                      float* __restrict__ M){
    __shared__ float sgx[H];
    int b = blockIdx.x;
    int g = b >> 2;
    int ek = (b & 3)*256 + threadIdx.x;
    if (threadIdx.x < H) sgx[threadIdx.x] = gx[g*H + threadIdx.x];
    __syncthreads();
    float v = 0.f;
#pragma unroll 8
    for (int d = 0; d < H; d++) v += sgx[d]*tnW[d*(H*TN) + ek];
    M[g*(H*TN) + ek] = v;
}

// ================= final scoring =================
__global__ void k_final(const float* __restrict__ gx, const float* __restrict__ hx,
                        const float* __restrict__ M, const float* __restrict__ tnV,
                        const float* __restrict__ tnb,
                        const float* __restrict__ scW1, const float* __restrict__ scb1,
                        const float* __restrict__ scW2, const float* __restrict__ scb2,
                        const float* __restrict__ alpha, float* __restrict__ outp){
    __shared__ float sg[H], sh[H], sc[TN], h2[TN];
    int g = blockIdx.x; int lane = threadIdx.x;
    float gv = gx[g*H + lane], hv = hx[g*H + lane];
    sg[lane] = gv; sh[lane] = hv;
    __syncthreads();
    const float* Mg = M + g*(H*TN) + lane*TN;
    float myt1 = 0.f;
#pragma unroll
    for (int k = 0; k < TN; k++){
        float part = Mg[k]*hv;
#pragma unroll
        for (int o = 32; o; o >>= 1) part += __shfl_xor(part, o, 64);
        if (lane == k) myt1 = part;
    }
    if (lane < TN){
        float t2 = tnb[lane];
        for (int d = 0; d < H; d++) t2 += sg[d]*tnV[lane*128 + d];
        for (int e = 0; e < H; e++) t2 += sh[e]*tnV[lane*128 + 64 + e];
        sc[lane] = fmaxf(myt1 + t2, 0.f);
    }
    __syncthreads();
    if (lane < TN){
        float v = scb1[lane];
        for (int j = 0; j < TN; j++) v += sc[j]*scW1[j*TN + lane];
        h2[lane] = fmaxf(v, 0.f);
    }
    __syncthreads();
    float dff = gv - hv;
    float ssq = dff*dff;
#pragma unroll
    for (int o = 32; o; o >>= 1) ssq += __shfl_xor(ssq, o, 64);
    if (lane == 0){
        float score = scb2[0];
        for (int j = 0; j < TN; j++) score += h2[j]*scW2[j];
        float l2 = sqrtf(ssq);
        float al = alpha[0];
        outp[g] = al*sigm(score) + (1.0f - al)*(1.0f/(1.0f + expf(l2)));
    }
}

extern "C" void kernel_launch(void* const* d_in, const int* in_sizes, int n_in,
                              void* d_out, int out_size, void* d_ws, size_t ws_size,
                              hipStream_t stream) {
    const int*   ei1   = (const int*)d_in[0];
    const int*   ei2   = (const int*)d_in[1];
    const int*   bat1  = (const int*)d_in[2];
    const int*   bat2  = (const int*)d_in[3];
    const float* feat1 = (const float*)d_in[4];
    const float* feat2 = (const float*)d_in[5];
    const float* preW  = (const float*)d_in[6];
    const float* preb  = (const float*)d_in[7];
    const float* convW = (const float*)d_in[8];
    const float* convb = (const float*)d_in[9];
    const float* delta = (const float*)d_in[10];
    const float* alpha = (const float*)d_in[11];
    const float* mu    = (const float*)d_in[12];
    const float* attW  = (const float*)d_in[13];
    const float* pW1   = (const float*)d_in[14];
    const float* pb1   = (const float*)d_in[15];
    const float* pW2   = (const float*)d_in[16];
    const float* pb2   = (const float*)d_in[17];
    const float* tnW   = (const float*)d_in[18];
    const float* tnV   = (const float*)d_in[19];
    const float* tnb   = (const float*)d_in[20];
    const float* scW1  = (const float*)d_in[21];
    const float* scb1  = (const float*)d_in[22];
    const float* scW2  = (const float*)d_in[23];
    const float* scb2  = (const float*)d_in[24];
    float* out = (float*)d_out;

    // workspace carve (16 B aligned chunks); dual-side arrays indexed [side]
    char* w = (char*)d_ws;
    float*    a      = (float*)w;    w += sizeof(float)*(size_t)NN*D;
    float*    f      = (float*)w;    w += sizeof(float)*(size_t)NN*H;
    u16*      xb     = (u16*)w;      w += sizeof(u16)*(size_t)NN*H;
    float*    dinv   = (float*)w;    w += sizeof(float)*2*NN;
    int*      off    = (int*)w;      w += sizeof(int)*2*ONN;
    int*      csrc   = (int*)w;      w += sizeof(int)*2*(size_t)NE;
    unsigned* staged = (unsigned*)w; w += sizeof(unsigned)*2*(size_t)NB*CAP;
    int*      gcur   = (int*)w;      w += sizeof(int)*2*NB;
    int*      gbase  = (int*)w;      w += sizeof(int)*2*NB;
    int*      bs     = (int*)w;      w += sizeof(int)*2*NG;
    int*      be     = (int*)w;      w += sizeof(int)*2*NG;
    float*    ssum   = (float*)w;    w += sizeof(float)*2*NG*D;
    float*    tmat   = (float*)w;    w += sizeof(float)*NG*D;
    float*    ap     = (float*)w;    w += sizeof(float)*2*NG*D;
    float*    gx     = (float*)w;    w += sizeof(float)*NG*H;
    float*    hx     = (float*)w;    w += sizeof(float)*NG*H;
    float*    M      = (float*)w;    w += sizeof(float)*NG*H*TN;

    const int B = 256;
    const int gNH = (NN*H + B - 1)/B;   // 25000
    const int gN  = (NN + B - 1)/B;     // 391
    const int gT  = (NN + 63)/64;       // 1563
    const int gGm = (NN + GB - 1)/GB;   // 782 (mfma gemm)
    const int gCoef = (gT + 3)/4;       // 391

    // ---- dual-side binned CSR build ----
    k_bounds2<<<2*gN, B, 0, stream>>>(bat1, bat2, bs, be, gcur, ssum, ap, gN);
    k_binA<<<2*NAB, B, 0, stream>>>(ei1, ei2, gcur, staged, NAB);
    k_bscan<<<2, 256, 0, stream>>>(gcur, gbase);
    k_binB<<<2*NB, B, 0, stream>>>(gcur, gbase, staged, off, dinv, csrc);

    auto run_side = [&](int side, const int* batch, const float* feat, float* gout){
        const int*   off_s  = off  + side*ONN;
        const int*   csrc_s = csrc + side*NE;
        const float* dinv_s = dinv + side*NN;
        const int*   bs_s   = bs   + side*NG;
        const int*   be_s   = be   + side*NG;
        float*       ssum_s = ssum + side*NG*D;
        float*       ap_s   = ap   + side*NG*D;

        k_pre<<<gT, B, 0, stream>>>(feat, preW, preb, batch, bs_s, be_s, delta, f, a);

        const float* xin = f; int xs = H;
        for (int i = 0; i < 3; i++){
            k_gemm64<<<gGm, B, 0, stream>>>(xin, xs, convW + i*H*H, dinv_s, xb);
            float* aout = a + (i + 1)*H;
            k_conv<<<gNH, B, 0, stream>>>(off_s, csrc_s, dinv_s, xb, convb + i*H, xin, xs, aout, i < 2 ? 1 : 0);
            xin = aout; xs = D;
        }
        k_segsum<<<gT, 256, 0, stream>>>(a, batch, ssum_s);
        k_ctx<<<NG*D/256, 256, 0, stream>>>(ssum_s, attW, bs_s, be_s, tmat);
        k_coef_ap<<<gCoef, 256, 0, stream>>>(a, batch, tmat, ap_s);
        k_mlp2<<<NG, 128, 0, stream>>>(ap_s, ssum_s, mu, pW1, pb1, pW2, pb2, gout);
    };

    run_side(0, bat1, feat1, gx);
    run_side(1, bat2, feat2, hx);
    k_ntn<<<NG*4, 256, 0, stream>>>(gx, tnW, M);
    k_final<<<NG, 64, 0, stream>>>(gx, hx, M, tnV, tnb, scW1, scb1, scW2, scb2, alpha, out);
}